// Round 6
// baseline (561.501 us; speedup 1.0000x reference)
//
#include <hip/hip_runtime.h>
#include <hip/hip_bf16.h>
#include <hip/hip_cooperative_groups.h>

// ---------------------------------------------------------------------------
// SPN layer (R14): prep{softmax||Wsplit||x->bf16||count||zero-cur} -> scan1 ->
// scatter(+inline bucket-base scan) -> slot3(+inline scan) -> gather ->
// mlp_coop (ONE cooperative kernel: gemm1 -> stats -> grid.sync -> BN1+ReLU
// in-registers (LDS bounce to A-frag layout) -> gemm2 -> stats -> grid.sync
// -> BN2+ReLU -> f32 out).  z1/z2 never hit HBM (saves 102MB + 2 launches).
// Launches 11 -> 6 (R13 had ~200us unaccounted vs per-kernel estimates ->
// dispatch overhead / small-pass latency is a first-class cost).
// Fallback: legacy gemm1/gemm2bn/bn2 path if cooperative launch errors.
// ---------------------------------------------------------------------------

#define RCAP 64    // slots per row; P(Poisson(16) > 64) ~ 1e-20 per row
#define P2B 256    // blocks in count/scatter passes
#define BPB 4      // blocks per bucket in slot3

typedef __attribute__((ext_vector_type(8))) short short8;
typedef __attribute__((ext_vector_type(4))) float f32x4;

__device__ inline unsigned short f2bf(float v) {           // RNE bf16 round
    unsigned int u = __float_as_uint(v);
    return (unsigned short)((u + 0x7fffu + ((u >> 16) & 1u)) >> 16);
}
__device__ inline float bf2f(unsigned int u) { return __uint_as_float(u << 16); }
__device__ inline float bflo(unsigned int u) { return __uint_as_float(u << 16); }
__device__ inline float bfhi(unsigned int u) { return __uint_as_float(u & 0xFFFF0000u); }

// --- prep: [0]=softmax+zero stats, [1..2]=W split, [3..3+NX)=x->bf16,
//     [3+NX..3+NX+P2B) = edge-count histogram + zero cur (bucketed path) ----
__global__ __launch_bounds__(256) void prep_k(
        const float* __restrict__ hc, float* __restrict__ hwp, float* __restrict__ sums,
        const float* __restrict__ W1, const float* __restrict__ W2,
        unsigned short* __restrict__ w1h, unsigned short* __restrict__ w1l,
        unsigned short* __restrict__ w2h, unsigned short* __restrict__ w2l,
        const float4* __restrict__ x4, uint4* __restrict__ xb, int K, long long n8,
        const int* __restrict__ rows, int* __restrict__ C, int* __restrict__ cur,
        int E, int per, int nbukp, int N, int NX) {
    __shared__ int hist[128];
    int b = blockIdx.x, tid = threadIdx.x;
    if (b == 0) {                                    // softmax + zero stats
        sums[tid] = 0.f; sums[tid + 256] = 0.f;
        if (tid == 0) {
            float tmp[8];
            float m = -1e30f;
            for (int k = 0; k < K; ++k) m = fmaxf(m, hc[k]);
            float s = 0.f;
            for (int k = 0; k < K; ++k) { float e = __expf(hc[k] - m); tmp[k] = e; s += e; }
            float inv = 1.f / s;
            for (int k = 0; k < 8; ++k) hwp[k] = 0.f;
            for (int k = 0; k < K; ++k) hwp[k + 1] = tmp[k] * inv;
        }
        return;
    }
    if (b <= 2) {                                    // W split (transposed hi/lo)
        const float* W = (b == 2) ? W2 : W1;
        unsigned short* th = (b == 2) ? w2h : w1h;
        unsigned short* tl = (b == 2) ? w2l : w1l;
        for (int i = tid; i < 16384; i += 256) {
            int k = i >> 7, n = i & 127;
            float v = W[k * 128 + n];
            unsigned short hi = f2bf(v);
            th[n * 128 + k] = hi;
            tl[n * 128 + k] = f2bf(v - bf2f(hi));
        }
        return;
    }
    if (b < 3 + NX) {                                // x -> bf16
        long long g = (long long)(b - 3) * 256 + tid;
        if (g >= n8) return;
        float4 a = x4[g * 2], c = x4[g * 2 + 1];
        union { unsigned short us[8]; uint4 v; } o;
        o.us[0] = f2bf(a.x); o.us[1] = f2bf(a.y); o.us[2] = f2bf(a.z); o.us[3] = f2bf(a.w);
        o.us[4] = f2bf(c.x); o.us[5] = f2bf(c.y); o.us[6] = f2bf(c.z); o.us[7] = f2bf(c.w);
        xb[g] = o.v;
        return;
    }
    // count role (only launched when bucketed): histogram of row>>10 + zero cur
    int cblk = b - 3 - NX;
    for (int i = tid; i < nbukp; i += 256) hist[i] = 0;
    __syncthreads();
    int e0 = cblk * per, e1 = min(E, e0 + per);
    for (int e = e0 + tid; e < e1; e += 256)
        atomicAdd(&hist[rows[e] >> 10], 1);
    __syncthreads();
    for (int i = tid; i < nbukp; i += 256) C[i * P2B + cblk] = hist[i];
    int zper = (N + P2B - 1) / P2B;
    int z0 = cblk * zper, z1 = min(N, z0 + zper);
    for (int i = z0 + tid; i < z1; i += 256) cur[i] = 0;
}

// P2a: block b scans bucket-b's row of C (coalesced; Hillis-Steele in LDS);
// C becomes within-bucket exclusive prefix; tot[b] = bucket total.
__global__ __launch_bounds__(256) void scan1_k(int* __restrict__ C,
        int* __restrict__ tot, int nbukp, int nblk) {
    __shared__ int buf[256];
    int b = blockIdx.x, tid = threadIdx.x;
    int v = (tid < nblk) ? C[b * P2B + tid] : 0;
    buf[tid] = v;
    __syncthreads();
#pragma unroll
    for (int off = 1; off < 256; off <<= 1) {
        int t = (tid >= off) ? buf[tid - off] : 0;
        __syncthreads();
        buf[tid] += t;
        __syncthreads();
    }
    if (tid < nblk) C[b * P2B + tid] = buf[tid] - v;     // exclusive
    if (tid == 255) tot[b] = buf[255];
}

// P2b: bucket-grouped 4B records: d | col<<3 | (row&1023)<<20
// bucket bases derived inline from tot[] (scan2 folded into prologue)
__global__ __launch_bounds__(256) void scatter_k(const int* __restrict__ rows,
        const int* __restrict__ cols, const int* __restrict__ ew,
        const int* __restrict__ O, const int* __restrict__ tot,
        unsigned* __restrict__ bucketed, int E, int per, int nbukp, int K) {
    __shared__ int buf[128];
    __shared__ unsigned curs[128];
    int blk = blockIdx.x, tid = threadIdx.x;
    int v = (tid < 128 && tid < nbukp) ? tot[tid] : 0;
    if (tid < 128) buf[tid] = v;
    __syncthreads();
#pragma unroll
    for (int off = 1; off < 128; off <<= 1) {
        int t = (tid >= off && tid < 128) ? buf[tid - off] : 0;
        __syncthreads();
        if (tid < 128) buf[tid] += t;
        __syncthreads();
    }
    if (tid < nbukp)
        curs[tid] = (unsigned)(O[tid * P2B + blk] + buf[tid] - v);  // excl base
    __syncthreads();
    int e0 = blk * per, e1 = min(E, e0 + per);
    for (int e = e0 + tid; e < e1; e += 256) {
        int r = rows[e];
        int c = cols[e];
        int d = ew[e];
        if (d < 1 || d > K) d = 0;                   // hwp[0] = 0 -> weight 0
        unsigned idx = atomicAdd(&curs[r >> 10], 1u);
        bucketed[idx] = (unsigned)d | ((unsigned)c << 3) | ((unsigned)(r & 1023) << 20);
    }
}

// P3: ticket + 4B staging scatter, one 1024-row bucket per BPB-block group.
// blockIdx % nbukp keeps a bucket's blocks on one XCD (nbukp % 8 == 0).
__global__ __launch_bounds__(256) void slot3_k(const unsigned* __restrict__ bucketed,
        const int* __restrict__ tot, int* __restrict__ cur,
        unsigned* __restrict__ staging, int nbukp) {
    __shared__ int buf[128];
    int tid = threadIdx.x;
    if (tid < 128) buf[tid] = (tid < nbukp) ? tot[tid] : 0;
    __syncthreads();
#pragma unroll
    for (int off = 1; off < 128; off <<= 1) {
        int t = (tid >= off && tid < 128) ? buf[tid - off] : 0;
        __syncthreads();
        if (tid < 128) buf[tid] += t;
        __syncthreads();
    }
    int bucket = blockIdx.x % nbukp, sub = blockIdx.x / nbukp;
    int s1 = buf[bucket];
    int s0 = s1 - tot[bucket];
    int cnt = s1 - s0;
    int qlo = s0 + (int)((long long)cnt * sub / BPB);
    int qhi = s0 + (int)((long long)cnt * (sub + 1) / BPB);
    int rbase = bucket << 10;
    for (int e = qlo + tid; e < qhi; e += 256) {
        unsigned u = bucketed[e];
        int row = rbase + (int)(u >> 20);
        int s = atomicAdd(&cur[row], 1);
        if (s < RCAP)
            staging[((size_t)row << 6) + s] = u & 0xFFFFFu;
    }
}

// legacy single-pass slot (fallback: N/K out of packing range or ws too small)
__global__ __launch_bounds__(256) void slot_k(const int* __restrict__ rows,
        const int* __restrict__ cols, const int* __restrict__ ew,
        int* __restrict__ cur, unsigned* __restrict__ staging, int E, int K) {
    int e = blockIdx.x * 256 + threadIdx.x;
    if (e >= E) return;
    int r = rows[e];
    int d = ew[e];
    if (d < 1 || d > K) d = 0;
    int s = atomicAdd(&cur[r], 1);
    if (s < RCAP)
        staging[((size_t)r << 6) + s] = (unsigned)d | ((unsigned)cols[e] << 3);
}

// one wave per row, 4 edges per wave-step: each 16-lane group loads one full
// 256B row (uint4/lane). 4B payload records; weight via 8-entry LDS table.
__global__ __launch_bounds__(256) void gather_k(
        const unsigned short* __restrict__ xb, const unsigned* __restrict__ staging,
        const int* __restrict__ cur, const float* __restrict__ hwp,
        unsigned short* __restrict__ h, int N) {
    __shared__ float hwl[8];
    int tid = threadIdx.x;
    if (tid < 8) hwl[tid] = hwp[tid];
    __syncthreads();
    int wid = (blockIdx.x * 256 + tid) >> 6;
    if (wid >= N) return;
    int lane = tid & 63;
    int g4 = lane >> 4, li = lane & 15;
    int deg = __builtin_amdgcn_readfirstlane(cur[wid]);
    deg = min(deg, RCAP);
    const unsigned* ep = staging + ((size_t)wid << 6);
    const unsigned short* xrow = xb + li * 8;          // 16B per lane within row
    float a0 = 0.f, a1 = 0.f, a2 = 0.f, a3 = 0.f;
    float a4 = 0.f, a5 = 0.f, a6 = 0.f, a7 = 0.f;
    if (g4 == 0) {                                     // GIN self term (eps=0)
        uint4 u = *(const uint4*)(xb + (size_t)wid * 128 + li * 8);
        a0 = bflo(u.x); a1 = bfhi(u.x); a2 = bflo(u.y); a3 = bfhi(u.y);
        a4 = bflo(u.z); a5 = bfhi(u.z); a6 = bflo(u.w); a7 = bfhi(u.w);
    }
    int j = 0;
    for (; j + 16 <= deg; j += 16) {
        unsigned p0 = ep[j + g4];
        unsigned p1 = ep[j + 4 + g4];
        unsigned p2 = ep[j + 8 + g4];
        unsigned p3 = ep[j + 12 + g4];
        uint4 u0 = *(const uint4*)(xrow + (size_t)(p0 >> 3) * 128);
        uint4 u1 = *(const uint4*)(xrow + (size_t)(p1 >> 3) * 128);
        uint4 u2 = *(const uint4*)(xrow + (size_t)(p2 >> 3) * 128);
        uint4 u3 = *(const uint4*)(xrow + (size_t)(p3 >> 3) * 128);
        float w0 = hwl[p0 & 7], w1 = hwl[p1 & 7];
        float w2 = hwl[p2 & 7], w3 = hwl[p3 & 7];
        a0 = fmaf(w0, bflo(u0.x), a0); a1 = fmaf(w0, bfhi(u0.x), a1);
        a2 = fmaf(w0, bflo(u0.y), a2); a3 = fmaf(w0, bfhi(u0.y), a3);
        a4 = fmaf(w0, bflo(u0.z), a4); a5 = fmaf(w0, bfhi(u0.z), a5);
        a6 = fmaf(w0, bflo(u0.w), a6); a7 = fmaf(w0, bfhi(u0.w), a7);
        a0 = fmaf(w1, bflo(u1.x), a0); a1 = fmaf(w1, bfhi(u1.x), a1);
        a2 = fmaf(w1, bflo(u1.y), a2); a3 = fmaf(w1, bfhi(u1.y), a3);
        a4 = fmaf(w1, bflo(u1.z), a4); a5 = fmaf(w1, bfhi(u1.z), a5);
        a6 = fmaf(w1, bflo(u1.w), a6); a7 = fmaf(w1, bfhi(u1.w), a7);
        a0 = fmaf(w2, bflo(u2.x), a0); a1 = fmaf(w2, bfhi(u2.x), a1);
        a2 = fmaf(w2, bflo(u2.y), a2); a3 = fmaf(w2, bfhi(u2.y), a3);
        a4 = fmaf(w2, bflo(u2.z), a4); a5 = fmaf(w2, bfhi(u2.z), a5);
        a6 = fmaf(w2, bflo(u2.w), a6); a7 = fmaf(w2, bfhi(u2.w), a7);
        a0 = fmaf(w3, bflo(u3.x), a0); a1 = fmaf(w3, bfhi(u3.x), a1);
        a2 = fmaf(w3, bflo(u3.y), a2); a3 = fmaf(w3, bfhi(u3.y), a3);
        a4 = fmaf(w3, bflo(u3.z), a4); a5 = fmaf(w3, bfhi(u3.z), a5);
        a6 = fmaf(w3, bflo(u3.w), a6); a7 = fmaf(w3, bfhi(u3.w), a7);
    }
    for (; j + 4 <= deg; j += 4) {
        unsigned p = ep[j + g4];
        uint4 u = *(const uint4*)(xrow + (size_t)(p >> 3) * 128);
        float w = hwl[p & 7];
        a0 = fmaf(w, bflo(u.x), a0); a1 = fmaf(w, bfhi(u.x), a1);
        a2 = fmaf(w, bflo(u.y), a2); a3 = fmaf(w, bfhi(u.y), a3);
        a4 = fmaf(w, bflo(u.z), a4); a5 = fmaf(w, bfhi(u.z), a5);
        a6 = fmaf(w, bflo(u.w), a6); a7 = fmaf(w, bfhi(u.w), a7);
    }
    if (j < deg) {                                     // tail 1..3 edges
        int jj = min(j + g4, deg - 1);
        unsigned p = ep[jj];
        float w = (j + g4 < deg) ? hwl[p & 7] : 0.f;
        uint4 u = *(const uint4*)(xrow + (size_t)(p >> 3) * 128);
        a0 = fmaf(w, bflo(u.x), a0); a1 = fmaf(w, bfhi(u.x), a1);
        a2 = fmaf(w, bflo(u.y), a2); a3 = fmaf(w, bfhi(u.y), a3);
        a4 = fmaf(w, bflo(u.z), a4); a5 = fmaf(w, bfhi(u.z), a5);
        a6 = fmaf(w, bflo(u.w), a6); a7 = fmaf(w, bfhi(u.w), a7);
    }
    a0 += __shfl_xor(a0, 16); a1 += __shfl_xor(a1, 16);
    a2 += __shfl_xor(a2, 16); a3 += __shfl_xor(a3, 16);
    a4 += __shfl_xor(a4, 16); a5 += __shfl_xor(a5, 16);
    a6 += __shfl_xor(a6, 16); a7 += __shfl_xor(a7, 16);
    a0 += __shfl_xor(a0, 32); a1 += __shfl_xor(a1, 32);
    a2 += __shfl_xor(a2, 32); a3 += __shfl_xor(a3, 32);
    a4 += __shfl_xor(a4, 32); a5 += __shfl_xor(a5, 32);
    a6 += __shfl_xor(a6, 32); a7 += __shfl_xor(a7, 32);
    if (g4 == 0) {
        uint4 o;
        o.x = (unsigned int)f2bf(a0) | ((unsigned int)f2bf(a1) << 16);
        o.y = (unsigned int)f2bf(a2) | ((unsigned int)f2bf(a3) << 16);
        o.z = (unsigned int)f2bf(a4) | ((unsigned int)f2bf(a5) << 16);
        o.w = (unsigned int)f2bf(a6) | ((unsigned int)f2bf(a7) << 16);
        *(uint4*)(h + (size_t)wid * 128 + li * 8) = o;
    }
}

// --- fully fused MLP: gemm1 -> BN1+ReLU (regs, LDS bounce) -> gemm2 -> BN2
// Cooperative: 782 blocks <= 256 CU * 4 blocks/CU (LDS 35KB, VGPR<=128).
__global__ __launch_bounds__(256, 4) void mlp_coop_k(
        const unsigned short* __restrict__ Ain,
        const unsigned short* __restrict__ B1h, const unsigned short* __restrict__ B1l,
        const float* __restrict__ bias1, const float* __restrict__ gamma1,
        const float* __restrict__ beta1,
        const unsigned short* __restrict__ B2h, const unsigned short* __restrict__ B2l,
        const float* __restrict__ bias2, const float* __restrict__ gamma2,
        const float* __restrict__ beta2,
        float* __restrict__ sums, float* __restrict__ outp, float invN, int N) {
    __shared__ unsigned short Bs[128 * 136];
    __shared__ float sc[128], sh[128];
    float* sum1 = sums;       float* sq1 = sums + 128;
    float* sum2 = sums + 256; float* sq2 = sums + 384;
    int tid = threadIdx.x;
    int wave = tid >> 6, lane = tid & 63;
    int n16 = lane & 15, q = lane >> 4;
    int rowbase = blockIdx.x * 128 + wave * 32;
    int ldsb = n16 * 136 + q * 8;

    // ---------------- layer 1 GEMM ----------------
    for (int i = tid; i < 2048; i += 256) {            // stage B1_hi
        int n = i >> 4, c = i & 15;
        *(uint4*)&Bs[n * 136 + c * 8] = *(const uint4*)(B1h + n * 128 + c * 8);
    }
    short8 afr[4][2];
#pragma unroll
    for (int kk = 0; kk < 4; kk++)
#pragma unroll
        for (int mt = 0; mt < 2; mt++) {
            int ar = rowbase + mt * 16 + n16;
            ar = min(ar, N - 1);
            afr[kk][mt] = *(const short8*)(Ain + (size_t)ar * 128 + kk * 32 + q * 8);
        }
    f32x4 acc[2][8];
#pragma unroll
    for (int mt = 0; mt < 2; mt++)
#pragma unroll
        for (int t = 0; t < 8; t++) acc[mt][t] = (f32x4){0.f, 0.f, 0.f, 0.f};
    __syncthreads();
#pragma unroll
    for (int kk = 0; kk < 4; kk++)
#pragma unroll
        for (int t = 0; t < 8; t++) {
            short8 b = *(const short8*)&Bs[t * 16 * 136 + ldsb + kk * 32];
            acc[0][t] = __builtin_amdgcn_mfma_f32_16x16x32_bf16(afr[kk][0], b, acc[0][t], 0, 0, 0);
            acc[1][t] = __builtin_amdgcn_mfma_f32_16x16x32_bf16(afr[kk][1], b, acc[1][t], 0, 0, 0);
        }
    __syncthreads();
    for (int i = tid; i < 2048; i += 256) {            // stage B1_lo
        int n = i >> 4, c = i & 15;
        *(uint4*)&Bs[n * 136 + c * 8] = *(const uint4*)(B1l + n * 128 + c * 8);
    }
    __syncthreads();
#pragma unroll
    for (int kk = 0; kk < 4; kk++)
#pragma unroll
        for (int t = 0; t < 8; t++) {
            short8 b = *(const short8*)&Bs[t * 16 * 136 + ldsb + kk * 32];
            acc[0][t] = __builtin_amdgcn_mfma_f32_16x16x32_bf16(afr[kk][0], b, acc[0][t], 0, 0, 0);
            acc[1][t] = __builtin_amdgcn_mfma_f32_16x16x32_bf16(afr[kk][1], b, acc[1][t], 0, 0, 0);
        }
    // epilogue 1: bias into acc (acc := z1, f32), column stats
    {
        float csum[8], csq[8];
#pragma unroll
        for (int t = 0; t < 8; t++) { csum[t] = 0.f; csq[t] = 0.f; }
#pragma unroll
        for (int t = 0; t < 8; t++) {
            int col = n16 + 16 * t;
            float bv = bias1[col];
#pragma unroll
            for (int mt = 0; mt < 2; mt++)
#pragma unroll
                for (int r = 0; r < 4; r++) {
                    float v = acc[mt][t][r] + bv;
                    acc[mt][t][r] = v;
                    int row = rowbase + mt * 16 + q * 4 + r;
                    if (row < N) { csum[t] += v; csq[t] += v * v; }
                }
        }
#pragma unroll
        for (int t = 0; t < 8; t++) {
            csum[t] += __shfl_xor(csum[t], 16);
            csum[t] += __shfl_xor(csum[t], 32);
            csq[t] += __shfl_xor(csq[t], 16);
            csq[t] += __shfl_xor(csq[t], 32);
        }
        __syncthreads();
        float* red = (float*)Bs;
        if (q == 0) {
#pragma unroll
            for (int t = 0; t < 8; t++) {
                int col = n16 + 16 * t;
                red[wave * 128 + col] = csum[t];
                red[512 + wave * 128 + col] = csq[t];
            }
        }
        __syncthreads();
        if (tid < 128) {
            float s = 0.f, qq = 0.f;
#pragma unroll
            for (int w = 0; w < 4; w++) {
                s += red[w * 128 + tid];
                qq += red[512 + w * 128 + tid];
            }
            atomicAdd(&sum1[tid], s);
            atomicAdd(&sq1[tid], qq);
        }
    }
    cooperative_groups::this_grid().sync();

    // -------- BN1+ReLU in regs, bounce through LDS into A-frag layout ------
    if (tid < 128) {
        float s_ = atomicAdd(&sum1[tid], 0.f);         // coherent cross-XCD read
        float qq_ = atomicAdd(&sq1[tid], 0.f);
        float mean = s_ * invN;
        float var = fmaxf(qq_ * invN - mean * mean, 0.f);
        float s = gamma1[tid] * rsqrtf(var + 1e-5f);
        sc[tid] = s;
        sh[tid] = beta1[tid] - mean * s;
    }
    __syncthreads();
#pragma unroll
    for (int t = 0; t < 8; t++) {
        int col = n16 + 16 * t;
#pragma unroll
        for (int mt = 0; mt < 2; mt++)
#pragma unroll
            for (int r = 0; r < 4; r++) {
                int lr = wave * 32 + mt * 16 + q * 4 + r;
                float bn = fmaxf(fmaf(acc[mt][t][r], sc[col], sh[col]), 0.f);
                Bs[lr * 136 + col] = f2bf(bn);
            }
    }
    __syncthreads();
#pragma unroll
    for (int kk = 0; kk < 4; kk++)
#pragma unroll
        for (int mt = 0; mt < 2; mt++) {
            int lr = wave * 32 + mt * 16 + n16;
            afr[kk][mt] = *(const short8*)&Bs[lr * 136 + kk * 32 + q * 8];
        }
    __syncthreads();

    // ---------------- layer 2 GEMM ----------------
    for (int i = tid; i < 2048; i += 256) {            // stage B2_hi
        int n = i >> 4, c = i & 15;
        *(uint4*)&Bs[n * 136 + c * 8] = *(const uint4*)(B2h + n * 128 + c * 8);
    }
#pragma unroll
    for (int mt = 0; mt < 2; mt++)
#pragma unroll
        for (int t = 0; t < 8; t++) acc[mt][t] = (f32x4){0.f, 0.f, 0.f, 0.f};
    __syncthreads();
#pragma unroll
    for (int kk = 0; kk < 4; kk++)
#pragma unroll
        for (int t = 0; t < 8; t++) {
            short8 b = *(const short8*)&Bs[t * 16 * 136 + ldsb + kk * 32];
            acc[0][t] = __builtin_amdgcn_mfma_f32_16x16x32_bf16(afr[kk][0], b, acc[0][t], 0, 0, 0);
            acc[1][t] = __builtin_amdgcn_mfma_f32_16x16x32_bf16(afr[kk][1], b, acc[1][t], 0, 0, 0);
        }
    __syncthreads();
    for (int i = tid; i < 2048; i += 256) {            // stage B2_lo
        int n = i >> 4, c = i & 15;
        *(uint4*)&Bs[n * 136 + c * 8] = *(const uint4*)(B2l + n * 128 + c * 8);
    }
    __syncthreads();
#pragma unroll
    for (int kk = 0; kk < 4; kk++)
#pragma unroll
        for (int t = 0; t < 8; t++) {
            short8 b = *(const short8*)&Bs[t * 16 * 136 + ldsb + kk * 32];
            acc[0][t] = __builtin_amdgcn_mfma_f32_16x16x32_bf16(afr[kk][0], b, acc[0][t], 0, 0, 0);
            acc[1][t] = __builtin_amdgcn_mfma_f32_16x16x32_bf16(afr[kk][1], b, acc[1][t], 0, 0, 0);
        }
    // epilogue 2: bias into acc (acc := z2), column stats
    {
        float csum[8], csq[8];
#pragma unroll
        for (int t = 0; t < 8; t++) { csum[t] = 0.f; csq[t] = 0.f; }
#pragma unroll
        for (int t = 0; t < 8; t++) {
            int col = n16 + 16 * t;
            float bv = bias2[col];
#pragma unroll
            for (int mt = 0; mt < 2; mt++)
#pragma unroll
                for (int r = 0; r < 4; r++) {
                    float v = acc[mt][t][r] + bv;
                    acc[mt][t][r] = v;
                    int row = rowbase + mt * 16 + q * 4 + r;
                    if (row < N) { csum[t] += v; csq[t] += v * v; }
                }
        }
#pragma unroll
        for (int t = 0; t < 8; t++) {
            csum[t] += __shfl_xor(csum[t], 16);
            csum[t] += __shfl_xor(csum[t], 32);
            csq[t] += __shfl_xor(csq[t], 16);
            csq[t] += __shfl_xor(csq[t], 32);
        }
        __syncthreads();
        float* red = (float*)Bs;
        if (q == 0) {
#pragma unroll
            for (int t = 0; t < 8; t++) {
                int col = n16 + 16 * t;
                red[wave * 128 + col] = csum[t];
                red[512 + wave * 128 + col] = csq[t];
            }
        }
        __syncthreads();
        if (tid < 128) {
            float s = 0.f, qq = 0.f;
#pragma unroll
            for (int w = 0; w < 4; w++) {
                s += red[w * 128 + tid];
                qq += red[512 + w * 128 + tid];
            }
            atomicAdd(&sum2[tid], s);
            atomicAdd(&sq2[tid], qq);
        }
    }
    cooperative_groups::this_grid().sync();

    // -------- BN2+ReLU, direct f32 output --------
    if (tid < 128) {
        float s_ = atomicAdd(&sum2[tid], 0.f);
        float qq_ = atomicAdd(&sq2[tid], 0.f);
        float mean = s_ * invN;
        float var = fmaxf(qq_ * invN - mean * mean, 0.f);
        float s = gamma2[tid] * rsqrtf(var + 1e-5f);
        sc[tid] = s;
        sh[tid] = beta2[tid] - mean * s;
    }
    __syncthreads();
#pragma unroll
    for (int t = 0; t < 8; t++) {
        int col = n16 + 16 * t;
#pragma unroll
        for (int mt = 0; mt < 2; mt++)
#pragma unroll
            for (int r = 0; r < 4; r++) {
                int row = rowbase + mt * 16 + q * 4 + r;
                if (row < N)
                    outp[(size_t)row * 128 + col] =
                        fmaxf(fmaf(acc[mt][t][r], sc[col], sh[col]), 0.f);
            }
    }
}

// ---- legacy fallback MLP path (used only if cooperative launch fails) -----
__global__ __launch_bounds__(256, 4) void gemm_mfma_k(
        const unsigned short* __restrict__ Ain,
        const unsigned short* __restrict__ Bhg, const unsigned short* __restrict__ Blg,
        const float* __restrict__ bias, unsigned short* __restrict__ zout,
        float* __restrict__ sum_out, float* __restrict__ sq_out, int N) {
    __shared__ unsigned short Bs[128 * 136];
    int tid = threadIdx.x;
    int wave = tid >> 6, lane = tid & 63;
    int n16 = lane & 15, q = lane >> 4;
    int rowbase = blockIdx.x * 128 + wave * 32;
    for (int i = tid; i < 2048; i += 256) {
        int n = i >> 4, c = i & 15;
        *(uint4*)&Bs[n * 136 + c * 8] = *(const uint4*)(Bhg + n * 128 + c * 8);
    }
    short8 afr[4][2];
#pragma unroll
    for (int kk = 0; kk < 4; kk++)
#pragma unroll
        for (int mt = 0; mt < 2; mt++) {
            int ar = rowbase + mt * 16 + n16;
            ar = min(ar, N - 1);
            afr[kk][mt] = *(const short8*)(Ain + (size_t)ar * 128 + kk * 32 + q * 8);
        }
    f32x4 acc[2][8];
#pragma unroll
    for (int mt = 0; mt < 2; mt++)
#pragma unroll
        for (int t = 0; t < 8; t++) acc[mt][t] = (f32x4){0.f, 0.f, 0.f, 0.f};
    __syncthreads();
    int ldsb = n16 * 136 + q * 8;
#pragma unroll
    for (int kk = 0; kk < 4; kk++)
#pragma unroll
        for (int t = 0; t < 8; t++) {
            short8 b = *(const short8*)&Bs[t * 16 * 136 + ldsb + kk * 32];
            acc[0][t] = __builtin_amdgcn_mfma_f32_16x16x32_bf16(afr[kk][0], b, acc[0][t], 0, 0, 0);
            acc[1][t] = __builtin_amdgcn_mfma_f32_16x16x32_bf16(afr[kk][1], b, acc[1][t], 0, 0, 0);
        }
    __syncthreads();
    for (int i = tid; i < 2048; i += 256) {
        int n = i >> 4, c = i & 15;
        *(uint4*)&Bs[n * 136 + c * 8] = *(const uint4*)(Blg + n * 128 + c * 8);
    }
    __syncthreads();
#pragma unroll
    for (int kk = 0; kk < 4; kk++)
#pragma unroll
        for (int t = 0; t < 8; t++) {
            short8 b = *(const short8*)&Bs[t * 16 * 136 + ldsb + kk * 32];
            acc[0][t] = __builtin_amdgcn_mfma_f32_16x16x32_bf16(afr[kk][0], b, acc[0][t], 0, 0, 0);
            acc[1][t] = __builtin_amdgcn_mfma_f32_16x16x32_bf16(afr[kk][1], b, acc[1][t], 0, 0, 0);
        }
    float csum[8], csq[8];
#pragma unroll
    for (int t = 0; t < 8; t++) { csum[t] = 0.f; csq[t] = 0.f; }
#pragma unroll
    for (int t = 0; t < 8; t++) {
        int col = n16 + 16 * t;
        float bv = bias[col];
#pragma unroll
        for (int mt = 0; mt < 2; mt++) {
#pragma unroll
            for (int r = 0; r < 4; r++) {
                int row = rowbase + mt * 16 + q * 4 + r;
                if (row < N) {
                    float v = acc[mt][t][r] + bv;
                    zout[(size_t)row * 128 + col] = f2bf(v);
                    csum[t] += v;
                    csq[t] += v * v;
                }
            }
        }
    }
#pragma unroll
    for (int t = 0; t < 8; t++) {
        csum[t] += __shfl_xor(csum[t], 16);
        csum[t] += __shfl_xor(csum[t], 32);
        csq[t] += __shfl_xor(csq[t], 16);
        csq[t] += __shfl_xor(csq[t], 32);
    }
    __syncthreads();
    float* red = (float*)Bs;
    if (q == 0) {
#pragma unroll
        for (int t = 0; t < 8; t++) {
            int col = n16 + 16 * t;
            red[wave * 128 + col] = csum[t];
            red[512 + wave * 128 + col] = csq[t];
        }
    }
    __syncthreads();
    if (tid < 128) {
        float s = 0.f, qq = 0.f;
#pragma unroll
        for (int w = 0; w < 4; w++) {
            s += red[w * 128 + tid];
            qq += red[512 + w * 128 + tid];
        }
        unsafeAtomicAdd(&sum_out[tid], s);
        unsafeAtomicAdd(&sq_out[tid], qq);
    }
}

__global__ __launch_bounds__(256, 4) void gemm_mfma_bn_k(
        const unsigned short* __restrict__ Zin,
        const float* __restrict__ sum_in, const float* __restrict__ sq_in,
        const float* __restrict__ gamma, const float* __restrict__ beta,
        float invN,
        const unsigned short* __restrict__ Bhg, const unsigned short* __restrict__ Blg,
        const float* __restrict__ bias, unsigned short* __restrict__ zout,
        float* __restrict__ sum_out, float* __restrict__ sq_out, int N) {
    __shared__ unsigned short Bs[128 * 136];
    __shared__ float sc[128], sh[128];
    int tid = threadIdx.x;
    int wave = tid >> 6, lane = tid & 63;
    int n16 = lane & 15, q = lane >> 4;
    int rowbase = blockIdx.x * 128 + wave * 32;
    for (int i = tid; i < 2048; i += 256) {
        int n = i >> 4, c = i & 15;
        *(uint4*)&Bs[n * 136 + c * 8] = *(const uint4*)(Bhg + n * 128 + c * 8);
    }
    if (tid < 128) {
        float mean = sum_in[tid] * invN;
        float var = fmaxf(sq_in[tid] * invN - mean * mean, 0.f);
        float s = gamma[tid] * rsqrtf(var + 1e-5f);
        sc[tid] = s;
        sh[tid] = beta[tid] - mean * s;
    }
    __syncthreads();
    short8 afr[4][2];
#pragma unroll
    for (int kk = 0; kk < 4; kk++)
#pragma unroll
        for (int mt = 0; mt < 2; mt++) {
            int ar = rowbase + mt * 16 + n16;
            ar = min(ar, N - 1);
            short8 raw = *(const short8*)(Zin + (size_t)ar * 128 + kk * 32 + q * 8);
            short8 outv;
#pragma unroll
            for (int i = 0; i < 8; i++) {
                int col = kk * 32 + q * 8 + i;
                float f = bf2f((unsigned short)raw[i]);
                float v = fmaxf(fmaf(f, sc[col], sh[col]), 0.f);
                outv[i] = (short)f2bf(v);
            }
            afr[kk][mt] = outv;
        }
    f32x4 acc[2][8];
#pragma unroll
    for (int mt = 0; mt < 2; mt++)
#pragma unroll
        for (int t = 0; t < 8; t++) acc[mt][t] = (f32x4){0.f, 0.f, 0.f, 0.f};
    int ldsb = n16 * 136 + q * 8;
#pragma unroll
    for (int kk = 0; kk < 4; kk++)
#pragma unroll
        for (int t = 0; t < 8; t++) {
            short8 b = *(const short8*)&Bs[t * 16 * 136 + ldsb + kk * 32];
            acc[0][t] = __builtin_amdgcn_mfma_f32_16x16x32_bf16(afr[kk][0], b, acc[0][t], 0, 0, 0);
            acc[1][t] = __builtin_amdgcn_mfma_f32_16x16x32_bf16(afr[kk][1], b, acc[1][t], 0, 0, 0);
        }
    __syncthreads();
    for (int i = tid; i < 2048; i += 256) {
        int n = i >> 4, c = i & 15;
        *(uint4*)&Bs[n * 136 + c * 8] = *(const uint4*)(Blg + n * 128 + c * 8);
    }
    __syncthreads();
#pragma unroll
    for (int kk = 0; kk < 4; kk++)
#pragma unroll
        for (int t = 0; t < 8; t++) {
            short8 b = *(const short8*)&Bs[t * 16 * 136 + ldsb + kk * 32];
            acc[0][t] = __builtin_amdgcn_mfma_f32_16x16x32_bf16(afr[kk][0], b, acc[0][t], 0, 0, 0);
            acc[1][t] = __builtin_amdgcn_mfma_f32_16x16x32_bf16(afr[kk][1], b, acc[1][t], 0, 0, 0);
        }
    float csum[8], csq[8];
#pragma unroll
    for (int t = 0; t < 8; t++) { csum[t] = 0.f; csq[t] = 0.f; }
#pragma unroll
    for (int t = 0; t < 8; t++) {
        int col = n16 + 16 * t;
        float bv = bias[col];
#pragma unroll
        for (int mt = 0; mt < 2; mt++) {
#pragma unroll
            for (int r = 0; r < 4; r++) {
                int row = rowbase + mt * 16 + q * 4 + r;
                if (row < N) {
                    float v = acc[mt][t][r] + bv;
                    zout[(size_t)row * 128 + col] = f2bf(v);
                    csum[t] += v;
                    csq[t] += v * v;
                }
            }
        }
    }
#pragma unroll
    for (int t = 0; t < 8; t++) {
        csum[t] += __shfl_xor(csum[t], 16);
        csum[t] += __shfl_xor(csum[t], 32);
        csq[t] += __shfl_xor(csq[t], 16);
        csq[t] += __shfl_xor(csq[t], 32);
    }
    __syncthreads();
    float* red = (float*)Bs;
    if (q == 0) {
#pragma unroll
        for (int t = 0; t < 8; t++) {
            int col = n16 + 16 * t;
            red[wave * 128 + col] = csum[t];
            red[512 + wave * 128 + col] = csq[t];
        }
    }
    __syncthreads();
    if (tid < 128) {
        float s = 0.f, qq = 0.f;
#pragma unroll
        for (int w = 0; w < 4; w++) {
            s += red[w * 128 + tid];
            qq += red[512 + w * 128 + tid];
        }
        unsafeAtomicAdd(&sum_out[tid], s);
        unsafeAtomicAdd(&sq_out[tid], qq);
    }
}

__global__ __launch_bounds__(256) void bn2_k(const unsigned short* __restrict__ z2,
        const float* __restrict__ sum2, const float* __restrict__ sq2,
        const float* __restrict__ gamma, const float* __restrict__ beta,
        float* __restrict__ out, long long n8, float invN) {
    __shared__ float sc[128], sh[128];
    int tid = threadIdx.x;
    if (tid < 128) {
        float mean = sum2[tid] * invN;
        float var = fmaxf(sq2[tid] * invN - mean * mean, 0.f);
        float s = gamma[tid] * rsqrtf(var + 1e-5f);
        sc[tid] = s;
        sh[tid] = beta[tid] - mean * s;
    }
    __syncthreads();
    long long g = (long long)blockIdx.x * 256 + tid;
    if (g >= n8) return;
    uint4 u = ((const uint4*)z2)[g];
    int cb = (int)((g * 8) & 127);
    float4 s0 = *(const float4*)&sc[cb], s1 = *(const float4*)&sc[cb + 4];
    float4 t0 = *(const float4*)&sh[cb], t1 = *(const float4*)&sh[cb + 4];
    float4 o0, o1;
    o0.x = fmaxf(fmaf(bflo(u.x), s0.x, t0.x), 0.f);
    o0.y = fmaxf(fmaf(bfhi(u.x), s0.y, t0.y), 0.f);
    o0.z = fmaxf(fmaf(bflo(u.y), s0.z, t0.z), 0.f);
    o0.w = fmaxf(fmaf(bfhi(u.y), s0.w, t0.w), 0.f);
    o1.x = fmaxf(fmaf(bflo(u.z), s1.x, t1.x), 0.f);
    o1.y = fmaxf(fmaf(bfhi(u.z), s1.y, t1.y), 0.f);
    o1.z = fmaxf(fmaf(bflo(u.w), s1.z, t1.z), 0.f);
    o1.w = fmaxf(fmaf(bfhi(u.w), s1.w, t1.w), 0.f);
    ((float4*)out)[g * 2] = o0;
    ((float4*)out)[g * 2 + 1] = o1;
}

extern "C" void kernel_launch(void* const* d_in, const int* in_sizes, int n_in,
                              void* d_out, int out_size, void* d_ws, size_t ws_size,
                              hipStream_t stream) {
    const float* x   = (const float*)d_in[0];
    const int*   ei  = (const int*)d_in[1];
    const int*   ew  = (const int*)d_in[2];
    const float* hc  = (const float*)d_in[3];
    const float* W1  = (const float*)d_in[4];
    const float* b1  = (const float*)d_in[5];
    const float* g1  = (const float*)d_in[6];
    const float* be1 = (const float*)d_in[7];
    const float* W2  = (const float*)d_in[8];
    const float* b2  = (const float*)d_in[9];
    const float* g2  = (const float*)d_in[10];
    const float* be2 = (const float*)d_in[11];

    int N = in_sizes[0] / 128;
    int E = in_sizes[2];
    int K = in_sizes[3];
    size_t NF = (size_t)N * 128;
    long long n8 = (long long)(NF / 8);
    int NX = (int)((n8 + 255) / 256);

    unsigned short* h = (unsigned short*)d_ws;          // NF ush
    unsigned short* xb = h + NF;                        // NF ush
    unsigned short* z1 = xb;                            // fallback alias
    unsigned short* z2 = h;                             // fallback alias
    unsigned* staging = (unsigned*)(xb + NF);           // N * RCAP u32
    int* cur = (int*)(staging + (size_t)N * RCAP);      // N
    unsigned short* w1h = (unsigned short*)(cur + N);
    unsigned short* w1l = w1h + 16384;
    unsigned short* w2h = w1l + 16384;
    unsigned short* w2l = w2h + 16384;
    float* hwp = (float*)(w2l + 16384);                 // 8
    float* sums = hwp + 8;                              // 512
    float* sum1 = sums, *sq1 = sums + 128, *sum2 = sums + 256, *sq2 = sums + 384;
    int nbuk  = (N + 1023) >> 10;
    int nbukp = (nbuk + 7) & ~7;                        // %8 == 0 for XCD mapping
    int* C = (int*)(sums + 512);                        // nbukp * P2B (transposed)
    int* tot = C + (size_t)nbukp * P2B;                 // nbukp
    unsigned* bucketed = (unsigned*)(tot + nbukp);      // E records
    size_t ws_need = (size_t)((char*)(bucketed + E) - (char*)d_ws);
    bool use_bucketed = (nbukp <= 128) && (N <= (1 << 17)) && (K <= 7)
                        && (ws_need <= ws_size);

    float invN = 1.0f / (float)N;
    int per = (E + P2B - 1) / P2B;

    int prep_grid = use_bucketed ? (3 + NX + P2B) : (3 + NX);
    if (!use_bucketed)
        hipMemsetAsync(cur, 0, (size_t)N * sizeof(int), stream);
    prep_k<<<prep_grid, 256, 0, stream>>>(hc, hwp, sums, W1, W2,
        w1h, w1l, w2h, w2l, (const float4*)x, (uint4*)xb, K, n8,
        ei, C, cur, E, per, nbukp, N, NX);
    if (use_bucketed) {
        scan1_k<<<nbukp, 256, 0, stream>>>(C, tot, nbukp, P2B);
        scatter_k<<<P2B, 256, 0, stream>>>(ei, ei + E, ew, C, tot, bucketed,
                                           E, per, nbukp, K);
        slot3_k<<<nbukp * BPB, 256, 0, stream>>>(bucketed, tot, cur, staging, nbukp);
    } else {
        slot_k<<<(E + 255) / 256, 256, 0, stream>>>(ei, ei + E, ew, cur, staging, E, K);
    }
    {
        long long tot_thr = (long long)N * 64;
        gather_k<<<(int)((tot_thr + 255) / 256), 256, 0, stream>>>(
            xb, staging, cur, hwp, h, N);
    }
    int gblocks = (N + 127) / 128;
    float* outf = (float*)d_out;
    hipError_t ce = hipErrorUnknown;
    if (gblocks <= 1024) {                              // co-residency capacity
        void* args[] = { (void*)&h, (void*)&w1h, (void*)&w1l,
                         (void*)&b1, (void*)&g1, (void*)&be1,
                         (void*)&w2h, (void*)&w2l,
                         (void*)&b2, (void*)&g2, (void*)&be2,
                         (void*)&sums, (void*)&outf, (void*)&invN, (void*)&N };
        ce = hipLaunchCooperativeKernel((const void*)mlp_coop_k,
                 dim3(gblocks), dim3(256), args, 0, stream);
    }
    if (ce != hipSuccess) {                             // legacy fallback path
        gemm_mfma_k<<<gblocks, 256, 0, stream>>>(h, w1h, w1l, b1, z1, sum1, sq1, N);
        gemm_mfma_bn_k<<<gblocks, 256, 0, stream>>>(z1, sum1, sq1, g1, be1, invN,
            w2h, w2l, b2, z2, sum2, sq2, N);
        bn2_k<<<NX, 256, 0, stream>>>(z2, sum2, sq2, g2, be2, outf, n8, invN);
    }
}

// Round 7
// 516.997 us; speedup vs baseline: 1.0861x; 1.0861x over previous
//
#include <hip/hip_runtime.h>
#include <hip/hip_bf16.h>
#include <hip/hip_cooperative_groups.h>

// ---------------------------------------------------------------------------
// SPN layer (R15): prep{softmax||Wsplit||x->bf16||count||zero-cur} -> scan1 ->
// scatter(+inline bucket-base scan) -> slot3(+inline scan) -> gather ->
// mlp_coop (gemm1 -> stats -> grid.sync -> BN1+ReLU regs -> gemm2 -> stats ->
// grid.sync -> BN2+ReLU -> f32 out).
// R14's coop was 230us with ALL pipes idle: plain float atomicAdd = CAS loop
// under 782-way contention (stats + atomic read-backs). R15: unsafeAtomicAdd
// (HW agent-scope fadd) for accumulation, __hip_atomic_load(AGENT) for the
// post-sync read (XCD-coherent plain load, no RMW serialization).
// Fallback: legacy gemm1/gemm2bn/bn2 path if cooperative launch errors.
// ---------------------------------------------------------------------------

#define RCAP 64    // slots per row; P(Poisson(16) > 64) ~ 1e-20 per row
#define P2B 256    // blocks in count/scatter passes
#define BPB 4      // blocks per bucket in slot3

typedef __attribute__((ext_vector_type(8))) short short8;
typedef __attribute__((ext_vector_type(4))) float f32x4;

__device__ inline unsigned short f2bf(float v) {           // RNE bf16 round
    unsigned int u = __float_as_uint(v);
    return (unsigned short)((u + 0x7fffu + ((u >> 16) & 1u)) >> 16);
}
__device__ inline float bf2f(unsigned int u) { return __uint_as_float(u << 16); }
__device__ inline float bflo(unsigned int u) { return __uint_as_float(u << 16); }
__device__ inline float bfhi(unsigned int u) { return __uint_as_float(u & 0xFFFF0000u); }

// --- prep: [0]=softmax+zero stats, [1..2]=W split, [3..3+NX)=x->bf16,
//     [3+NX..3+NX+P2B) = edge-count histogram + zero cur (bucketed path) ----
__global__ __launch_bounds__(256) void prep_k(
        const float* __restrict__ hc, float* __restrict__ hwp, float* __restrict__ sums,
        const float* __restrict__ W1, const float* __restrict__ W2,
        unsigned short* __restrict__ w1h, unsigned short* __restrict__ w1l,
        unsigned short* __restrict__ w2h, unsigned short* __restrict__ w2l,
        const float4* __restrict__ x4, uint4* __restrict__ xb, int K, long long n8,
        const int* __restrict__ rows, int* __restrict__ C, int* __restrict__ cur,
        int E, int per, int nbukp, int N, int NX) {
    __shared__ int hist[128];
    int b = blockIdx.x, tid = threadIdx.x;
    if (b == 0) {                                    // softmax + zero stats
        sums[tid] = 0.f; sums[tid + 256] = 0.f;
        if (tid == 0) {
            float tmp[8];
            float m = -1e30f;
            for (int k = 0; k < K; ++k) m = fmaxf(m, hc[k]);
            float s = 0.f;
            for (int k = 0; k < K; ++k) { float e = __expf(hc[k] - m); tmp[k] = e; s += e; }
            float inv = 1.f / s;
            for (int k = 0; k < 8; ++k) hwp[k] = 0.f;
            for (int k = 0; k < K; ++k) hwp[k + 1] = tmp[k] * inv;
        }
        return;
    }
    if (b <= 2) {                                    // W split (transposed hi/lo)
        const float* W = (b == 2) ? W2 : W1;
        unsigned short* th = (b == 2) ? w2h : w1h;
        unsigned short* tl = (b == 2) ? w2l : w1l;
        for (int i = tid; i < 16384; i += 256) {
            int k = i >> 7, n = i & 127;
            float v = W[k * 128 + n];
            unsigned short hi = f2bf(v);
            th[n * 128 + k] = hi;
            tl[n * 128 + k] = f2bf(v - bf2f(hi));
        }
        return;
    }
    if (b < 3 + NX) {                                // x -> bf16
        long long g = (long long)(b - 3) * 256 + tid;
        if (g >= n8) return;
        float4 a = x4[g * 2], c = x4[g * 2 + 1];
        union { unsigned short us[8]; uint4 v; } o;
        o.us[0] = f2bf(a.x); o.us[1] = f2bf(a.y); o.us[2] = f2bf(a.z); o.us[3] = f2bf(a.w);
        o.us[4] = f2bf(c.x); o.us[5] = f2bf(c.y); o.us[6] = f2bf(c.z); o.us[7] = f2bf(c.w);
        xb[g] = o.v;
        return;
    }
    // count role (only launched when bucketed): histogram of row>>10 + zero cur
    int cblk = b - 3 - NX;
    for (int i = tid; i < nbukp; i += 256) hist[i] = 0;
    __syncthreads();
    int e0 = cblk * per, e1 = min(E, e0 + per);
    for (int e = e0 + tid; e < e1; e += 256)
        atomicAdd(&hist[rows[e] >> 10], 1);
    __syncthreads();
    for (int i = tid; i < nbukp; i += 256) C[i * P2B + cblk] = hist[i];
    int zper = (N + P2B - 1) / P2B;
    int z0 = cblk * zper, z1 = min(N, z0 + zper);
    for (int i = z0 + tid; i < z1; i += 256) cur[i] = 0;
}

// P2a: block b scans bucket-b's row of C (coalesced; Hillis-Steele in LDS);
// C becomes within-bucket exclusive prefix; tot[b] = bucket total.
__global__ __launch_bounds__(256) void scan1_k(int* __restrict__ C,
        int* __restrict__ tot, int nbukp, int nblk) {
    __shared__ int buf[256];
    int b = blockIdx.x, tid = threadIdx.x;
    int v = (tid < nblk) ? C[b * P2B + tid] : 0;
    buf[tid] = v;
    __syncthreads();
#pragma unroll
    for (int off = 1; off < 256; off <<= 1) {
        int t = (tid >= off) ? buf[tid - off] : 0;
        __syncthreads();
        buf[tid] += t;
        __syncthreads();
    }
    if (tid < nblk) C[b * P2B + tid] = buf[tid] - v;     // exclusive
    if (tid == 255) tot[b] = buf[255];
}

// P2b: bucket-grouped 4B records: d | col<<3 | (row&1023)<<20
// bucket bases derived inline from tot[] (scan2 folded into prologue)
__global__ __launch_bounds__(256) void scatter_k(const int* __restrict__ rows,
        const int* __restrict__ cols, const int* __restrict__ ew,
        const int* __restrict__ O, const int* __restrict__ tot,
        unsigned* __restrict__ bucketed, int E, int per, int nbukp, int K) {
    __shared__ int buf[128];
    __shared__ unsigned curs[128];
    int blk = blockIdx.x, tid = threadIdx.x;
    int v = (tid < 128 && tid < nbukp) ? tot[tid] : 0;
    if (tid < 128) buf[tid] = v;
    __syncthreads();
#pragma unroll
    for (int off = 1; off < 128; off <<= 1) {
        int t = (tid >= off && tid < 128) ? buf[tid - off] : 0;
        __syncthreads();
        if (tid < 128) buf[tid] += t;
        __syncthreads();
    }
    if (tid < nbukp)
        curs[tid] = (unsigned)(O[tid * P2B + blk] + buf[tid] - v);  // excl base
    __syncthreads();
    int e0 = blk * per, e1 = min(E, e0 + per);
    for (int e = e0 + tid; e < e1; e += 256) {
        int r = rows[e];
        int c = cols[e];
        int d = ew[e];
        if (d < 1 || d > K) d = 0;                   // hwp[0] = 0 -> weight 0
        unsigned idx = atomicAdd(&curs[r >> 10], 1u);
        bucketed[idx] = (unsigned)d | ((unsigned)c << 3) | ((unsigned)(r & 1023) << 20);
    }
}

// P3: ticket + 4B staging scatter, one 1024-row bucket per BPB-block group.
// blockIdx % nbukp keeps a bucket's blocks on one XCD (nbukp % 8 == 0).
__global__ __launch_bounds__(256) void slot3_k(const unsigned* __restrict__ bucketed,
        const int* __restrict__ tot, int* __restrict__ cur,
        unsigned* __restrict__ staging, int nbukp) {
    __shared__ int buf[128];
    int tid = threadIdx.x;
    if (tid < 128) buf[tid] = (tid < nbukp) ? tot[tid] : 0;
    __syncthreads();
#pragma unroll
    for (int off = 1; off < 128; off <<= 1) {
        int t = (tid >= off && tid < 128) ? buf[tid - off] : 0;
        __syncthreads();
        if (tid < 128) buf[tid] += t;
        __syncthreads();
    }
    int bucket = blockIdx.x % nbukp, sub = blockIdx.x / nbukp;
    int s1 = buf[bucket];
    int s0 = s1 - tot[bucket];
    int cnt = s1 - s0;
    int qlo = s0 + (int)((long long)cnt * sub / BPB);
    int qhi = s0 + (int)((long long)cnt * (sub + 1) / BPB);
    int rbase = bucket << 10;
    for (int e = qlo + tid; e < qhi; e += 256) {
        unsigned u = bucketed[e];
        int row = rbase + (int)(u >> 20);
        int s = atomicAdd(&cur[row], 1);
        if (s < RCAP)
            staging[((size_t)row << 6) + s] = u & 0xFFFFFu;
    }
}

// legacy single-pass slot (fallback: N/K out of packing range or ws too small)
__global__ __launch_bounds__(256) void slot_k(const int* __restrict__ rows,
        const int* __restrict__ cols, const int* __restrict__ ew,
        int* __restrict__ cur, unsigned* __restrict__ staging, int E, int K) {
    int e = blockIdx.x * 256 + threadIdx.x;
    if (e >= E) return;
    int r = rows[e];
    int d = ew[e];
    if (d < 1 || d > K) d = 0;
    int s = atomicAdd(&cur[r], 1);
    if (s < RCAP)
        staging[((size_t)r << 6) + s] = (unsigned)d | ((unsigned)cols[e] << 3);
}

// one wave per row, 4 edges per wave-step: each 16-lane group loads one full
// 256B row (uint4/lane). 4B payload records; weight via 8-entry LDS table.
__global__ __launch_bounds__(256) void gather_k(
        const unsigned short* __restrict__ xb, const unsigned* __restrict__ staging,
        const int* __restrict__ cur, const float* __restrict__ hwp,
        unsigned short* __restrict__ h, int N) {
    __shared__ float hwl[8];
    int tid = threadIdx.x;
    if (tid < 8) hwl[tid] = hwp[tid];
    __syncthreads();
    int wid = (blockIdx.x * 256 + tid) >> 6;
    if (wid >= N) return;
    int lane = tid & 63;
    int g4 = lane >> 4, li = lane & 15;
    int deg = __builtin_amdgcn_readfirstlane(cur[wid]);
    deg = min(deg, RCAP);
    const unsigned* ep = staging + ((size_t)wid << 6);
    const unsigned short* xrow = xb + li * 8;          // 16B per lane within row
    float a0 = 0.f, a1 = 0.f, a2 = 0.f, a3 = 0.f;
    float a4 = 0.f, a5 = 0.f, a6 = 0.f, a7 = 0.f;
    if (g4 == 0) {                                     // GIN self term (eps=0)
        uint4 u = *(const uint4*)(xb + (size_t)wid * 128 + li * 8);
        a0 = bflo(u.x); a1 = bfhi(u.x); a2 = bflo(u.y); a3 = bfhi(u.y);
        a4 = bflo(u.z); a5 = bfhi(u.z); a6 = bflo(u.w); a7 = bfhi(u.w);
    }
    int j = 0;
    for (; j + 16 <= deg; j += 16) {
        unsigned p0 = ep[j + g4];
        unsigned p1 = ep[j + 4 + g4];
        unsigned p2 = ep[j + 8 + g4];
        unsigned p3 = ep[j + 12 + g4];
        uint4 u0 = *(const uint4*)(xrow + (size_t)(p0 >> 3) * 128);
        uint4 u1 = *(const uint4*)(xrow + (size_t)(p1 >> 3) * 128);
        uint4 u2 = *(const uint4*)(xrow + (size_t)(p2 >> 3) * 128);
        uint4 u3 = *(const uint4*)(xrow + (size_t)(p3 >> 3) * 128);
        float w0 = hwl[p0 & 7], w1 = hwl[p1 & 7];
        float w2 = hwl[p2 & 7], w3 = hwl[p3 & 7];
        a0 = fmaf(w0, bflo(u0.x), a0); a1 = fmaf(w0, bfhi(u0.x), a1);
        a2 = fmaf(w0, bflo(u0.y), a2); a3 = fmaf(w0, bfhi(u0.y), a3);
        a4 = fmaf(w0, bflo(u0.z), a4); a5 = fmaf(w0, bfhi(u0.z), a5);
        a6 = fmaf(w0, bflo(u0.w), a6); a7 = fmaf(w0, bfhi(u0.w), a7);
        a0 = fmaf(w1, bflo(u1.x), a0); a1 = fmaf(w1, bfhi(u1.x), a1);
        a2 = fmaf(w1, bflo(u1.y), a2); a3 = fmaf(w1, bfhi(u1.y), a3);
        a4 = fmaf(w1, bflo(u1.z), a4); a5 = fmaf(w1, bfhi(u1.z), a5);
        a6 = fmaf(w1, bflo(u1.w), a6); a7 = fmaf(w1, bfhi(u1.w), a7);
        a0 = fmaf(w2, bflo(u2.x), a0); a1 = fmaf(w2, bfhi(u2.x), a1);
        a2 = fmaf(w2, bflo(u2.y), a2); a3 = fmaf(w2, bfhi(u2.y), a3);
        a4 = fmaf(w2, bflo(u2.z), a4); a5 = fmaf(w2, bfhi(u2.z), a5);
        a6 = fmaf(w2, bflo(u2.w), a6); a7 = fmaf(w2, bfhi(u2.w), a7);
        a0 = fmaf(w3, bflo(u3.x), a0); a1 = fmaf(w3, bfhi(u3.x), a1);
        a2 = fmaf(w3, bflo(u3.y), a2); a3 = fmaf(w3, bfhi(u3.y), a3);
        a4 = fmaf(w3, bflo(u3.z), a4); a5 = fmaf(w3, bfhi(u3.z), a5);
        a6 = fmaf(w3, bflo(u3.w), a6); a7 = fmaf(w3, bfhi(u3.w), a7);
    }
    for (; j + 4 <= deg; j += 4) {
        unsigned p = ep[j + g4];
        uint4 u = *(const uint4*)(xrow + (size_t)(p >> 3) * 128);
        float w = hwl[p & 7];
        a0 = fmaf(w, bflo(u.x), a0); a1 = fmaf(w, bfhi(u.x), a1);
        a2 = fmaf(w, bflo(u.y), a2); a3 = fmaf(w, bfhi(u.y), a3);
        a4 = fmaf(w, bflo(u.z), a4); a5 = fmaf(w, bfhi(u.z), a5);
        a6 = fmaf(w, bflo(u.w), a6); a7 = fmaf(w, bfhi(u.w), a7);
    }
    if (j < deg) {                                     // tail 1..3 edges
        int jj = min(j + g4, deg - 1);
        unsigned p = ep[jj];
        float w = (j + g4 < deg) ? hwl[p & 7] : 0.f;
        uint4 u = *(const uint4*)(xrow + (size_t)(p >> 3) * 128);
        a0 = fmaf(w, bflo(u.x), a0); a1 = fmaf(w, bfhi(u.x), a1);
        a2 = fmaf(w, bflo(u.y), a2); a3 = fmaf(w, bfhi(u.y), a3);
        a4 = fmaf(w, bflo(u.z), a4); a5 = fmaf(w, bfhi(u.z), a5);
        a6 = fmaf(w, bflo(u.w), a6); a7 = fmaf(w, bfhi(u.w), a7);
    }
    a0 += __shfl_xor(a0, 16); a1 += __shfl_xor(a1, 16);
    a2 += __shfl_xor(a2, 16); a3 += __shfl_xor(a3, 16);
    a4 += __shfl_xor(a4, 16); a5 += __shfl_xor(a5, 16);
    a6 += __shfl_xor(a6, 16); a7 += __shfl_xor(a7, 16);
    a0 += __shfl_xor(a0, 32); a1 += __shfl_xor(a1, 32);
    a2 += __shfl_xor(a2, 32); a3 += __shfl_xor(a3, 32);
    a4 += __shfl_xor(a4, 32); a5 += __shfl_xor(a5, 32);
    a6 += __shfl_xor(a6, 32); a7 += __shfl_xor(a7, 32);
    if (g4 == 0) {
        uint4 o;
        o.x = (unsigned int)f2bf(a0) | ((unsigned int)f2bf(a1) << 16);
        o.y = (unsigned int)f2bf(a2) | ((unsigned int)f2bf(a3) << 16);
        o.z = (unsigned int)f2bf(a4) | ((unsigned int)f2bf(a5) << 16);
        o.w = (unsigned int)f2bf(a6) | ((unsigned int)f2bf(a7) << 16);
        *(uint4*)(h + (size_t)wid * 128 + li * 8) = o;
    }
}

// --- fully fused MLP: gemm1 -> BN1+ReLU (regs, LDS bounce) -> gemm2 -> BN2
// Cooperative: 782 blocks <= 256 CU * 4 blocks/CU (LDS 35KB, VGPR<=128).
// Stats: unsafeAtomicAdd (HW fadd, agent scope); read-back after grid.sync
// via __hip_atomic_load(AGENT) -- XCD-coherent, no CAS/RMW serialization.
__global__ __launch_bounds__(256, 4) void mlp_coop_k(
        const unsigned short* __restrict__ Ain,
        const unsigned short* __restrict__ B1h, const unsigned short* __restrict__ B1l,
        const float* __restrict__ bias1, const float* __restrict__ gamma1,
        const float* __restrict__ beta1,
        const unsigned short* __restrict__ B2h, const unsigned short* __restrict__ B2l,
        const float* __restrict__ bias2, const float* __restrict__ gamma2,
        const float* __restrict__ beta2,
        float* __restrict__ sums, float* __restrict__ outp, float invN, int N) {
    __shared__ unsigned short Bs[128 * 136];
    __shared__ float sc[128], sh[128];
    float* sum1 = sums;       float* sq1 = sums + 128;
    float* sum2 = sums + 256; float* sq2 = sums + 384;
    int tid = threadIdx.x;
    int wave = tid >> 6, lane = tid & 63;
    int n16 = lane & 15, q = lane >> 4;
    int rowbase = blockIdx.x * 128 + wave * 32;
    int ldsb = n16 * 136 + q * 8;

    // ---------------- layer 1 GEMM ----------------
    for (int i = tid; i < 2048; i += 256) {            // stage B1_hi
        int n = i >> 4, c = i & 15;
        *(uint4*)&Bs[n * 136 + c * 8] = *(const uint4*)(B1h + n * 128 + c * 8);
    }
    short8 afr[4][2];
#pragma unroll
    for (int kk = 0; kk < 4; kk++)
#pragma unroll
        for (int mt = 0; mt < 2; mt++) {
            int ar = rowbase + mt * 16 + n16;
            ar = min(ar, N - 1);
            afr[kk][mt] = *(const short8*)(Ain + (size_t)ar * 128 + kk * 32 + q * 8);
        }
    f32x4 acc[2][8];
#pragma unroll
    for (int mt = 0; mt < 2; mt++)
#pragma unroll
        for (int t = 0; t < 8; t++) acc[mt][t] = (f32x4){0.f, 0.f, 0.f, 0.f};
    __syncthreads();
#pragma unroll
    for (int kk = 0; kk < 4; kk++)
#pragma unroll
        for (int t = 0; t < 8; t++) {
            short8 b = *(const short8*)&Bs[t * 16 * 136 + ldsb + kk * 32];
            acc[0][t] = __builtin_amdgcn_mfma_f32_16x16x32_bf16(afr[kk][0], b, acc[0][t], 0, 0, 0);
            acc[1][t] = __builtin_amdgcn_mfma_f32_16x16x32_bf16(afr[kk][1], b, acc[1][t], 0, 0, 0);
        }
    __syncthreads();
    for (int i = tid; i < 2048; i += 256) {            // stage B1_lo
        int n = i >> 4, c = i & 15;
        *(uint4*)&Bs[n * 136 + c * 8] = *(const uint4*)(B1l + n * 128 + c * 8);
    }
    __syncthreads();
#pragma unroll
    for (int kk = 0; kk < 4; kk++)
#pragma unroll
        for (int t = 0; t < 8; t++) {
            short8 b = *(const short8*)&Bs[t * 16 * 136 + ldsb + kk * 32];
            acc[0][t] = __builtin_amdgcn_mfma_f32_16x16x32_bf16(afr[kk][0], b, acc[0][t], 0, 0, 0);
            acc[1][t] = __builtin_amdgcn_mfma_f32_16x16x32_bf16(afr[kk][1], b, acc[1][t], 0, 0, 0);
        }
    // epilogue 1: bias into acc (acc := z1, f32), column stats
    {
        float csum[8], csq[8];
#pragma unroll
        for (int t = 0; t < 8; t++) { csum[t] = 0.f; csq[t] = 0.f; }
#pragma unroll
        for (int t = 0; t < 8; t++) {
            int col = n16 + 16 * t;
            float bv = bias1[col];
#pragma unroll
            for (int mt = 0; mt < 2; mt++)
#pragma unroll
                for (int r = 0; r < 4; r++) {
                    float v = acc[mt][t][r] + bv;
                    acc[mt][t][r] = v;
                    int row = rowbase + mt * 16 + q * 4 + r;
                    if (row < N) { csum[t] += v; csq[t] += v * v; }
                }
        }
#pragma unroll
        for (int t = 0; t < 8; t++) {
            csum[t] += __shfl_xor(csum[t], 16);
            csum[t] += __shfl_xor(csum[t], 32);
            csq[t] += __shfl_xor(csq[t], 16);
            csq[t] += __shfl_xor(csq[t], 32);
        }
        __syncthreads();
        float* red = (float*)Bs;
        if (q == 0) {
#pragma unroll
            for (int t = 0; t < 8; t++) {
                int col = n16 + 16 * t;
                red[wave * 128 + col] = csum[t];
                red[512 + wave * 128 + col] = csq[t];
            }
        }
        __syncthreads();
        if (tid < 128) {
            float s = 0.f, qq = 0.f;
#pragma unroll
            for (int w = 0; w < 4; w++) {
                s += red[w * 128 + tid];
                qq += red[512 + w * 128 + tid];
            }
            unsafeAtomicAdd(&sum1[tid], s);
            unsafeAtomicAdd(&sq1[tid], qq);
        }
    }
    cooperative_groups::this_grid().sync();

    // -------- BN1+ReLU in regs, bounce through LDS into A-frag layout ------
    if (tid < 128) {
        float s_ = __hip_atomic_load(&sum1[tid], __ATOMIC_RELAXED,
                                     __HIP_MEMORY_SCOPE_AGENT);
        float qq_ = __hip_atomic_load(&sq1[tid], __ATOMIC_RELAXED,
                                      __HIP_MEMORY_SCOPE_AGENT);
        float mean = s_ * invN;
        float var = fmaxf(qq_ * invN - mean * mean, 0.f);
        float s = gamma1[tid] * rsqrtf(var + 1e-5f);
        sc[tid] = s;
        sh[tid] = beta1[tid] - mean * s;
    }
    __syncthreads();
#pragma unroll
    for (int t = 0; t < 8; t++) {
        int col = n16 + 16 * t;
#pragma unroll
        for (int mt = 0; mt < 2; mt++)
#pragma unroll
            for (int r = 0; r < 4; r++) {
                int lr = wave * 32 + mt * 16 + q * 4 + r;
                float bn = fmaxf(fmaf(acc[mt][t][r], sc[col], sh[col]), 0.f);
                Bs[lr * 136 + col] = f2bf(bn);
            }
    }
    __syncthreads();
#pragma unroll
    for (int kk = 0; kk < 4; kk++)
#pragma unroll
        for (int mt = 0; mt < 2; mt++) {
            int lr = wave * 32 + mt * 16 + n16;
            afr[kk][mt] = *(const short8*)&Bs[lr * 136 + kk * 32 + q * 8];
        }
    __syncthreads();

    // ---------------- layer 2 GEMM ----------------
    for (int i = tid; i < 2048; i += 256) {            // stage B2_hi
        int n = i >> 4, c = i & 15;
        *(uint4*)&Bs[n * 136 + c * 8] = *(const uint4*)(B2h + n * 128 + c * 8);
    }
#pragma unroll
    for (int mt = 0; mt < 2; mt++)
#pragma unroll
        for (int t = 0; t < 8; t++) acc[mt][t] = (f32x4){0.f, 0.f, 0.f, 0.f};
    __syncthreads();
#pragma unroll
    for (int kk = 0; kk < 4; kk++)
#pragma unroll
        for (int t = 0; t < 8; t++) {
            short8 b = *(const short8*)&Bs[t * 16 * 136 + ldsb + kk * 32];
            acc[0][t] = __builtin_amdgcn_mfma_f32_16x16x32_bf16(afr[kk][0], b, acc[0][t], 0, 0, 0);
            acc[1][t] = __builtin_amdgcn_mfma_f32_16x16x32_bf16(afr[kk][1], b, acc[1][t], 0, 0, 0);
        }
    __syncthreads();
    for (int i = tid; i < 2048; i += 256) {            // stage B2_lo
        int n = i >> 4, c = i & 15;
        *(uint4*)&Bs[n * 136 + c * 8] = *(const uint4*)(B2l + n * 128 + c * 8);
    }
    __syncthreads();
#pragma unroll
    for (int kk = 0; kk < 4; kk++)
#pragma unroll
        for (int t = 0; t < 8; t++) {
            short8 b = *(const short8*)&Bs[t * 16 * 136 + ldsb + kk * 32];
            acc[0][t] = __builtin_amdgcn_mfma_f32_16x16x32_bf16(afr[kk][0], b, acc[0][t], 0, 0, 0);
            acc[1][t] = __builtin_amdgcn_mfma_f32_16x16x32_bf16(afr[kk][1], b, acc[1][t], 0, 0, 0);
        }
    // epilogue 2: bias into acc (acc := z2), column stats
    {
        float csum[8], csq[8];
#pragma unroll
        for (int t = 0; t < 8; t++) { csum[t] = 0.f; csq[t] = 0.f; }
#pragma unroll
        for (int t = 0; t < 8; t++) {
            int col = n16 + 16 * t;
            float bv = bias2[col];
#pragma unroll
            for (int mt = 0; mt < 2; mt++)
#pragma unroll
                for (int r = 0; r < 4; r++) {
                    float v = acc[mt][t][r] + bv;
                    acc[mt][t][r] = v;
                    int row = rowbase + mt * 16 + q * 4 + r;
                    if (row < N) { csum[t] += v; csq[t] += v * v; }
                }
        }
#pragma unroll
        for (int t = 0; t < 8; t++) {
            csum[t] += __shfl_xor(csum[t], 16);
            csum[t] += __shfl_xor(csum[t], 32);
            csq[t] += __shfl_xor(csq[t], 16);
            csq[t] += __shfl_xor(csq[t], 32);
        }
        __syncthreads();
        float* red = (float*)Bs;
        if (q == 0) {
#pragma unroll
            for (int t = 0; t < 8; t++) {
                int col = n16 + 16 * t;
                red[wave * 128 + col] = csum[t];
                red[512 + wave * 128 + col] = csq[t];
            }
        }
        __syncthreads();
        if (tid < 128) {
            float s = 0.f, qq = 0.f;
#pragma unroll
            for (int w = 0; w < 4; w++) {
                s += red[w * 128 + tid];
                qq += red[512 + w * 128 + tid];
            }
            unsafeAtomicAdd(&sum2[tid], s);
            unsafeAtomicAdd(&sq2[tid], qq);
        }
    }
    cooperative_groups::this_grid().sync();

    // -------- BN2+ReLU, direct f32 output --------
    if (tid < 128) {
        float s_ = __hip_atomic_load(&sum2[tid], __ATOMIC_RELAXED,
                                     __HIP_MEMORY_SCOPE_AGENT);
        float qq_ = __hip_atomic_load(&sq2[tid], __ATOMIC_RELAXED,
                                      __HIP_MEMORY_SCOPE_AGENT);
        float mean = s_ * invN;
        float var = fmaxf(qq_ * invN - mean * mean, 0.f);
        float s = gamma2[tid] * rsqrtf(var + 1e-5f);
        sc[tid] = s;
        sh[tid] = beta2[tid] - mean * s;
    }
    __syncthreads();
#pragma unroll
    for (int t = 0; t < 8; t++) {
        int col = n16 + 16 * t;
#pragma unroll
        for (int mt = 0; mt < 2; mt++)
#pragma unroll
            for (int r = 0; r < 4; r++) {
                int row = rowbase + mt * 16 + q * 4 + r;
                if (row < N)
                    outp[(size_t)row * 128 + col] =
                        fmaxf(fmaf(acc[mt][t][r], sc[col], sh[col]), 0.f);
            }
    }
}

// ---- legacy fallback MLP path (used only if cooperative launch fails) -----
__global__ __launch_bounds__(256, 4) void gemm_mfma_k(
        const unsigned short* __restrict__ Ain,
        const unsigned short* __restrict__ Bhg, const unsigned short* __restrict__ Blg,
        const float* __restrict__ bias, unsigned short* __restrict__ zout,
        float* __restrict__ sum_out, float* __restrict__ sq_out, int N) {
    __shared__ unsigned short Bs[128 * 136];
    int tid = threadIdx.x;
    int wave = tid >> 6, lane = tid & 63;
    int n16 = lane & 15, q = lane >> 4;
    int rowbase = blockIdx.x * 128 + wave * 32;
    for (int i = tid; i < 2048; i += 256) {
        int n = i >> 4, c = i & 15;
        *(uint4*)&Bs[n * 136 + c * 8] = *(const uint4*)(Bhg + n * 128 + c * 8);
    }
    short8 afr[4][2];
#pragma unroll
    for (int kk = 0; kk < 4; kk++)
#pragma unroll
        for (int mt = 0; mt < 2; mt++) {
            int ar = rowbase + mt * 16 + n16;
            ar = min(ar, N - 1);
            afr[kk][mt] = *(const short8*)(Ain + (size_t)ar * 128 + kk * 32 + q * 8);
        }
    f32x4 acc[2][8];
#pragma unroll
    for (int mt = 0; mt < 2; mt++)
#pragma unroll
        for (int t = 0; t < 8; t++) acc[mt][t] = (f32x4){0.f, 0.f, 0.f, 0.f};
    __syncthreads();
    int ldsb = n16 * 136 + q * 8;
#pragma unroll
    for (int kk = 0; kk < 4; kk++)
#pragma unroll
        for (int t = 0; t < 8; t++) {
            short8 b = *(const short8*)&Bs[t * 16 * 136 + ldsb + kk * 32];
            acc[0][t] = __builtin_amdgcn_mfma_f32_16x16x32_bf16(afr[kk][0], b, acc[0][t], 0, 0, 0);
            acc[1][t] = __builtin_amdgcn_mfma_f32_16x16x32_bf16(afr[kk][1], b, acc[1][t], 0, 0, 0);
        }
    __syncthreads();
    for (int i = tid; i < 2048; i += 256) {
        int n = i >> 4, c = i & 15;
        *(uint4*)&Bs[n * 136 + c * 8] = *(const uint4*)(Blg + n * 128 + c * 8);
    }
    __syncthreads();
#pragma unroll
    for (int kk = 0; kk < 4; kk++)
#pragma unroll
        for (int t = 0; t < 8; t++) {
            short8 b = *(const short8*)&Bs[t * 16 * 136 + ldsb + kk * 32];
            acc[0][t] = __builtin_amdgcn_mfma_f32_16x16x32_bf16(afr[kk][0], b, acc[0][t], 0, 0, 0);
            acc[1][t] = __builtin_amdgcn_mfma_f32_16x16x32_bf16(afr[kk][1], b, acc[1][t], 0, 0, 0);
        }
    float csum[8], csq[8];
#pragma unroll
    for (int t = 0; t < 8; t++) { csum[t] = 0.f; csq[t] = 0.f; }
#pragma unroll
    for (int t = 0; t < 8; t++) {
        int col = n16 + 16 * t;
        float bv = bias[col];
#pragma unroll
        for (int mt = 0; mt < 2; mt++) {
#pragma unroll
            for (int r = 0; r < 4; r++) {
                int row = rowbase + mt * 16 + q * 4 + r;
                if (row < N) {
                    float v = acc[mt][t][r] + bv;
                    zout[(size_t)row * 128 + col] = f2bf(v);
                    csum[t] += v;
                    csq[t] += v * v;
                }
            }
        }
    }
#pragma unroll
    for (int t = 0; t < 8; t++) {
        csum[t] += __shfl_xor(csum[t], 16);
        csum[t] += __shfl_xor(csum[t], 32);
        csq[t] += __shfl_xor(csq[t], 16);
        csq[t] += __shfl_xor(csq[t], 32);
    }
    __syncthreads();
    float* red = (float*)Bs;
    if (q == 0) {
#pragma unroll
        for (int t = 0; t < 8; t++) {
            int col = n16 + 16 * t;
            red[wave * 128 + col] = csum[t];
            red[512 + wave * 128 + col] = csq[t];
        }
    }
    __syncthreads();
    if (tid < 128) {
        float s = 0.f, qq = 0.f;
#pragma unroll
        for (int w = 0; w < 4; w++) {
            s += red[w * 128 + tid];
            qq += red[512 + w * 128 + tid];
        }
        unsafeAtomicAdd(&sum_out[tid], s);
        unsafeAtomicAdd(&sq_out[tid], qq);
    }
}

__global__ __launch_bounds__(256, 4) void gemm_mfma_bn_k(
        const unsigned short* __restrict__ Zin,
        const float* __restrict__ sum_in, const float* __restrict__ sq_in,
        const float* __restrict__ gamma, const float* __restrict__ beta,
        float invN,
        const unsigned short* __restrict__ Bhg, const unsigned short* __restrict__ Blg,
        const float* __restrict__ bias, unsigned short* __restrict__ zout,
        float* __restrict__ sum_out, float* __restrict__ sq_out, int N) {
    __shared__ unsigned short Bs[128 * 136];
    __shared__ float sc[128], sh[128];
    int tid = threadIdx.x;
    int wave = tid >> 6, lane = tid & 63;
    int n16 = lane & 15, q = lane >> 4;
    int rowbase = blockIdx.x * 128 + wave * 32;
    for (int i = tid; i < 2048; i += 256) {
        int n = i >> 4, c = i & 15;
        *(uint4*)&Bs[n * 136 + c * 8] = *(const uint4*)(Bhg + n * 128 + c * 8);
    }
    if (tid < 128) {
        float mean = sum_in[tid] * invN;
        float var = fmaxf(sq_in[tid] * invN - mean * mean, 0.f);
        float s = gamma[tid] * rsqrtf(var + 1e-5f);
        sc[tid] = s;
        sh[tid] = beta[tid] - mean * s;
    }
    __syncthreads();
    short8 afr[4][2];
#pragma unroll
    for (int kk = 0; kk < 4; kk++)
#pragma unroll
        for (int mt = 0; mt < 2; mt++) {
            int ar = rowbase + mt * 16 + n16;
            ar = min(ar, N - 1);
            short8 raw = *(const short8*)(Zin + (size_t)ar * 128 + kk * 32 + q * 8);
            short8 outv;
#pragma unroll
            for (int i = 0; i < 8; i++) {
                int col = kk * 32 + q * 8 + i;
                float f = bf2f((unsigned short)raw[i]);
                float v = fmaxf(fmaf(f, sc[col], sh[col]), 0.f);
                outv[i] = (short)f2bf(v);
            }
            afr[kk][mt] = outv;
        }
    f32x4 acc[2][8];
#pragma unroll
    for (int mt = 0; mt < 2; mt++)
#pragma unroll
        for (int t = 0; t < 8; t++) acc[mt][t] = (f32x4){0.f, 0.f, 0.f, 0.f};
    int ldsb = n16 * 136 + q * 8;
#pragma unroll
    for (int kk = 0; kk < 4; kk++)
#pragma unroll
        for (int t = 0; t < 8; t++) {
            short8 b = *(const short8*)&Bs[t * 16 * 136 + ldsb + kk * 32];
            acc[0][t] = __builtin_amdgcn_mfma_f32_16x16x32_bf16(afr[kk][0], b, acc[0][t], 0, 0, 0);
            acc[1][t] = __builtin_amdgcn_mfma_f32_16x16x32_bf16(afr[kk][1], b, acc[1][t], 0, 0, 0);
        }
    __syncthreads();
    for (int i = tid; i < 2048; i += 256) {
        int n = i >> 4, c = i & 15;
        *(uint4*)&Bs[n * 136 + c * 8] = *(const uint4*)(Blg + n * 128 + c * 8);
    }
    __syncthreads();
#pragma unroll
    for (int kk = 0; kk < 4; kk++)
#pragma unroll
        for (int t = 0; t < 8; t++) {
            short8 b = *(const short8*)&Bs[t * 16 * 136 + ldsb + kk * 32];
            acc[0][t] = __builtin_amdgcn_mfma_f32_16x16x32_bf16(afr[kk][0], b, acc[0][t], 0, 0, 0);
            acc[1][t] = __builtin_amdgcn_mfma_f32_16x16x32_bf16(afr[kk][1], b, acc[1][t], 0, 0, 0);
        }
    float csum[8], csq[8];
#pragma unroll
    for (int t = 0; t < 8; t++) { csum[t] = 0.f; csq[t] = 0.f; }
#pragma unroll
    for (int t = 0; t < 8; t++) {
        int col = n16 + 16 * t;
        float bv = bias[col];
#pragma unroll
        for (int mt = 0; mt < 2; mt++) {
#pragma unroll
            for (int r = 0; r < 4; r++) {
                int row = rowbase + mt * 16 + q * 4 + r;
                if (row < N) {
                    float v = acc[mt][t][r] + bv;
                    zout[(size_t)row * 128 + col] = f2bf(v);
                    csum[t] += v;
                    csq[t] += v * v;
                }
            }
        }
    }
#pragma unroll
    for (int t = 0; t < 8; t++) {
        csum[t] += __shfl_xor(csum[t], 16);
        csum[t] += __shfl_xor(csum[t], 32);
        csq[t] += __shfl_xor(csq[t], 16);
        csq[t] += __shfl_xor(csq[t], 32);
    }
    __syncthreads();
    float* red = (float*)Bs;
    if (q == 0) {
#pragma unroll
        for (int t = 0; t < 8; t++) {
            int col = n16 + 16 * t;
            red[wave * 128 + col] = csum[t];
            red[512 + wave * 128 + col] = csq[t];
        }
    }
    __syncthreads();
    if (tid < 128) {
        float s = 0.f, qq = 0.f;
#pragma unroll
        for (int w = 0; w < 4; w++) {
            s += red[w * 128 + tid];
            qq += red[512 + w * 128 + tid];
        }
        unsafeAtomicAdd(&sum_out[tid], s);
        unsafeAtomicAdd(&sq_out[tid], qq);
    }
}

__global__ __launch_bounds__(256) void bn2_k(const unsigned short* __restrict__ z2,
        const float* __restrict__ sum2, const float* __restrict__ sq2,
        const float* __restrict__ gamma, const float* __restrict__ beta,
        float* __restrict__ out, long long n8, float invN) {
    __shared__ float sc[128], sh[128];
    int tid = threadIdx.x;
    if (tid < 128) {
        float mean = sum2[tid] * invN;
        float var = fmaxf(sq2[tid] * invN - mean * mean, 0.f);
        float s = gamma[tid] * rsqrtf(var + 1e-5f);
        sc[tid] = s;
        sh[tid] = beta[tid] - mean * s;
    }
    __syncthreads();
    long long g = (long long)blockIdx.x * 256 + tid;
    if (g >= n8) return;
    uint4 u = ((const uint4*)z2)[g];
    int cb = (int)((g * 8) & 127);
    float4 s0 = *(const float4*)&sc[cb], s1 = *(const float4*)&sc[cb + 4];
    float4 t0 = *(const float4*)&sh[cb], t1 = *(const float4*)&sh[cb + 4];
    float4 o0, o1;
    o0.x = fmaxf(fmaf(bflo(u.x), s0.x, t0.x), 0.f);
    o0.y = fmaxf(fmaf(bfhi(u.x), s0.y, t0.y), 0.f);
    o0.z = fmaxf(fmaf(bflo(u.y), s0.z, t0.z), 0.f);
    o0.w = fmaxf(fmaf(bfhi(u.y), s0.w, t0.w), 0.f);
    o1.x = fmaxf(fmaf(bflo(u.z), s1.x, t1.x), 0.f);
    o1.y = fmaxf(fmaf(bfhi(u.z), s1.y, t1.y), 0.f);
    o1.z = fmaxf(fmaf(bflo(u.w), s1.z, t1.z), 0.f);
    o1.w = fmaxf(fmaf(bfhi(u.w), s1.w, t1.w), 0.f);
    ((float4*)out)[g * 2] = o0;
    ((float4*)out)[g * 2 + 1] = o1;
}

extern "C" void kernel_launch(void* const* d_in, const int* in_sizes, int n_in,
                              void* d_out, int out_size, void* d_ws, size_t ws_size,
                              hipStream_t stream) {
    const float* x   = (const float*)d_in[0];
    const int*   ei  = (const int*)d_in[1];
    const int*   ew  = (const int*)d_in[2];
    const float* hc  = (const float*)d_in[3];
    const float* W1  = (const float*)d_in[4];
    const float* b1  = (const float*)d_in[5];
    const float* g1  = (const float*)d_in[6];
    const float* be1 = (const float*)d_in[7];
    const float* W2  = (const float*)d_in[8];
    const float* b2  = (const float*)d_in[9];
    const float* g2  = (const float*)d_in[10];
    const float* be2 = (const float*)d_in[11];

    int N = in_sizes[0] / 128;
    int E = in_sizes[2];
    int K = in_sizes[3];
    size_t NF = (size_t)N * 128;
    long long n8 = (long long)(NF / 8);
    int NX = (int)((n8 + 255) / 256);

    unsigned short* h = (unsigned short*)d_ws;          // NF ush
    unsigned short* xb = h + NF;                        // NF ush
    unsigned short* z1 = xb;                            // fallback alias
    unsigned short* z2 = h;                             // fallback alias
    unsigned* staging = (unsigned*)(xb + NF);           // N * RCAP u32
    int* cur = (int*)(staging + (size_t)N * RCAP);      // N
    unsigned short* w1h = (unsigned short*)(cur + N);
    unsigned short* w1l = w1h + 16384;
    unsigned short* w2h = w1l + 16384;
    unsigned short* w2l = w2h + 16384;
    float* hwp = (float*)(w2l + 16384);                 // 8
    float* sums = hwp + 8;                              // 512
    float* sum1 = sums, *sq1 = sums + 128, *sum2 = sums + 256, *sq2 = sums + 384;
    int nbuk  = (N + 1023) >> 10;
    int nbukp = (nbuk + 7) & ~7;                        // %8 == 0 for XCD mapping
    int* C = (int*)(sums + 512);                        // nbukp * P2B (transposed)
    int* tot = C + (size_t)nbukp * P2B;                 // nbukp
    unsigned* bucketed = (unsigned*)(tot + nbukp);      // E records
    size_t ws_need = (size_t)((char*)(bucketed + E) - (char*)d_ws);
    bool use_bucketed = (nbukp <= 128) && (N <= (1 << 17)) && (K <= 7)
                        && (ws_need <= ws_size);

    float invN = 1.0f / (float)N;
    int per = (E + P2B - 1) / P2B;

    int prep_grid = use_bucketed ? (3 + NX + P2B) : (3 + NX);
    if (!use_bucketed)
        hipMemsetAsync(cur, 0, (size_t)N * sizeof(int), stream);
    prep_k<<<prep_grid, 256, 0, stream>>>(hc, hwp, sums, W1, W2,
        w1h, w1l, w2h, w2l, (const float4*)x, (uint4*)xb, K, n8,
        ei, C, cur, E, per, nbukp, N, NX);
    if (use_bucketed) {
        scan1_k<<<nbukp, 256, 0, stream>>>(C, tot, nbukp, P2B);
        scatter_k<<<P2B, 256, 0, stream>>>(ei, ei + E, ew, C, tot, bucketed,
                                           E, per, nbukp, K);
        slot3_k<<<nbukp * BPB, 256, 0, stream>>>(bucketed, tot, cur, staging, nbukp);
    } else {
        slot_k<<<(E + 255) / 256, 256, 0, stream>>>(ei, ei + E, ew, cur, staging, E, K);
    }
    {
        long long tot_thr = (long long)N * 64;
        gather_k<<<(int)((tot_thr + 255) / 256), 256, 0, stream>>>(
            xb, staging, cur, hwp, h, N);
    }
    int gblocks = (N + 127) / 128;
    float* outf = (float*)d_out;
    hipError_t ce = hipErrorUnknown;
    if (gblocks <= 1024) {                              // co-residency capacity
        void* args[] = { (void*)&h, (void*)&w1h, (void*)&w1l,
                         (void*)&b1, (void*)&g1, (void*)&be1,
                         (void*)&w2h, (void*)&w2l,
                         (void*)&b2, (void*)&g2, (void*)&be2,
                         (void*)&sums, (void*)&outf, (void*)&invN, (void*)&N };
        ce = hipLaunchCooperativeKernel((const void*)mlp_coop_k,
                 dim3(gblocks), dim3(256), args, 0, stream);
    }
    if (ce != hipSuccess) {                             // legacy fallback path
        gemm_mfma_k<<<gblocks, 256, 0, stream>>>(h, w1h, w1l, b1, z1, sum1, sq1, N);
        gemm_mfma_bn_k<<<gblocks, 256, 0, stream>>>(z1, sum1, sq1, g1, be1, invN,
            w2h, w2l, b2, z2, sum2, sq2, N);
        bn2_k<<<NX, 256, 0, stream>>>(z2, sum2, sq2, g2, be2, outf, n8, invN);
    }
}

// Round 8
// 465.051 us; speedup vs baseline: 1.2074x; 1.1117x over previous
//
#include <hip/hip_runtime.h>
#include <hip/hip_bf16.h>
#include <hip/hip_cooperative_groups.h>

// ---------------------------------------------------------------------------
// SPN layer (R16): prep{softmax||Wsplit||x->bf16||count||zero-cur} -> scan1 ->
// scatter -> slot3 -> gather -> mlp_coop (gemm1 -> stats -> grid.sync ->
// BN1+ReLU regs -> gemm2 -> stats -> grid.sync -> BN2+ReLU -> f32 out).
// R15 coop was 190us: VGPR_Count=64 + 42MB excess writes = ACC SPILLED TO
// SCRATCH under launch_bounds(256,4)'s 128-VGPR cap. R16: launch_bounds
// (256,2) -> 256 VGPR budget; grid halved to ceil(N/256) blocks (<=512
// co-resident at 2 blocks/CU), each block owns TWO 128-row tiles.
// acc[2][2][8]=128 VGPR stays in registers; A-frags reloaded per B-pass.
// Fallback: legacy gemm1/gemm2bn/bn2 path if cooperative launch errors.
// ---------------------------------------------------------------------------

#define RCAP 64    // slots per row; P(Poisson(16) > 64) ~ 1e-20 per row
#define P2B 256    // blocks in count/scatter passes
#define BPB 4      // blocks per bucket in slot3

typedef __attribute__((ext_vector_type(8))) short short8;
typedef __attribute__((ext_vector_type(4))) float f32x4;

__device__ inline unsigned short f2bf(float v) {           // RNE bf16 round
    unsigned int u = __float_as_uint(v);
    return (unsigned short)((u + 0x7fffu + ((u >> 16) & 1u)) >> 16);
}
__device__ inline float bf2f(unsigned int u) { return __uint_as_float(u << 16); }
__device__ inline float bflo(unsigned int u) { return __uint_as_float(u << 16); }
__device__ inline float bfhi(unsigned int u) { return __uint_as_float(u & 0xFFFF0000u); }

// --- prep: [0]=softmax+zero stats, [1..2]=W split, [3..3+NX)=x->bf16,
//     [3+NX..3+NX+P2B) = edge-count histogram + zero cur (bucketed path) ----
__global__ __launch_bounds__(256) void prep_k(
        const float* __restrict__ hc, float* __restrict__ hwp, float* __restrict__ sums,
        const float* __restrict__ W1, const float* __restrict__ W2,
        unsigned short* __restrict__ w1h, unsigned short* __restrict__ w1l,
        unsigned short* __restrict__ w2h, unsigned short* __restrict__ w2l,
        const float4* __restrict__ x4, uint4* __restrict__ xb, int K, long long n8,
        const int* __restrict__ rows, int* __restrict__ C, int* __restrict__ cur,
        int E, int per, int nbukp, int N, int NX) {
    __shared__ int hist[128];
    int b = blockIdx.x, tid = threadIdx.x;
    if (b == 0) {                                    // softmax + zero stats
        sums[tid] = 0.f; sums[tid + 256] = 0.f;
        if (tid == 0) {
            float tmp[8];
            float m = -1e30f;
            for (int k = 0; k < K; ++k) m = fmaxf(m, hc[k]);
            float s = 0.f;
            for (int k = 0; k < K; ++k) { float e = __expf(hc[k] - m); tmp[k] = e; s += e; }
            float inv = 1.f / s;
            for (int k = 0; k < 8; ++k) hwp[k] = 0.f;
            for (int k = 0; k < K; ++k) hwp[k + 1] = tmp[k] * inv;
        }
        return;
    }
    if (b <= 2) {                                    // W split (transposed hi/lo)
        const float* W = (b == 2) ? W2 : W1;
        unsigned short* th = (b == 2) ? w2h : w1h;
        unsigned short* tl = (b == 2) ? w2l : w1l;
        for (int i = tid; i < 16384; i += 256) {
            int k = i >> 7, n = i & 127;
            float v = W[k * 128 + n];
            unsigned short hi = f2bf(v);
            th[n * 128 + k] = hi;
            tl[n * 128 + k] = f2bf(v - bf2f(hi));
        }
        return;
    }
    if (b < 3 + NX) {                                // x -> bf16
        long long g = (long long)(b - 3) * 256 + tid;
        if (g >= n8) return;
        float4 a = x4[g * 2], c = x4[g * 2 + 1];
        union { unsigned short us[8]; uint4 v; } o;
        o.us[0] = f2bf(a.x); o.us[1] = f2bf(a.y); o.us[2] = f2bf(a.z); o.us[3] = f2bf(a.w);
        o.us[4] = f2bf(c.x); o.us[5] = f2bf(c.y); o.us[6] = f2bf(c.z); o.us[7] = f2bf(c.w);
        xb[g] = o.v;
        return;
    }
    // count role (only launched when bucketed): histogram of row>>10 + zero cur
    int cblk = b - 3 - NX;
    for (int i = tid; i < nbukp; i += 256) hist[i] = 0;
    __syncthreads();
    int e0 = cblk * per, e1 = min(E, e0 + per);
    for (int e = e0 + tid; e < e1; e += 256)
        atomicAdd(&hist[rows[e] >> 10], 1);
    __syncthreads();
    for (int i = tid; i < nbukp; i += 256) C[i * P2B + cblk] = hist[i];
    int zper = (N + P2B - 1) / P2B;
    int z0 = cblk * zper, z1 = min(N, z0 + zper);
    for (int i = z0 + tid; i < z1; i += 256) cur[i] = 0;
}

// P2a: block b scans bucket-b's row of C (coalesced; Hillis-Steele in LDS);
// C becomes within-bucket exclusive prefix; tot[b] = bucket total.
__global__ __launch_bounds__(256) void scan1_k(int* __restrict__ C,
        int* __restrict__ tot, int nbukp, int nblk) {
    __shared__ int buf[256];
    int b = blockIdx.x, tid = threadIdx.x;
    int v = (tid < nblk) ? C[b * P2B + tid] : 0;
    buf[tid] = v;
    __syncthreads();
#pragma unroll
    for (int off = 1; off < 256; off <<= 1) {
        int t = (tid >= off) ? buf[tid - off] : 0;
        __syncthreads();
        buf[tid] += t;
        __syncthreads();
    }
    if (tid < nblk) C[b * P2B + tid] = buf[tid] - v;     // exclusive
    if (tid == 255) tot[b] = buf[255];
}

// P2b: bucket-grouped 4B records: d | col<<3 | (row&1023)<<20
// bucket bases derived inline from tot[] (scan2 folded into prologue)
__global__ __launch_bounds__(256) void scatter_k(const int* __restrict__ rows,
        const int* __restrict__ cols, const int* __restrict__ ew,
        const int* __restrict__ O, const int* __restrict__ tot,
        unsigned* __restrict__ bucketed, int E, int per, int nbukp, int K) {
    __shared__ int buf[128];
    __shared__ unsigned curs[128];
    int blk = blockIdx.x, tid = threadIdx.x;
    int v = (tid < 128 && tid < nbukp) ? tot[tid] : 0;
    if (tid < 128) buf[tid] = v;
    __syncthreads();
#pragma unroll
    for (int off = 1; off < 128; off <<= 1) {
        int t = (tid >= off && tid < 128) ? buf[tid - off] : 0;
        __syncthreads();
        if (tid < 128) buf[tid] += t;
        __syncthreads();
    }
    if (tid < nbukp)
        curs[tid] = (unsigned)(O[tid * P2B + blk] + buf[tid] - v);  // excl base
    __syncthreads();
    int e0 = blk * per, e1 = min(E, e0 + per);
    for (int e = e0 + tid; e < e1; e += 256) {
        int r = rows[e];
        int c = cols[e];
        int d = ew[e];
        if (d < 1 || d > K) d = 0;                   // hwp[0] = 0 -> weight 0
        unsigned idx = atomicAdd(&curs[r >> 10], 1u);
        bucketed[idx] = (unsigned)d | ((unsigned)c << 3) | ((unsigned)(r & 1023) << 20);
    }
}

// P3: ticket + 4B staging scatter, one 1024-row bucket per BPB-block group.
// blockIdx % nbukp keeps a bucket's blocks on one XCD (nbukp % 8 == 0).
__global__ __launch_bounds__(256) void slot3_k(const unsigned* __restrict__ bucketed,
        const int* __restrict__ tot, int* __restrict__ cur,
        unsigned* __restrict__ staging, int nbukp) {
    __shared__ int buf[128];
    int tid = threadIdx.x;
    if (tid < 128) buf[tid] = (tid < nbukp) ? tot[tid] : 0;
    __syncthreads();
#pragma unroll
    for (int off = 1; off < 128; off <<= 1) {
        int t = (tid >= off && tid < 128) ? buf[tid - off] : 0;
        __syncthreads();
        if (tid < 128) buf[tid] += t;
        __syncthreads();
    }
    int bucket = blockIdx.x % nbukp, sub = blockIdx.x / nbukp;
    int s1 = buf[bucket];
    int s0 = s1 - tot[bucket];
    int cnt = s1 - s0;
    int qlo = s0 + (int)((long long)cnt * sub / BPB);
    int qhi = s0 + (int)((long long)cnt * (sub + 1) / BPB);
    int rbase = bucket << 10;
    for (int e = qlo + tid; e < qhi; e += 256) {
        unsigned u = bucketed[e];
        int row = rbase + (int)(u >> 20);
        int s = atomicAdd(&cur[row], 1);
        if (s < RCAP)
            staging[((size_t)row << 6) + s] = u & 0xFFFFFu;
    }
}

// legacy single-pass slot (fallback: N/K out of packing range or ws too small)
__global__ __launch_bounds__(256) void slot_k(const int* __restrict__ rows,
        const int* __restrict__ cols, const int* __restrict__ ew,
        int* __restrict__ cur, unsigned* __restrict__ staging, int E, int K) {
    int e = blockIdx.x * 256 + threadIdx.x;
    if (e >= E) return;
    int r = rows[e];
    int d = ew[e];
    if (d < 1 || d > K) d = 0;
    int s = atomicAdd(&cur[r], 1);
    if (s < RCAP)
        staging[((size_t)r << 6) + s] = (unsigned)d | ((unsigned)cols[e] << 3);
}

// one wave per row, 4 edges per wave-step: each 16-lane group loads one full
// 256B row (uint4/lane). 4B payload records; weight via 8-entry LDS table.
__global__ __launch_bounds__(256) void gather_k(
        const unsigned short* __restrict__ xb, const unsigned* __restrict__ staging,
        const int* __restrict__ cur, const float* __restrict__ hwp,
        unsigned short* __restrict__ h, int N) {
    __shared__ float hwl[8];
    int tid = threadIdx.x;
    if (tid < 8) hwl[tid] = hwp[tid];
    __syncthreads();
    int wid = (blockIdx.x * 256 + tid) >> 6;
    if (wid >= N) return;
    int lane = tid & 63;
    int g4 = lane >> 4, li = lane & 15;
    int deg = __builtin_amdgcn_readfirstlane(cur[wid]);
    deg = min(deg, RCAP);
    const unsigned* ep = staging + ((size_t)wid << 6);
    const unsigned short* xrow = xb + li * 8;          // 16B per lane within row
    float a0 = 0.f, a1 = 0.f, a2 = 0.f, a3 = 0.f;
    float a4 = 0.f, a5 = 0.f, a6 = 0.f, a7 = 0.f;
    if (g4 == 0) {                                     // GIN self term (eps=0)
        uint4 u = *(const uint4*)(xb + (size_t)wid * 128 + li * 8);
        a0 = bflo(u.x); a1 = bfhi(u.x); a2 = bflo(u.y); a3 = bfhi(u.y);
        a4 = bflo(u.z); a5 = bfhi(u.z); a6 = bflo(u.w); a7 = bfhi(u.w);
    }
    int j = 0;
    for (; j + 16 <= deg; j += 16) {
        unsigned p0 = ep[j + g4];
        unsigned p1 = ep[j + 4 + g4];
        unsigned p2 = ep[j + 8 + g4];
        unsigned p3 = ep[j + 12 + g4];
        uint4 u0 = *(const uint4*)(xrow + (size_t)(p0 >> 3) * 128);
        uint4 u1 = *(const uint4*)(xrow + (size_t)(p1 >> 3) * 128);
        uint4 u2 = *(const uint4*)(xrow + (size_t)(p2 >> 3) * 128);
        uint4 u3 = *(const uint4*)(xrow + (size_t)(p3 >> 3) * 128);
        float w0 = hwl[p0 & 7], w1 = hwl[p1 & 7];
        float w2 = hwl[p2 & 7], w3 = hwl[p3 & 7];
        a0 = fmaf(w0, bflo(u0.x), a0); a1 = fmaf(w0, bfhi(u0.x), a1);
        a2 = fmaf(w0, bflo(u0.y), a2); a3 = fmaf(w0, bfhi(u0.y), a3);
        a4 = fmaf(w0, bflo(u0.z), a4); a5 = fmaf(w0, bfhi(u0.z), a5);
        a6 = fmaf(w0, bflo(u0.w), a6); a7 = fmaf(w0, bfhi(u0.w), a7);
        a0 = fmaf(w1, bflo(u1.x), a0); a1 = fmaf(w1, bfhi(u1.x), a1);
        a2 = fmaf(w1, bflo(u1.y), a2); a3 = fmaf(w1, bfhi(u1.y), a3);
        a4 = fmaf(w1, bflo(u1.z), a4); a5 = fmaf(w1, bfhi(u1.z), a5);
        a6 = fmaf(w1, bflo(u1.w), a6); a7 = fmaf(w1, bfhi(u1.w), a7);
        a0 = fmaf(w2, bflo(u2.x), a0); a1 = fmaf(w2, bfhi(u2.x), a1);
        a2 = fmaf(w2, bflo(u2.y), a2); a3 = fmaf(w2, bfhi(u2.y), a3);
        a4 = fmaf(w2, bflo(u2.z), a4); a5 = fmaf(w2, bfhi(u2.z), a5);
        a6 = fmaf(w2, bflo(u2.w), a6); a7 = fmaf(w2, bfhi(u2.w), a7);
        a0 = fmaf(w3, bflo(u3.x), a0); a1 = fmaf(w3, bfhi(u3.x), a1);
        a2 = fmaf(w3, bflo(u3.y), a2); a3 = fmaf(w3, bfhi(u3.y), a3);
        a4 = fmaf(w3, bflo(u3.z), a4); a5 = fmaf(w3, bfhi(u3.z), a5);
        a6 = fmaf(w3, bflo(u3.w), a6); a7 = fmaf(w3, bfhi(u3.w), a7);
    }
    for (; j + 4 <= deg; j += 4) {
        unsigned p = ep[j + g4];
        uint4 u = *(const uint4*)(xrow + (size_t)(p >> 3) * 128);
        float w = hwl[p & 7];
        a0 = fmaf(w, bflo(u.x), a0); a1 = fmaf(w, bfhi(u.x), a1);
        a2 = fmaf(w, bflo(u.y), a2); a3 = fmaf(w, bfhi(u.y), a3);
        a4 = fmaf(w, bflo(u.z), a4); a5 = fmaf(w, bfhi(u.z), a5);
        a6 = fmaf(w, bflo(u.w), a6); a7 = fmaf(w, bfhi(u.w), a7);
    }
    if (j < deg) {                                     // tail 1..3 edges
        int jj = min(j + g4, deg - 1);
        unsigned p = ep[jj];
        float w = (j + g4 < deg) ? hwl[p & 7] : 0.f;
        uint4 u = *(const uint4*)(xrow + (size_t)(p >> 3) * 128);
        a0 = fmaf(w, bflo(u.x), a0); a1 = fmaf(w, bfhi(u.x), a1);
        a2 = fmaf(w, bflo(u.y), a2); a3 = fmaf(w, bfhi(u.y), a3);
        a4 = fmaf(w, bflo(u.z), a4); a5 = fmaf(w, bfhi(u.z), a5);
        a6 = fmaf(w, bflo(u.w), a6); a7 = fmaf(w, bfhi(u.w), a7);
    }
    a0 += __shfl_xor(a0, 16); a1 += __shfl_xor(a1, 16);
    a2 += __shfl_xor(a2, 16); a3 += __shfl_xor(a3, 16);
    a4 += __shfl_xor(a4, 16); a5 += __shfl_xor(a5, 16);
    a6 += __shfl_xor(a6, 16); a7 += __shfl_xor(a7, 16);
    a0 += __shfl_xor(a0, 32); a1 += __shfl_xor(a1, 32);
    a2 += __shfl_xor(a2, 32); a3 += __shfl_xor(a3, 32);
    a4 += __shfl_xor(a4, 32); a5 += __shfl_xor(a5, 32);
    a6 += __shfl_xor(a6, 32); a7 += __shfl_xor(a7, 32);
    if (g4 == 0) {
        uint4 o;
        o.x = (unsigned int)f2bf(a0) | ((unsigned int)f2bf(a1) << 16);
        o.y = (unsigned int)f2bf(a2) | ((unsigned int)f2bf(a3) << 16);
        o.z = (unsigned int)f2bf(a4) | ((unsigned int)f2bf(a5) << 16);
        o.w = (unsigned int)f2bf(a6) | ((unsigned int)f2bf(a7) << 16);
        *(uint4*)(h + (size_t)wid * 128 + li * 8) = o;
    }
}

// --- fused MLP, 2 tiles (256 rows) per block, launch_bounds(256,2):
// 256-VGPR budget so acc[2][2][8] (128 VGPR) stays in registers (R15 spilled
// at the 128-VGPR cap: VGPR_Count=64 + 42MB scratch writes). Grid = ceil(
// N/256) <= 512 = 2 blocks/CU co-residency. A-frags reloaded per B-pass.
__global__ __launch_bounds__(256, 2) void mlp_coop_k(
        const unsigned short* __restrict__ Ain,
        const unsigned short* __restrict__ B1h, const unsigned short* __restrict__ B1l,
        const float* __restrict__ bias1, const float* __restrict__ gamma1,
        const float* __restrict__ beta1,
        const unsigned short* __restrict__ B2h, const unsigned short* __restrict__ B2l,
        const float* __restrict__ bias2, const float* __restrict__ gamma2,
        const float* __restrict__ beta2,
        float* __restrict__ sums, float* __restrict__ outp, float invN, int N) {
    __shared__ unsigned short Bs[128 * 136];
    __shared__ float sc[128], sh[128];
    float* sum1 = sums;       float* sq1 = sums + 128;
    float* sum2 = sums + 256; float* sq2 = sums + 384;
    int tid = threadIdx.x;
    int wave = tid >> 6, lane = tid & 63;
    int n16 = lane & 15, q = lane >> 4;
    int rb = blockIdx.x * 256;                          // two tiles: rb, rb+128
    int ldsb = n16 * 136 + q * 8;

    f32x4 acc[2][2][8];                                 // [tile][mt][t] 128 VGPR
#pragma unroll
    for (int t2 = 0; t2 < 2; t2++)
#pragma unroll
        for (int mt = 0; mt < 2; mt++)
#pragma unroll
            for (int t = 0; t < 8; t++) acc[t2][mt][t] = (f32x4){0.f, 0.f, 0.f, 0.f};

    // ---------------- layer 1 GEMM ----------------
    for (int i = tid; i < 2048; i += 256) {             // stage B1_hi
        int n = i >> 4, c = i & 15;
        *(uint4*)&Bs[n * 136 + c * 8] = *(const uint4*)(B1h + n * 128 + c * 8);
    }
    __syncthreads();
#pragma unroll
    for (int t2 = 0; t2 < 2; t2++) {
        short8 afr[4][2];
#pragma unroll
        for (int kk = 0; kk < 4; kk++)
#pragma unroll
            for (int mt = 0; mt < 2; mt++) {
                int ar = min(rb + t2 * 128 + wave * 32 + mt * 16 + n16, N - 1);
                afr[kk][mt] = *(const short8*)(Ain + (size_t)ar * 128 + kk * 32 + q * 8);
            }
#pragma unroll
        for (int kk = 0; kk < 4; kk++)
#pragma unroll
            for (int t = 0; t < 8; t++) {
                short8 b = *(const short8*)&Bs[t * 16 * 136 + ldsb + kk * 32];
                acc[t2][0][t] = __builtin_amdgcn_mfma_f32_16x16x32_bf16(afr[kk][0], b, acc[t2][0][t], 0, 0, 0);
                acc[t2][1][t] = __builtin_amdgcn_mfma_f32_16x16x32_bf16(afr[kk][1], b, acc[t2][1][t], 0, 0, 0);
            }
    }
    __syncthreads();
    for (int i = tid; i < 2048; i += 256) {             // stage B1_lo
        int n = i >> 4, c = i & 15;
        *(uint4*)&Bs[n * 136 + c * 8] = *(const uint4*)(B1l + n * 128 + c * 8);
    }
    __syncthreads();
#pragma unroll
    for (int t2 = 0; t2 < 2; t2++) {
        short8 afr[4][2];
#pragma unroll
        for (int kk = 0; kk < 4; kk++)
#pragma unroll
            for (int mt = 0; mt < 2; mt++) {
                int ar = min(rb + t2 * 128 + wave * 32 + mt * 16 + n16, N - 1);
                afr[kk][mt] = *(const short8*)(Ain + (size_t)ar * 128 + kk * 32 + q * 8);
            }
#pragma unroll
        for (int kk = 0; kk < 4; kk++)
#pragma unroll
            for (int t = 0; t < 8; t++) {
                short8 b = *(const short8*)&Bs[t * 16 * 136 + ldsb + kk * 32];
                acc[t2][0][t] = __builtin_amdgcn_mfma_f32_16x16x32_bf16(afr[kk][0], b, acc[t2][0][t], 0, 0, 0);
                acc[t2][1][t] = __builtin_amdgcn_mfma_f32_16x16x32_bf16(afr[kk][1], b, acc[t2][1][t], 0, 0, 0);
            }
    }
    // epilogue 1: bias into acc (acc := z1, f32), column stats over both tiles
    {
        float csum[8], csq[8];
#pragma unroll
        for (int t = 0; t < 8; t++) { csum[t] = 0.f; csq[t] = 0.f; }
#pragma unroll
        for (int t = 0; t < 8; t++) {
            int col = n16 + 16 * t;
            float bv = bias1[col];
#pragma unroll
            for (int t2 = 0; t2 < 2; t2++)
#pragma unroll
                for (int mt = 0; mt < 2; mt++)
#pragma unroll
                    for (int r = 0; r < 4; r++) {
                        float v = acc[t2][mt][t][r] + bv;
                        acc[t2][mt][t][r] = v;
                        int row = rb + t2 * 128 + wave * 32 + mt * 16 + q * 4 + r;
                        if (row < N) { csum[t] += v; csq[t] += v * v; }
                    }
        }
#pragma unroll
        for (int t = 0; t < 8; t++) {
            csum[t] += __shfl_xor(csum[t], 16);
            csum[t] += __shfl_xor(csum[t], 32);
            csq[t] += __shfl_xor(csq[t], 16);
            csq[t] += __shfl_xor(csq[t], 32);
        }
        __syncthreads();
        float* red = (float*)Bs;
        if (q == 0) {
#pragma unroll
            for (int t = 0; t < 8; t++) {
                int col = n16 + 16 * t;
                red[wave * 128 + col] = csum[t];
                red[512 + wave * 128 + col] = csq[t];
            }
        }
        __syncthreads();
        if (tid < 128) {
            float s = 0.f, qq = 0.f;
#pragma unroll
            for (int w = 0; w < 4; w++) {
                s += red[w * 128 + tid];
                qq += red[512 + w * 128 + tid];
            }
            unsafeAtomicAdd(&sum1[tid], s);
            unsafeAtomicAdd(&sq1[tid], qq);
        }
    }
    cooperative_groups::this_grid().sync();

    // -------- BN1+ReLU in regs, bounce each tile through LDS to A-frags ----
    if (tid < 128) {
        float s_ = __hip_atomic_load(&sum1[tid], __ATOMIC_RELAXED,
                                     __HIP_MEMORY_SCOPE_AGENT);
        float qq_ = __hip_atomic_load(&sq1[tid], __ATOMIC_RELAXED,
                                      __HIP_MEMORY_SCOPE_AGENT);
        float mean = s_ * invN;
        float var = fmaxf(qq_ * invN - mean * mean, 0.f);
        float s = gamma1[tid] * rsqrtf(var + 1e-5f);
        sc[tid] = s;
        sh[tid] = beta1[tid] - mean * s;
    }
    __syncthreads();
    short8 afr0[4][2], afr1[4][2];
    // tile 0 bounce
#pragma unroll
    for (int t = 0; t < 8; t++) {
        int col = n16 + 16 * t;
#pragma unroll
        for (int mt = 0; mt < 2; mt++)
#pragma unroll
            for (int r = 0; r < 4; r++) {
                int lr = wave * 32 + mt * 16 + q * 4 + r;
                float bn = fmaxf(fmaf(acc[0][mt][t][r], sc[col], sh[col]), 0.f);
                Bs[lr * 136 + col] = f2bf(bn);
            }
    }
    __syncthreads();
#pragma unroll
    for (int kk = 0; kk < 4; kk++)
#pragma unroll
        for (int mt = 0; mt < 2; mt++) {
            int lr = wave * 32 + mt * 16 + n16;
            afr0[kk][mt] = *(const short8*)&Bs[lr * 136 + kk * 32 + q * 8];
        }
    __syncthreads();
    // tile 1 bounce
#pragma unroll
    for (int t = 0; t < 8; t++) {
        int col = n16 + 16 * t;
#pragma unroll
        for (int mt = 0; mt < 2; mt++)
#pragma unroll
            for (int r = 0; r < 4; r++) {
                int lr = wave * 32 + mt * 16 + q * 4 + r;
                float bn = fmaxf(fmaf(acc[1][mt][t][r], sc[col], sh[col]), 0.f);
                Bs[lr * 136 + col] = f2bf(bn);
            }
    }
    __syncthreads();
#pragma unroll
    for (int kk = 0; kk < 4; kk++)
#pragma unroll
        for (int mt = 0; mt < 2; mt++) {
            int lr = wave * 32 + mt * 16 + n16;
            afr1[kk][mt] = *(const short8*)&Bs[lr * 136 + kk * 32 + q * 8];
        }
    __syncthreads();

    // ---------------- layer 2 GEMM ----------------
#pragma unroll
    for (int t2 = 0; t2 < 2; t2++)
#pragma unroll
        for (int mt = 0; mt < 2; mt++)
#pragma unroll
            for (int t = 0; t < 8; t++) acc[t2][mt][t] = (f32x4){0.f, 0.f, 0.f, 0.f};
    for (int i = tid; i < 2048; i += 256) {             // stage B2_hi
        int n = i >> 4, c = i & 15;
        *(uint4*)&Bs[n * 136 + c * 8] = *(const uint4*)(B2h + n * 128 + c * 8);
    }
    __syncthreads();
#pragma unroll
    for (int kk = 0; kk < 4; kk++)
#pragma unroll
        for (int t = 0; t < 8; t++) {
            short8 b = *(const short8*)&Bs[t * 16 * 136 + ldsb + kk * 32];
            acc[0][0][t] = __builtin_amdgcn_mfma_f32_16x16x32_bf16(afr0[kk][0], b, acc[0][0][t], 0, 0, 0);
            acc[0][1][t] = __builtin_amdgcn_mfma_f32_16x16x32_bf16(afr0[kk][1], b, acc[0][1][t], 0, 0, 0);
            acc[1][0][t] = __builtin_amdgcn_mfma_f32_16x16x32_bf16(afr1[kk][0], b, acc[1][0][t], 0, 0, 0);
            acc[1][1][t] = __builtin_amdgcn_mfma_f32_16x16x32_bf16(afr1[kk][1], b, acc[1][1][t], 0, 0, 0);
        }
    __syncthreads();
    for (int i = tid; i < 2048; i += 256) {             // stage B2_lo
        int n = i >> 4, c = i & 15;
        *(uint4*)&Bs[n * 136 + c * 8] = *(const uint4*)(B2l + n * 128 + c * 8);
    }
    __syncthreads();
#pragma unroll
    for (int kk = 0; kk < 4; kk++)
#pragma unroll
        for (int t = 0; t < 8; t++) {
            short8 b = *(const short8*)&Bs[t * 16 * 136 + ldsb + kk * 32];
            acc[0][0][t] = __builtin_amdgcn_mfma_f32_16x16x32_bf16(afr0[kk][0], b, acc[0][0][t], 0, 0, 0);
            acc[0][1][t] = __builtin_amdgcn_mfma_f32_16x16x32_bf16(afr0[kk][1], b, acc[0][1][t], 0, 0, 0);
            acc[1][0][t] = __builtin_amdgcn_mfma_f32_16x16x32_bf16(afr1[kk][0], b, acc[1][0][t], 0, 0, 0);
            acc[1][1][t] = __builtin_amdgcn_mfma_f32_16x16x32_bf16(afr1[kk][1], b, acc[1][1][t], 0, 0, 0);
        }
    // epilogue 2: bias into acc (acc := z2), column stats
    {
        float csum[8], csq[8];
#pragma unroll
        for (int t = 0; t < 8; t++) { csum[t] = 0.f; csq[t] = 0.f; }
#pragma unroll
        for (int t = 0; t < 8; t++) {
            int col = n16 + 16 * t;
            float bv = bias2[col];
#pragma unroll
            for (int t2 = 0; t2 < 2; t2++)
#pragma unroll
                for (int mt = 0; mt < 2; mt++)
#pragma unroll
                    for (int r = 0; r < 4; r++) {
                        float v = acc[t2][mt][t][r] + bv;
                        acc[t2][mt][t][r] = v;
                        int row = rb + t2 * 128 + wave * 32 + mt * 16 + q * 4 + r;
                        if (row < N) { csum[t] += v; csq[t] += v * v; }
                    }
        }
#pragma unroll
        for (int t = 0; t < 8; t++) {
            csum[t] += __shfl_xor(csum[t], 16);
            csum[t] += __shfl_xor(csum[t], 32);
            csq[t] += __shfl_xor(csq[t], 16);
            csq[t] += __shfl_xor(csq[t], 32);
        }
        __syncthreads();
        float* red = (float*)Bs;
        if (q == 0) {
#pragma unroll
            for (int t = 0; t < 8; t++) {
                int col = n16 + 16 * t;
                red[wave * 128 + col] = csum[t];
                red[512 + wave * 128 + col] = csq[t];
            }
        }
        __syncthreads();
        if (tid < 128) {
            float s = 0.f, qq = 0.f;
#pragma unroll
            for (int w = 0; w < 4; w++) {
                s += red[w * 128 + tid];
                qq += red[512 + w * 128 + tid];
            }
            unsafeAtomicAdd(&sum2[tid], s);
            unsafeAtomicAdd(&sq2[tid], qq);
        }
    }
    cooperative_groups::this_grid().sync();

    // -------- BN2+ReLU, direct f32 output --------
    if (tid < 128) {
        float s_ = __hip_atomic_load(&sum2[tid], __ATOMIC_RELAXED,
                                     __HIP_MEMORY_SCOPE_AGENT);
        float qq_ = __hip_atomic_load(&sq2[tid], __ATOMIC_RELAXED,
                                      __HIP_MEMORY_SCOPE_AGENT);
        float mean = s_ * invN;
        float var = fmaxf(qq_ * invN - mean * mean, 0.f);
        float s = gamma2[tid] * rsqrtf(var + 1e-5f);
        sc[tid] = s;
        sh[tid] = beta2[tid] - mean * s;
    }
    __syncthreads();
#pragma unroll
    for (int t = 0; t < 8; t++) {
        int col = n16 + 16 * t;
#pragma unroll
        for (int t2 = 0; t2 < 2; t2++)
#pragma unroll
            for (int mt = 0; mt < 2; mt++)
#pragma unroll
                for (int r = 0; r < 4; r++) {
                    int row = rb + t2 * 128 + wave * 32 + mt * 16 + q * 4 + r;
                    if (row < N)
                        outp[(size_t)row * 128 + col] =
                            fmaxf(fmaf(acc[t2][mt][t][r], sc[col], sh[col]), 0.f);
                }
    }
}

// ---- legacy fallback MLP path (used only if cooperative launch fails) -----
__global__ __launch_bounds__(256, 4) void gemm_mfma_k(
        const unsigned short* __restrict__ Ain,
        const unsigned short* __restrict__ Bhg, const unsigned short* __restrict__ Blg,
        const float* __restrict__ bias, unsigned short* __restrict__ zout,
        float* __restrict__ sum_out, float* __restrict__ sq_out, int N) {
    __shared__ unsigned short Bs[128 * 136];
    int tid = threadIdx.x;
    int wave = tid >> 6, lane = tid & 63;
    int n16 = lane & 15, q = lane >> 4;
    int rowbase = blockIdx.x * 128 + wave * 32;
    for (int i = tid; i < 2048; i += 256) {
        int n = i >> 4, c = i & 15;
        *(uint4*)&Bs[n * 136 + c * 8] = *(const uint4*)(Bhg + n * 128 + c * 8);
    }
    short8 afr[4][2];
#pragma unroll
    for (int kk = 0; kk < 4; kk++)
#pragma unroll
        for (int mt = 0; mt < 2; mt++) {
            int ar = rowbase + mt * 16 + n16;
            ar = min(ar, N - 1);
            afr[kk][mt] = *(const short8*)(Ain + (size_t)ar * 128 + kk * 32 + q * 8);
        }
    f32x4 acc[2][8];
#pragma unroll
    for (int mt = 0; mt < 2; mt++)
#pragma unroll
        for (int t = 0; t < 8; t++) acc[mt][t] = (f32x4){0.f, 0.f, 0.f, 0.f};
    __syncthreads();
    int ldsb = n16 * 136 + q * 8;
#pragma unroll
    for (int kk = 0; kk < 4; kk++)
#pragma unroll
        for (int t = 0; t < 8; t++) {
            short8 b = *(const short8*)&Bs[t * 16 * 136 + ldsb + kk * 32];
            acc[0][t] = __builtin_amdgcn_mfma_f32_16x16x32_bf16(afr[kk][0], b, acc[0][t], 0, 0, 0);
            acc[1][t] = __builtin_amdgcn_mfma_f32_16x16x32_bf16(afr[kk][1], b, acc[1][t], 0, 0, 0);
        }
    __syncthreads();
    for (int i = tid; i < 2048; i += 256) {
        int n = i >> 4, c = i & 15;
        *(uint4*)&Bs[n * 136 + c * 8] = *(const uint4*)(Blg + n * 128 + c * 8);
    }
    __syncthreads();
#pragma unroll
    for (int kk = 0; kk < 4; kk++)
#pragma unroll
        for (int t = 0; t < 8; t++) {
            short8 b = *(const short8*)&Bs[t * 16 * 136 + ldsb + kk * 32];
            acc[0][t] = __builtin_amdgcn_mfma_f32_16x16x32_bf16(afr[kk][0], b, acc[0][t], 0, 0, 0);
            acc[1][t] = __builtin_amdgcn_mfma_f32_16x16x32_bf16(afr[kk][1], b, acc[1][t], 0, 0, 0);
        }
    float csum[8], csq[8];
#pragma unroll
    for (int t = 0; t < 8; t++) { csum[t] = 0.f; csq[t] = 0.f; }
#pragma unroll
    for (int t = 0; t < 8; t++) {
        int col = n16 + 16 * t;
        float bv = bias[col];
#pragma unroll
        for (int mt = 0; mt < 2; mt++) {
#pragma unroll
            for (int r = 0; r < 4; r++) {
                int row = rowbase + mt * 16 + q * 4 + r;
                if (row < N) {
                    float v = acc[mt][t][r] + bv;
                    zout[(size_t)row * 128 + col] = f2bf(v);
                    csum[t] += v;
                    csq[t] += v * v;
                }
            }
        }
    }
#pragma unroll
    for (int t = 0; t < 8; t++) {
        csum[t] += __shfl_xor(csum[t], 16);
        csum[t] += __shfl_xor(csum[t], 32);
        csq[t] += __shfl_xor(csq[t], 16);
        csq[t] += __shfl_xor(csq[t], 32);
    }
    __syncthreads();
    float* red = (float*)Bs;
    if (q == 0) {
#pragma unroll
        for (int t = 0; t < 8; t++) {
            int col = n16 + 16 * t;
            red[wave * 128 + col] = csum[t];
            red[512 + wave * 128 + col] = csq[t];
        }
    }
    __syncthreads();
    if (tid < 128) {
        float s = 0.f, qq = 0.f;
#pragma unroll
        for (int w = 0; w < 4; w++) {
            s += red[w * 128 + tid];
            qq += red[512 + w * 128 + tid];
        }
        unsafeAtomicAdd(&sum_out[tid], s);
        unsafeAtomicAdd(&sq_out[tid], qq);
    }
}

__global__ __launch_bounds__(256, 4) void gemm_mfma_bn_k(
        const unsigned short* __restrict__ Zin,
        const float* __restrict__ sum_in, const float* __restrict__ sq_in,
        const float* __restrict__ gamma, const float* __restrict__ beta,
        float invN,
        const unsigned short* __restrict__ Bhg, const unsigned short* __restrict__ Blg,
        const float* __restrict__ bias, unsigned short* __restrict__ zout,
        float* __restrict__ sum_out, float* __restrict__ sq_out, int N) {
    __shared__ unsigned short Bs[128 * 136];
    __shared__ float sc[128], sh[128];
    int tid = threadIdx.x;
    int wave = tid >> 6, lane = tid & 63;
    int n16 = lane & 15, q = lane >> 4;
    int rowbase = blockIdx.x * 128 + wave * 32;
    for (int i = tid; i < 2048; i += 256) {
        int n = i >> 4, c = i & 15;
        *(uint4*)&Bs[n * 136 + c * 8] = *(const uint4*)(Bhg + n * 128 + c * 8);
    }
    if (tid < 128) {
        float mean = sum_in[tid] * invN;
        float var = fmaxf(sq_in[tid] * invN - mean * mean, 0.f);
        float s = gamma[tid] * rsqrtf(var + 1e-5f);
        sc[tid] = s;
        sh[tid] = beta[tid] - mean * s;
    }
    __syncthreads();
    short8 afr[4][2];
#pragma unroll
    for (int kk = 0; kk < 4; kk++)
#pragma unroll
        for (int mt = 0; mt < 2; mt++) {
            int ar = rowbase + mt * 16 + n16;
            ar = min(ar, N - 1);
            short8 raw = *(const short8*)(Zin + (size_t)ar * 128 + kk * 32 + q * 8);
            short8 outv;
#pragma unroll
            for (int i = 0; i < 8; i++) {
                int col = kk * 32 + q * 8 + i;
                float f = bf2f((unsigned short)raw[i]);
                float v = fmaxf(fmaf(f, sc[col], sh[col]), 0.f);
                outv[i] = (short)f2bf(v);
            }
            afr[kk][mt] = outv;
        }
    f32x4 acc[2][8];
#pragma unroll
    for (int mt = 0; mt < 2; mt++)
#pragma unroll
        for (int t = 0; t < 8; t++) acc[mt][t] = (f32x4){0.f, 0.f, 0.f, 0.f};
    int ldsb = n16 * 136 + q * 8;
#pragma unroll
    for (int kk = 0; kk < 4; kk++)
#pragma unroll
        for (int t = 0; t < 8; t++) {
            short8 b = *(const short8*)&Bs[t * 16 * 136 + ldsb + kk * 32];
            acc[0][t] = __builtin_amdgcn_mfma_f32_16x16x32_bf16(afr[kk][0], b, acc[0][t], 0, 0, 0);
            acc[1][t] = __builtin_amdgcn_mfma_f32_16x16x32_bf16(afr[kk][1], b, acc[1][t], 0, 0, 0);
        }
    __syncthreads();
    for (int i = tid; i < 2048; i += 256) {
        int n = i >> 4, c = i & 15;
        *(uint4*)&Bs[n * 136 + c * 8] = *(const uint4*)(Blg + n * 128 + c * 8);
    }
    __syncthreads();
#pragma unroll
    for (int kk = 0; kk < 4; kk++)
#pragma unroll
        for (int t = 0; t < 8; t++) {
            short8 b = *(const short8*)&Bs[t * 16 * 136 + ldsb + kk * 32];
            acc[0][t] = __builtin_amdgcn_mfma_f32_16x16x32_bf16(afr[kk][0], b, acc[0][t], 0, 0, 0);
            acc[1][t] = __builtin_amdgcn_mfma_f32_16x16x32_bf16(afr[kk][1], b, acc[1][t], 0, 0, 0);
        }
    float csum[8], csq[8];
#pragma unroll
    for (int t = 0; t < 8; t++) { csum[t] = 0.f; csq[t] = 0.f; }
#pragma unroll
    for (int t = 0; t < 8; t++) {
        int col = n16 + 16 * t;
        float bv = bias[col];
#pragma unroll
        for (int mt = 0; mt < 2; mt++) {
#pragma unroll
            for (int r = 0; r < 4; r++) {
                int row = rowbase + mt * 16 + q * 4 + r;
                if (row < N) {
                    float v = acc[mt][t][r] + bv;
                    zout[(size_t)row * 128 + col] = f2bf(v);
                    csum[t] += v;
                    csq[t] += v * v;
                }
            }
        }
    }
#pragma unroll
    for (int t = 0; t < 8; t++) {
        csum[t] += __shfl_xor(csum[t], 16);
        csum[t] += __shfl_xor(csum[t], 32);
        csq[t] += __shfl_xor(csq[t], 16);
        csq[t] += __shfl_xor(csq[t], 32);
    }
    __syncthreads();
    float* red = (float*)Bs;
    if (q == 0) {
#pragma unroll
        for (int t = 0; t < 8; t++) {
            int col = n16 + 16 * t;
            red[wave * 128 + col] = csum[t];
            red[512 + wave * 128 + col] = csq[t];
        }
    }
    __syncthreads();
    if (tid < 128) {
        float s = 0.f, qq = 0.f;
#pragma unroll
        for (int w = 0; w < 4; w++) {
            s += red[w * 128 + tid];
            qq += red[512 + w * 128 + tid];
        }
        unsafeAtomicAdd(&sum_out[tid], s);
        unsafeAtomicAdd(&sq_out[tid], qq);
    }
}

__global__ __launch_bounds__(256) void bn2_k(const unsigned short* __restrict__ z2,
        const float* __restrict__ sum2, const float* __restrict__ sq2,
        const float* __restrict__ gamma, const float* __restrict__ beta,
        float* __restrict__ out, long long n8, float invN) {
    __shared__ float sc[128], sh[128];
    int tid = threadIdx.x;
    if (tid < 128) {
        float mean = sum2[tid] * invN;
        float var = fmaxf(sq2[tid] * invN - mean * mean, 0.f);
        float s = gamma[tid] * rsqrtf(var + 1e-5f);
        sc[tid] = s;
        sh[tid] = beta[tid] - mean * s;
    }
    __syncthreads();
    long long g = (long long)blockIdx.x * 256 + tid;
    if (g >= n8) return;
    uint4 u = ((const uint4*)z2)[g];
    int cb = (int)((g * 8) & 127);
    float4 s0 = *(const float4*)&sc[cb], s1 = *(const float4*)&sc[cb + 4];
    float4 t0 = *(const float4*)&sh[cb], t1 = *(const float4*)&sh[cb + 4];
    float4 o0, o1;
    o0.x = fmaxf(fmaf(bflo(u.x), s0.x, t0.x), 0.f);
    o0.y = fmaxf(fmaf(bfhi(u.x), s0.y, t0.y), 0.f);
    o0.z = fmaxf(fmaf(bflo(u.y), s0.z, t0.z), 0.f);
    o0.w = fmaxf(fmaf(bfhi(u.y), s0.w, t0.w), 0.f);
    o1.x = fmaxf(fmaf(bflo(u.z), s1.x, t1.x), 0.f);
    o1.y = fmaxf(fmaf(bfhi(u.z), s1.y, t1.y), 0.f);
    o1.z = fmaxf(fmaf(bflo(u.w), s1.z, t1.z), 0.f);
    o1.w = fmaxf(fmaf(bfhi(u.w), s1.w, t1.w), 0.f);
    ((float4*)out)[g * 2] = o0;
    ((float4*)out)[g * 2 + 1] = o1;
}

extern "C" void kernel_launch(void* const* d_in, const int* in_sizes, int n_in,
                              void* d_out, int out_size, void* d_ws, size_t ws_size,
                              hipStream_t stream) {
    const float* x   = (const float*)d_in[0];
    const int*   ei  = (const int*)d_in[1];
    const int*   ew  = (const int*)d_in[2];
    const float* hc  = (const float*)d_in[3];
    const float* W1  = (const float*)d_in[4];
    const float* b1  = (const float*)d_in[5];
    const float* g1  = (const float*)d_in[6];
    const float* be1 = (const float*)d_in[7];
    const float* W2  = (const float*)d_in[8];
    const float* b2  = (const float*)d_in[9];
    const float* g2  = (const float*)d_in[10];
    const float* be2 = (const float*)d_in[11];

    int N = in_sizes[0] / 128;
    int E = in_sizes[2];
    int K = in_sizes[3];
    size_t NF = (size_t)N * 128;
    long long n8 = (long long)(NF / 8);
    int NX = (int)((n8 + 255) / 256);

    unsigned short* h = (unsigned short*)d_ws;          // NF ush
    unsigned short* xb = h + NF;                        // NF ush
    unsigned short* z1 = xb;                            // fallback alias
    unsigned short* z2 = h;                             // fallback alias
    unsigned* staging = (unsigned*)(xb + NF);           // N * RCAP u32
    int* cur = (int*)(staging + (size_t)N * RCAP);      // N
    unsigned short* w1h = (unsigned short*)(cur + N);
    unsigned short* w1l = w1h + 16384;
    unsigned short* w2h = w1l + 16384;
    unsigned short* w2l = w2h + 16384;
    float* hwp = (float*)(w2l + 16384);                 // 8
    float* sums = hwp + 8;                              // 512
    float* sum1 = sums, *sq1 = sums + 128, *sum2 = sums + 256, *sq2 = sums + 384;
    int nbuk  = (N + 1023) >> 10;
    int nbukp = (nbuk + 7) & ~7;                        // %8 == 0 for XCD mapping
    int* C = (int*)(sums + 512);                        // nbukp * P2B (transposed)
    int* tot = C + (size_t)nbukp * P2B;                 // nbukp
    unsigned* bucketed = (unsigned*)(tot + nbukp);      // E records
    size_t ws_need = (size_t)((char*)(bucketed + E) - (char*)d_ws);
    bool use_bucketed = (nbukp <= 128) && (N <= (1 << 17)) && (K <= 7)
                        && (ws_need <= ws_size);

    float invN = 1.0f / (float)N;
    int per = (E + P2B - 1) / P2B;

    int prep_grid = use_bucketed ? (3 + NX + P2B) : (3 + NX);
    if (!use_bucketed)
        hipMemsetAsync(cur, 0, (size_t)N * sizeof(int), stream);
    prep_k<<<prep_grid, 256, 0, stream>>>(hc, hwp, sums, W1, W2,
        w1h, w1l, w2h, w2l, (const float4*)x, (uint4*)xb, K, n8,
        ei, C, cur, E, per, nbukp, N, NX);
    if (use_bucketed) {
        scan1_k<<<nbukp, 256, 0, stream>>>(C, tot, nbukp, P2B);
        scatter_k<<<P2B, 256, 0, stream>>>(ei, ei + E, ew, C, tot, bucketed,
                                           E, per, nbukp, K);
        slot3_k<<<nbukp * BPB, 256, 0, stream>>>(bucketed, tot, cur, staging, nbukp);
    } else {
        slot_k<<<(E + 255) / 256, 256, 0, stream>>>(ei, ei + E, ew, cur, staging, E, K);
    }
    {
        long long tot_thr = (long long)N * 64;
        gather_k<<<(int)((tot_thr + 255) / 256), 256, 0, stream>>>(
            xb, staging, cur, hwp, h, N);
    }
    int gblocks = (N + 127) / 128;                      // legacy grid
    int gblocks2 = (N + 255) / 256;                     // coop grid (2 tiles/blk)
    float* outf = (float*)d_out;
    hipError_t ce = hipErrorUnknown;
    if (gblocks2 <= 512) {                              // 2 blocks/CU co-residency
        void* args[] = { (void*)&h, (void*)&w1h, (void*)&w1l,
                         (void*)&b1, (void*)&g1, (void*)&be1,
                         (void*)&w2h, (void*)&w2l,
                         (void*)&b2, (void*)&g2, (void*)&be2,
                         (void*)&sums, (void*)&outf, (void*)&invN, (void*)&N };
        ce = hipLaunchCooperativeKernel((const void*)mlp_coop_k,
                 dim3(gblocks2), dim3(256), args, 0, stream);
    }
    if (ce != hipSuccess) {                             // legacy fallback path
        gemm_mfma_k<<<gblocks, 256, 0, stream>>>(h, w1h, w1l, b1, z1, sum1, sq1, N);
        gemm_mfma_bn_k<<<gblocks, 256, 0, stream>>>(z1, sum1, sq1, g1, be1, invN,
            w2h, w2l, b2, z2, sum2, sq2, N);
        bn2_k<<<NX, 256, 0, stream>>>(z2, sum2, sq2, g2, be2, outf, n8, invN);
    }
}

// Round 9
// 422.713 us; speedup vs baseline: 1.3283x; 1.1002x over previous
//
#include <hip/hip_runtime.h>
#include <hip/hip_bf16.h>

// ---------------------------------------------------------------------------
// SPN layer (R17): prep{softmax||Wsplit||x->bf16||count||zero-cur} -> scan1 ->
// scatter(+inline bucket-base scan) -> slot3(+inline scan) -> gather ->
// gemm1 -> gemm2+fusedBN1 -> bn2.
// R14-R16 (cooperative fused MLP) falsified: even with HW fadd atomics,
// agent-scope loads and a 256-VGPR budget it lands at 180us (MfmaUtil 2.8%,
// residual spill from unified VGPR+AGPR pressure, grid-limited occupancy,
// 2 grid syncs) vs ~130-160us for the legacy 3-kernel MLP. Reverted to the
// verified R13 MLP; kept the merged edge pipeline (2 fewer launches).
// ---------------------------------------------------------------------------

#define RCAP 64    // slots per row; P(Poisson(16) > 64) ~ 1e-20 per row
#define P2B 256    // blocks in count/scatter passes
#define BPB 4      // blocks per bucket in slot3

typedef __attribute__((ext_vector_type(8))) short short8;
typedef __attribute__((ext_vector_type(4))) float f32x4;

__device__ inline unsigned short f2bf(float v) {           // RNE bf16 round
    unsigned int u = __float_as_uint(v);
    return (unsigned short)((u + 0x7fffu + ((u >> 16) & 1u)) >> 16);
}
__device__ inline float bf2f(unsigned int u) { return __uint_as_float(u << 16); }
__device__ inline float bflo(unsigned int u) { return __uint_as_float(u << 16); }
__device__ inline float bfhi(unsigned int u) { return __uint_as_float(u & 0xFFFF0000u); }

// --- prep: [0]=softmax+zero stats, [1..2]=W split, [3..3+NX)=x->bf16,
//     [3+NX..3+NX+P2B) = edge-count histogram + zero cur (bucketed path) ----
__global__ __launch_bounds__(256) void prep_k(
        const float* __restrict__ hc, float* __restrict__ hwp, float* __restrict__ sums,
        const float* __restrict__ W1, const float* __restrict__ W2,
        unsigned short* __restrict__ w1h, unsigned short* __restrict__ w1l,
        unsigned short* __restrict__ w2h, unsigned short* __restrict__ w2l,
        const float4* __restrict__ x4, uint4* __restrict__ xb, int K, long long n8,
        const int* __restrict__ rows, int* __restrict__ C, int* __restrict__ cur,
        int E, int per, int nbukp, int N, int NX) {
    __shared__ int hist[128];
    int b = blockIdx.x, tid = threadIdx.x;
    if (b == 0) {                                    // softmax + zero stats
        sums[tid] = 0.f; sums[tid + 256] = 0.f;
        if (tid == 0) {
            float tmp[8];
            float m = -1e30f;
            for (int k = 0; k < K; ++k) m = fmaxf(m, hc[k]);
            float s = 0.f;
            for (int k = 0; k < K; ++k) { float e = __expf(hc[k] - m); tmp[k] = e; s += e; }
            float inv = 1.f / s;
            for (int k = 0; k < 8; ++k) hwp[k] = 0.f;
            for (int k = 0; k < K; ++k) hwp[k + 1] = tmp[k] * inv;
        }
        return;
    }
    if (b <= 2) {                                    // W split (transposed hi/lo)
        const float* W = (b == 2) ? W2 : W1;
        unsigned short* th = (b == 2) ? w2h : w1h;
        unsigned short* tl = (b == 2) ? w2l : w1l;
        for (int i = tid; i < 16384; i += 256) {
            int k = i >> 7, n = i & 127;
            float v = W[k * 128 + n];
            unsigned short hi = f2bf(v);
            th[n * 128 + k] = hi;
            tl[n * 128 + k] = f2bf(v - bf2f(hi));
        }
        return;
    }
    if (b < 3 + NX) {                                // x -> bf16
        long long g = (long long)(b - 3) * 256 + tid;
        if (g >= n8) return;
        float4 a = x4[g * 2], c = x4[g * 2 + 1];
        union { unsigned short us[8]; uint4 v; } o;
        o.us[0] = f2bf(a.x); o.us[1] = f2bf(a.y); o.us[2] = f2bf(a.z); o.us[3] = f2bf(a.w);
        o.us[4] = f2bf(c.x); o.us[5] = f2bf(c.y); o.us[6] = f2bf(c.z); o.us[7] = f2bf(c.w);
        xb[g] = o.v;
        return;
    }
    // count role (only launched when bucketed): histogram of row>>10 + zero cur
    int cblk = b - 3 - NX;
    for (int i = tid; i < nbukp; i += 256) hist[i] = 0;
    __syncthreads();
    int e0 = cblk * per, e1 = min(E, e0 + per);
    for (int e = e0 + tid; e < e1; e += 256)
        atomicAdd(&hist[rows[e] >> 10], 1);
    __syncthreads();
    for (int i = tid; i < nbukp; i += 256) C[i * P2B + cblk] = hist[i];
    int zper = (N + P2B - 1) / P2B;
    int z0 = cblk * zper, z1 = min(N, z0 + zper);
    for (int i = z0 + tid; i < z1; i += 256) cur[i] = 0;
}

// P2a: block b scans bucket-b's row of C (coalesced; Hillis-Steele in LDS);
// C becomes within-bucket exclusive prefix; tot[b] = bucket total.
__global__ __launch_bounds__(256) void scan1_k(int* __restrict__ C,
        int* __restrict__ tot, int nbukp, int nblk) {
    __shared__ int buf[256];
    int b = blockIdx.x, tid = threadIdx.x;
    int v = (tid < nblk) ? C[b * P2B + tid] : 0;
    buf[tid] = v;
    __syncthreads();
#pragma unroll
    for (int off = 1; off < 256; off <<= 1) {
        int t = (tid >= off) ? buf[tid - off] : 0;
        __syncthreads();
        buf[tid] += t;
        __syncthreads();
    }
    if (tid < nblk) C[b * P2B + tid] = buf[tid] - v;     // exclusive
    if (tid == 255) tot[b] = buf[255];
}

// P2b: bucket-grouped 4B records: d | col<<3 | (row&1023)<<20
// bucket bases derived inline from tot[] (scan2 folded into prologue)
__global__ __launch_bounds__(256) void scatter_k(const int* __restrict__ rows,
        const int* __restrict__ cols, const int* __restrict__ ew,
        const int* __restrict__ O, const int* __restrict__ tot,
        unsigned* __restrict__ bucketed, int E, int per, int nbukp, int K) {
    __shared__ int buf[128];
    __shared__ unsigned curs[128];
    int blk = blockIdx.x, tid = threadIdx.x;
    int v = (tid < 128 && tid < nbukp) ? tot[tid] : 0;
    if (tid < 128) buf[tid] = v;
    __syncthreads();
#pragma unroll
    for (int off = 1; off < 128; off <<= 1) {
        int t = (tid >= off && tid < 128) ? buf[tid - off] : 0;
        __syncthreads();
        if (tid < 128) buf[tid] += t;
        __syncthreads();
    }
    if (tid < nbukp)
        curs[tid] = (unsigned)(O[tid * P2B + blk] + buf[tid] - v);  // excl base
    __syncthreads();
    int e0 = blk * per, e1 = min(E, e0 + per);
    for (int e = e0 + tid; e < e1; e += 256) {
        int r = rows[e];
        int c = cols[e];
        int d = ew[e];
        if (d < 1 || d > K) d = 0;                   // hwp[0] = 0 -> weight 0
        unsigned idx = atomicAdd(&curs[r >> 10], 1u);
        bucketed[idx] = (unsigned)d | ((unsigned)c << 3) | ((unsigned)(r & 1023) << 20);
    }
}

// P3: ticket + 4B staging scatter, one 1024-row bucket per BPB-block group.
// blockIdx % nbukp keeps a bucket's blocks on one XCD (nbukp % 8 == 0).
__global__ __launch_bounds__(256) void slot3_k(const unsigned* __restrict__ bucketed,
        const int* __restrict__ tot, int* __restrict__ cur,
        unsigned* __restrict__ staging, int nbukp) {
    __shared__ int buf[128];
    int tid = threadIdx.x;
    if (tid < 128) buf[tid] = (tid < nbukp) ? tot[tid] : 0;
    __syncthreads();
#pragma unroll
    for (int off = 1; off < 128; off <<= 1) {
        int t = (tid >= off && tid < 128) ? buf[tid - off] : 0;
        __syncthreads();
        if (tid < 128) buf[tid] += t;
        __syncthreads();
    }
    int bucket = blockIdx.x % nbukp, sub = blockIdx.x / nbukp;
    int s1 = buf[bucket];
    int s0 = s1 - tot[bucket];
    int cnt = s1 - s0;
    int qlo = s0 + (int)((long long)cnt * sub / BPB);
    int qhi = s0 + (int)((long long)cnt * (sub + 1) / BPB);
    int rbase = bucket << 10;
    for (int e = qlo + tid; e < qhi; e += 256) {
        unsigned u = bucketed[e];
        int row = rbase + (int)(u >> 20);
        int s = atomicAdd(&cur[row], 1);
        if (s < RCAP)
            staging[((size_t)row << 6) + s] = u & 0xFFFFFu;
    }
}

// legacy single-pass slot (fallback: N/K out of packing range or ws too small)
__global__ __launch_bounds__(256) void slot_k(const int* __restrict__ rows,
        const int* __restrict__ cols, const int* __restrict__ ew,
        int* __restrict__ cur, unsigned* __restrict__ staging, int E, int K) {
    int e = blockIdx.x * 256 + threadIdx.x;
    if (e >= E) return;
    int r = rows[e];
    int d = ew[e];
    if (d < 1 || d > K) d = 0;
    int s = atomicAdd(&cur[r], 1);
    if (s < RCAP)
        staging[((size_t)r << 6) + s] = (unsigned)d | ((unsigned)cols[e] << 3);
}

// one wave per row, 4 edges per wave-step: each 16-lane group loads one full
// 256B row (uint4/lane). 4B payload records; weight via 8-entry LDS table.
__global__ __launch_bounds__(256) void gather_k(
        const unsigned short* __restrict__ xb, const unsigned* __restrict__ staging,
        const int* __restrict__ cur, const float* __restrict__ hwp,
        unsigned short* __restrict__ h, int N) {
    __shared__ float hwl[8];
    int tid = threadIdx.x;
    if (tid < 8) hwl[tid] = hwp[tid];
    __syncthreads();
    int wid = (blockIdx.x * 256 + tid) >> 6;
    if (wid >= N) return;
    int lane = tid & 63;
    int g4 = lane >> 4, li = lane & 15;
    int deg = __builtin_amdgcn_readfirstlane(cur[wid]);
    deg = min(deg, RCAP);
    const unsigned* ep = staging + ((size_t)wid << 6);
    const unsigned short* xrow = xb + li * 8;          // 16B per lane within row
    float a0 = 0.f, a1 = 0.f, a2 = 0.f, a3 = 0.f;
    float a4 = 0.f, a5 = 0.f, a6 = 0.f, a7 = 0.f;
    if (g4 == 0) {                                     // GIN self term (eps=0)
        uint4 u = *(const uint4*)(xb + (size_t)wid * 128 + li * 8);
        a0 = bflo(u.x); a1 = bfhi(u.x); a2 = bflo(u.y); a3 = bfhi(u.y);
        a4 = bflo(u.z); a5 = bfhi(u.z); a6 = bflo(u.w); a7 = bfhi(u.w);
    }
    int j = 0;
    for (; j + 16 <= deg; j += 16) {
        unsigned p0 = ep[j + g4];
        unsigned p1 = ep[j + 4 + g4];
        unsigned p2 = ep[j + 8 + g4];
        unsigned p3 = ep[j + 12 + g4];
        uint4 u0 = *(const uint4*)(xrow + (size_t)(p0 >> 3) * 128);
        uint4 u1 = *(const uint4*)(xrow + (size_t)(p1 >> 3) * 128);
        uint4 u2 = *(const uint4*)(xrow + (size_t)(p2 >> 3) * 128);
        uint4 u3 = *(const uint4*)(xrow + (size_t)(p3 >> 3) * 128);
        float w0 = hwl[p0 & 7], w1 = hwl[p1 & 7];
        float w2 = hwl[p2 & 7], w3 = hwl[p3 & 7];
        a0 = fmaf(w0, bflo(u0.x), a0); a1 = fmaf(w0, bfhi(u0.x), a1);
        a2 = fmaf(w0, bflo(u0.y), a2); a3 = fmaf(w0, bfhi(u0.y), a3);
        a4 = fmaf(w0, bflo(u0.z), a4); a5 = fmaf(w0, bfhi(u0.z), a5);
        a6 = fmaf(w0, bflo(u0.w), a6); a7 = fmaf(w0, bfhi(u0.w), a7);
        a0 = fmaf(w1, bflo(u1.x), a0); a1 = fmaf(w1, bfhi(u1.x), a1);
        a2 = fmaf(w1, bflo(u1.y), a2); a3 = fmaf(w1, bfhi(u1.y), a3);
        a4 = fmaf(w1, bflo(u1.z), a4); a5 = fmaf(w1, bfhi(u1.z), a5);
        a6 = fmaf(w1, bflo(u1.w), a6); a7 = fmaf(w1, bfhi(u1.w), a7);
        a0 = fmaf(w2, bflo(u2.x), a0); a1 = fmaf(w2, bfhi(u2.x), a1);
        a2 = fmaf(w2, bflo(u2.y), a2); a3 = fmaf(w2, bfhi(u2.y), a3);
        a4 = fmaf(w2, bflo(u2.z), a4); a5 = fmaf(w2, bfhi(u2.z), a5);
        a6 = fmaf(w2, bflo(u2.w), a6); a7 = fmaf(w2, bfhi(u2.w), a7);
        a0 = fmaf(w3, bflo(u3.x), a0); a1 = fmaf(w3, bfhi(u3.x), a1);
        a2 = fmaf(w3, bflo(u3.y), a2); a3 = fmaf(w3, bfhi(u3.y), a3);
        a4 = fmaf(w3, bflo(u3.z), a4); a5 = fmaf(w3, bfhi(u3.z), a5);
        a6 = fmaf(w3, bflo(u3.w), a6); a7 = fmaf(w3, bfhi(u3.w), a7);
    }
    for (; j + 4 <= deg; j += 4) {
        unsigned p = ep[j + g4];
        uint4 u = *(const uint4*)(xrow + (size_t)(p >> 3) * 128);
        float w = hwl[p & 7];
        a0 = fmaf(w, bflo(u.x), a0); a1 = fmaf(w, bfhi(u.x), a1);
        a2 = fmaf(w, bflo(u.y), a2); a3 = fmaf(w, bfhi(u.y), a3);
        a4 = fmaf(w, bflo(u.z), a4); a5 = fmaf(w, bfhi(u.z), a5);
        a6 = fmaf(w, bflo(u.w), a6); a7 = fmaf(w, bfhi(u.w), a7);
    }
    if (j < deg) {                                     // tail 1..3 edges
        int jj = min(j + g4, deg - 1);
        unsigned p = ep[jj];
        float w = (j + g4 < deg) ? hwl[p & 7] : 0.f;
        uint4 u = *(const uint4*)(xrow + (size_t)(p >> 3) * 128);
        a0 = fmaf(w, bflo(u.x), a0); a1 = fmaf(w, bfhi(u.x), a1);
        a2 = fmaf(w, bflo(u.y), a2); a3 = fmaf(w, bfhi(u.y), a3);
        a4 = fmaf(w, bflo(u.z), a4); a5 = fmaf(w, bfhi(u.z), a5);
        a6 = fmaf(w, bflo(u.w), a6); a7 = fmaf(w, bfhi(u.w), a7);
    }
    a0 += __shfl_xor(a0, 16); a1 += __shfl_xor(a1, 16);
    a2 += __shfl_xor(a2, 16); a3 += __shfl_xor(a3, 16);
    a4 += __shfl_xor(a4, 16); a5 += __shfl_xor(a5, 16);
    a6 += __shfl_xor(a6, 16); a7 += __shfl_xor(a7, 16);
    a0 += __shfl_xor(a0, 32); a1 += __shfl_xor(a1, 32);
    a2 += __shfl_xor(a2, 32); a3 += __shfl_xor(a3, 32);
    a4 += __shfl_xor(a4, 32); a5 += __shfl_xor(a5, 32);
    a6 += __shfl_xor(a6, 32); a7 += __shfl_xor(a7, 32);
    if (g4 == 0) {
        uint4 o;
        o.x = (unsigned int)f2bf(a0) | ((unsigned int)f2bf(a1) << 16);
        o.y = (unsigned int)f2bf(a2) | ((unsigned int)f2bf(a3) << 16);
        o.z = (unsigned int)f2bf(a4) | ((unsigned int)f2bf(a5) << 16);
        o.w = (unsigned int)f2bf(a6) | ((unsigned int)f2bf(a7) << 16);
        *(uint4*)(h + (size_t)wid * 128 + li * 8) = o;
    }
}

// --- bf16 MFMA GEMM, 2-pass B staging (hi then lo), A cached in registers.
__global__ __launch_bounds__(256, 4) void gemm_mfma_k(
        const unsigned short* __restrict__ Ain,
        const unsigned short* __restrict__ Bhg, const unsigned short* __restrict__ Blg,
        const float* __restrict__ bias, unsigned short* __restrict__ zout,
        float* __restrict__ sum_out, float* __restrict__ sq_out, int N) {
    __shared__ unsigned short Bs[128 * 136];
    int tid = threadIdx.x;
    int wave = tid >> 6, lane = tid & 63;
    int n16 = lane & 15, q = lane >> 4;
    int rowbase = blockIdx.x * 128 + wave * 32;
    for (int i = tid; i < 2048; i += 256) {            // stage B_hi
        int n = i >> 4, c = i & 15;
        *(uint4*)&Bs[n * 136 + c * 8] = *(const uint4*)(Bhg + n * 128 + c * 8);
    }
    short8 afr[4][2];                                  // all A frags, kept in regs
#pragma unroll
    for (int kk = 0; kk < 4; kk++)
#pragma unroll
        for (int mt = 0; mt < 2; mt++) {
            int ar = rowbase + mt * 16 + n16;
            ar = min(ar, N - 1);
            afr[kk][mt] = *(const short8*)(Ain + (size_t)ar * 128 + kk * 32 + q * 8);
        }
    f32x4 acc[2][8];
#pragma unroll
    for (int mt = 0; mt < 2; mt++)
#pragma unroll
        for (int t = 0; t < 8; t++) acc[mt][t] = (f32x4){0.f, 0.f, 0.f, 0.f};
    __syncthreads();
    int ldsb = n16 * 136 + q * 8;
#pragma unroll
    for (int kk = 0; kk < 4; kk++)
#pragma unroll
        for (int t = 0; t < 8; t++) {
            short8 b = *(const short8*)&Bs[t * 16 * 136 + ldsb + kk * 32];
            acc[0][t] = __builtin_amdgcn_mfma_f32_16x16x32_bf16(afr[kk][0], b, acc[0][t], 0, 0, 0);
            acc[1][t] = __builtin_amdgcn_mfma_f32_16x16x32_bf16(afr[kk][1], b, acc[1][t], 0, 0, 0);
        }
    __syncthreads();
    for (int i = tid; i < 2048; i += 256) {            // stage B_lo
        int n = i >> 4, c = i & 15;
        *(uint4*)&Bs[n * 136 + c * 8] = *(const uint4*)(Blg + n * 128 + c * 8);
    }
    __syncthreads();
#pragma unroll
    for (int kk = 0; kk < 4; kk++)
#pragma unroll
        for (int t = 0; t < 8; t++) {
            short8 b = *(const short8*)&Bs[t * 16 * 136 + ldsb + kk * 32];
            acc[0][t] = __builtin_amdgcn_mfma_f32_16x16x32_bf16(afr[kk][0], b, acc[0][t], 0, 0, 0);
            acc[1][t] = __builtin_amdgcn_mfma_f32_16x16x32_bf16(afr[kk][1], b, acc[1][t], 0, 0, 0);
        }
    // epilogue: bias, store bf16 z, per-column stats
    float csum[8], csq[8];
#pragma unroll
    for (int t = 0; t < 8; t++) { csum[t] = 0.f; csq[t] = 0.f; }
#pragma unroll
    for (int t = 0; t < 8; t++) {
        int col = n16 + 16 * t;
        float bv = bias[col];
#pragma unroll
        for (int mt = 0; mt < 2; mt++) {
#pragma unroll
            for (int r = 0; r < 4; r++) {
                int row = rowbase + mt * 16 + q * 4 + r;
                if (row < N) {
                    float v = acc[mt][t][r] + bv;
                    zout[(size_t)row * 128 + col] = f2bf(v);
                    csum[t] += v;
                    csq[t] += v * v;
                }
            }
        }
    }
#pragma unroll
    for (int t = 0; t < 8; t++) {
        csum[t] += __shfl_xor(csum[t], 16);
        csum[t] += __shfl_xor(csum[t], 32);
        csq[t] += __shfl_xor(csq[t], 16);
        csq[t] += __shfl_xor(csq[t], 32);
    }
    __syncthreads();
    float* red = (float*)Bs;
    if (q == 0) {
#pragma unroll
        for (int t = 0; t < 8; t++) {
            int col = n16 + 16 * t;
            red[wave * 128 + col] = csum[t];
            red[512 + wave * 128 + col] = csq[t];
        }
    }
    __syncthreads();
    if (tid < 128) {
        float s = 0.f, qq = 0.f;
#pragma unroll
        for (int w = 0; w < 4; w++) {
            s += red[w * 128 + tid];
            qq += red[512 + w * 128 + tid];
        }
        unsafeAtomicAdd(&sum_out[tid], s);
        unsafeAtomicAdd(&sq_out[tid], qq);
    }
}

// --- gemm2 with BN1+ReLU fused at A-load: A = f2bf(relu(s*z1+t)).
__global__ __launch_bounds__(256, 4) void gemm_mfma_bn_k(
        const unsigned short* __restrict__ Zin,
        const float* __restrict__ sum_in, const float* __restrict__ sq_in,
        const float* __restrict__ gamma, const float* __restrict__ beta,
        float invN,
        const unsigned short* __restrict__ Bhg, const unsigned short* __restrict__ Blg,
        const float* __restrict__ bias, unsigned short* __restrict__ zout,
        float* __restrict__ sum_out, float* __restrict__ sq_out, int N) {
    __shared__ unsigned short Bs[128 * 136];
    __shared__ float sc[128], sh[128];
    int tid = threadIdx.x;
    int wave = tid >> 6, lane = tid & 63;
    int n16 = lane & 15, q = lane >> 4;
    int rowbase = blockIdx.x * 128 + wave * 32;
    for (int i = tid; i < 2048; i += 256) {            // stage B_hi
        int n = i >> 4, c = i & 15;
        *(uint4*)&Bs[n * 136 + c * 8] = *(const uint4*)(Bhg + n * 128 + c * 8);
    }
    if (tid < 128) {                                   // BN1 constants
        float mean = sum_in[tid] * invN;
        float var = fmaxf(sq_in[tid] * invN - mean * mean, 0.f);
        float s = gamma[tid] * rsqrtf(var + 1e-5f);
        sc[tid] = s;
        sh[tid] = beta[tid] - mean * s;
    }
    __syncthreads();
    short8 afr[4][2];                                  // A = relu-BN(z1), bf16
#pragma unroll
    for (int kk = 0; kk < 4; kk++)
#pragma unroll
        for (int mt = 0; mt < 2; mt++) {
            int ar = rowbase + mt * 16 + n16;
            ar = min(ar, N - 1);
            short8 raw = *(const short8*)(Zin + (size_t)ar * 128 + kk * 32 + q * 8);
            short8 outv;
#pragma unroll
            for (int i = 0; i < 8; i++) {
                int col = kk * 32 + q * 8 + i;
                float f = bf2f((unsigned short)raw[i]);
                float v = fmaxf(fmaf(f, sc[col], sh[col]), 0.f);
                outv[i] = (short)f2bf(v);
            }
            afr[kk][mt] = outv;
        }
    f32x4 acc[2][8];
#pragma unroll
    for (int mt = 0; mt < 2; mt++)
#pragma unroll
        for (int t = 0; t < 8; t++) acc[mt][t] = (f32x4){0.f, 0.f, 0.f, 0.f};
    int ldsb = n16 * 136 + q * 8;
#pragma unroll
    for (int kk = 0; kk < 4; kk++)
#pragma unroll
        for (int t = 0; t < 8; t++) {
            short8 b = *(const short8*)&Bs[t * 16 * 136 + ldsb + kk * 32];
            acc[0][t] = __builtin_amdgcn_mfma_f32_16x16x32_bf16(afr[kk][0], b, acc[0][t], 0, 0, 0);
            acc[1][t] = __builtin_amdgcn_mfma_f32_16x16x32_bf16(afr[kk][1], b, acc[1][t], 0, 0, 0);
        }
    __syncthreads();
    for (int i = tid; i < 2048; i += 256) {            // stage B_lo
        int n = i >> 4, c = i & 15;
        *(uint4*)&Bs[n * 136 + c * 8] = *(const uint4*)(Blg + n * 128 + c * 8);
    }
    __syncthreads();
#pragma unroll
    for (int kk = 0; kk < 4; kk++)
#pragma unroll
        for (int t = 0; t < 8; t++) {
            short8 b = *(const short8*)&Bs[t * 16 * 136 + ldsb + kk * 32];
            acc[0][t] = __builtin_amdgcn_mfma_f32_16x16x32_bf16(afr[kk][0], b, acc[0][t], 0, 0, 0);
            acc[1][t] = __builtin_amdgcn_mfma_f32_16x16x32_bf16(afr[kk][1], b, acc[1][t], 0, 0, 0);
        }
    // epilogue: bias, store bf16 z, per-column stats
    float csum[8], csq[8];
#pragma unroll
    for (int t = 0; t < 8; t++) { csum[t] = 0.f; csq[t] = 0.f; }
#pragma unroll
    for (int t = 0; t < 8; t++) {
        int col = n16 + 16 * t;
        float bv = bias[col];
#pragma unroll
        for (int mt = 0; mt < 2; mt++) {
#pragma unroll
            for (int r = 0; r < 4; r++) {
                int row = rowbase + mt * 16 + q * 4 + r;
                if (row < N) {
                    float v = acc[mt][t][r] + bv;
                    zout[(size_t)row * 128 + col] = f2bf(v);
                    csum[t] += v;
                    csq[t] += v * v;
                }
            }
        }
    }
#pragma unroll
    for (int t = 0; t < 8; t++) {
        csum[t] += __shfl_xor(csum[t], 16);
        csum[t] += __shfl_xor(csum[t], 32);
        csq[t] += __shfl_xor(csq[t], 16);
        csq[t] += __shfl_xor(csq[t], 32);
    }
    __syncthreads();
    float* red = (float*)Bs;
    if (q == 0) {
#pragma unroll
        for (int t = 0; t < 8; t++) {
            int col = n16 + 16 * t;
            red[wave * 128 + col] = csum[t];
            red[512 + wave * 128 + col] = csq[t];
        }
    }
    __syncthreads();
    if (tid < 128) {
        float s = 0.f, qq = 0.f;
#pragma unroll
        for (int w = 0; w < 4; w++) {
            s += red[w * 128 + tid];
            qq += red[512 + w * 128 + tid];
        }
        unsafeAtomicAdd(&sum_out[tid], s);
        unsafeAtomicAdd(&sq_out[tid], qq);
    }
}

// out = relu(BN2(z2))  (bf16 in, f32 out)
__global__ __launch_bounds__(256) void bn2_k(const unsigned short* __restrict__ z2,
        const float* __restrict__ sum2, const float* __restrict__ sq2,
        const float* __restrict__ gamma, const float* __restrict__ beta,
        float* __restrict__ out, long long n8, float invN) {
    __shared__ float sc[128], sh[128];
    int tid = threadIdx.x;
    if (tid < 128) {
        float mean = sum2[tid] * invN;
        float var = fmaxf(sq2[tid] * invN - mean * mean, 0.f);
        float s = gamma[tid] * rsqrtf(var + 1e-5f);
        sc[tid] = s;
        sh[tid] = beta[tid] - mean * s;
    }
    __syncthreads();
    long long g = (long long)blockIdx.x * 256 + tid;
    if (g >= n8) return;
    uint4 u = ((const uint4*)z2)[g];
    int cb = (int)((g * 8) & 127);
    float4 s0 = *(const float4*)&sc[cb], s1 = *(const float4*)&sc[cb + 4];
    float4 t0 = *(const float4*)&sh[cb], t1 = *(const float4*)&sh[cb + 4];
    float4 o0, o1;
    o0.x = fmaxf(fmaf(bflo(u.x), s0.x, t0.x), 0.f);
    o0.y = fmaxf(fmaf(bfhi(u.x), s0.y, t0.y), 0.f);
    o0.z = fmaxf(fmaf(bflo(u.y), s0.z, t0.z), 0.f);
    o0.w = fmaxf(fmaf(bfhi(u.y), s0.w, t0.w), 0.f);
    o1.x = fmaxf(fmaf(bflo(u.z), s1.x, t1.x), 0.f);
    o1.y = fmaxf(fmaf(bfhi(u.z), s1.y, t1.y), 0.f);
    o1.z = fmaxf(fmaf(bflo(u.w), s1.z, t1.z), 0.f);
    o1.w = fmaxf(fmaf(bfhi(u.w), s1.w, t1.w), 0.f);
    ((float4*)out)[g * 2] = o0;
    ((float4*)out)[g * 2 + 1] = o1;
}

extern "C" void kernel_launch(void* const* d_in, const int* in_sizes, int n_in,
                              void* d_out, int out_size, void* d_ws, size_t ws_size,
                              hipStream_t stream) {
    const float* x   = (const float*)d_in[0];
    const int*   ei  = (const int*)d_in[1];
    const int*   ew  = (const int*)d_in[2];
    const float* hc  = (const float*)d_in[3];
    const float* W1  = (const float*)d_in[4];
    const float* b1  = (const float*)d_in[5];
    const float* g1  = (const float*)d_in[6];
    const float* be1 = (const float*)d_in[7];
    const float* W2  = (const float*)d_in[8];
    const float* b2  = (const float*)d_in[9];
    const float* g2  = (const float*)d_in[10];
    const float* be2 = (const float*)d_in[11];

    int N = in_sizes[0] / 128;
    int E = in_sizes[2];
    int K = in_sizes[3];
    size_t NF = (size_t)N * 128;
    long long n8 = (long long)(NF / 8);
    int NX = (int)((n8 + 255) / 256);

    // workspace (aliases: z1 reuses xb after gather; z2 reuses h after gemm1)
    unsigned short* h = (unsigned short*)d_ws;          // NF ush
    unsigned short* xb = h + NF;                        // NF ush
    unsigned short* z1 = xb;                            // alias (xb dead post-gather)
    unsigned short* z2 = h;                             // alias (h dead post-gemm1)
    unsigned* staging = (unsigned*)(xb + NF);           // N * RCAP u32 (25.6 MB)
    int* cur = (int*)(staging + (size_t)N * RCAP);      // N
    unsigned short* w1h = (unsigned short*)(cur + N);
    unsigned short* w1l = w1h + 16384;
    unsigned short* w2h = w1l + 16384;
    unsigned short* w2l = w2h + 16384;
    float* hwp = (float*)(w2l + 16384);                 // 8
    float* sums = hwp + 8;                              // 512
    float* sum1 = sums, *sq1 = sums + 128, *sum2 = sums + 256, *sq2 = sums + 384;
    int nbuk  = (N + 1023) >> 10;
    int nbukp = (nbuk + 7) & ~7;                        // %8 == 0 for XCD mapping
    int* C = (int*)(sums + 512);                        // nbukp * P2B (transposed)
    int* tot = C + (size_t)nbukp * P2B;                 // nbukp
    unsigned* bucketed = (unsigned*)(tot + nbukp);      // E records
    size_t ws_need = (size_t)((char*)(bucketed + E) - (char*)d_ws);
    bool use_bucketed = (nbukp <= 128) && (N <= (1 << 17)) && (K <= 7)
                        && (ws_need <= ws_size);

    float invN = 1.0f / (float)N;
    int per = (E + P2B - 1) / P2B;

    int prep_grid = use_bucketed ? (3 + NX + P2B) : (3 + NX);
    if (!use_bucketed)
        hipMemsetAsync(cur, 0, (size_t)N * sizeof(int), stream);
    prep_k<<<prep_grid, 256, 0, stream>>>(hc, hwp, sums, W1, W2,
        w1h, w1l, w2h, w2l, (const float4*)x, (uint4*)xb, K, n8,
        ei, C, cur, E, per, nbukp, N, NX);
    if (use_bucketed) {
        scan1_k<<<nbukp, 256, 0, stream>>>(C, tot, nbukp, P2B);
        scatter_k<<<P2B, 256, 0, stream>>>(ei, ei + E, ew, C, tot, bucketed,
                                           E, per, nbukp, K);
        slot3_k<<<nbukp * BPB, 256, 0, stream>>>(bucketed, tot, cur, staging, nbukp);
    } else {
        slot_k<<<(E + 255) / 256, 256, 0, stream>>>(ei, ei + E, ew, cur, staging, E, K);
    }
    {
        long long tot_thr = (long long)N * 64;
        gather_k<<<(int)((tot_thr + 255) / 256), 256, 0, stream>>>(
            xb, staging, cur, hwp, h, N);
    }
    int gblocks = (N + 127) / 128;
    gemm_mfma_k<<<gblocks, 256, 0, stream>>>(h, w1h, w1l, b1, z1, sum1, sq1, N);
    gemm_mfma_bn_k<<<gblocks, 256, 0, stream>>>(z1, sum1, sq1, g1, be1, invN,
        w2h, w2l, b2, z2, sum2, sq2, N);
    bn2_k<<<NX, 256, 0, stream>>>(z2, sum2, sq2, g2, be2, (float*)d_out, n8, invN);
}

// Round 10
// 409.152 us; speedup vs baseline: 1.3724x; 1.0331x over previous
//
#include <hip/hip_runtime.h>
#include <hip/hip_bf16.h>

// ---------------------------------------------------------------------------
// SPN layer (R18): prep{softmax||Wsplit||x->bf16||count} -> scan1 ->
// scatter(+inline bucket-base scan) -> slot3s (per-bucket LDS COUNTING SORT:
// compact row-sorted edge array + rowstart[N+1]; replaces R17's slot3
// ticket-atomic scatter -- no global atomics, no RCAP cap, no cur) ->
// gather (rowstart/rowsorted, contiguous payloads) -> gemm1 ->
// gemm2+fusedBN1 -> bn2.
// gather measured at ~87% of its structural floor (FETCH 190MB = each XCD
// fills ~the whole 25.6MB xb table; random columns -> no locality left).
// ---------------------------------------------------------------------------

#define RCAP 64    // fallback path only
#define P2B 256    // blocks in count/scatter passes

typedef __attribute__((ext_vector_type(8))) short short8;
typedef __attribute__((ext_vector_type(4))) float f32x4;

__device__ inline unsigned short f2bf(float v) {           // RNE bf16 round
    unsigned int u = __float_as_uint(v);
    return (unsigned short)((u + 0x7fffu + ((u >> 16) & 1u)) >> 16);
}
__device__ inline float bf2f(unsigned int u) { return __uint_as_float(u << 16); }
__device__ inline float bflo(unsigned int u) { return __uint_as_float(u << 16); }
__device__ inline float bfhi(unsigned int u) { return __uint_as_float(u & 0xFFFF0000u); }

// --- prep: [0]=softmax+zero stats, [1..2]=W split, [3..3+NX)=x->bf16,
//     [3+NX..3+NX+P2B) = edge-count histogram (bucketed path) --------------
__global__ __launch_bounds__(256) void prep_k(
        const float* __restrict__ hc, float* __restrict__ hwp, float* __restrict__ sums,
        const float* __restrict__ W1, const float* __restrict__ W2,
        unsigned short* __restrict__ w1h, unsigned short* __restrict__ w1l,
        unsigned short* __restrict__ w2h, unsigned short* __restrict__ w2l,
        const float4* __restrict__ x4, uint4* __restrict__ xb, int K, long long n8,
        const int* __restrict__ rows, int* __restrict__ C,
        int E, int per, int nbukp, int N, int NX) {
    __shared__ int hist[128];
    int b = blockIdx.x, tid = threadIdx.x;
    if (b == 0) {                                    // softmax + zero stats
        sums[tid] = 0.f; sums[tid + 256] = 0.f;
        if (tid == 0) {
            float tmp[8];
            float m = -1e30f;
            for (int k = 0; k < K; ++k) m = fmaxf(m, hc[k]);
            float s = 0.f;
            for (int k = 0; k < K; ++k) { float e = __expf(hc[k] - m); tmp[k] = e; s += e; }
            float inv = 1.f / s;
            for (int k = 0; k < 8; ++k) hwp[k] = 0.f;
            for (int k = 0; k < K; ++k) hwp[k + 1] = tmp[k] * inv;
        }
        return;
    }
    if (b <= 2) {                                    // W split (transposed hi/lo)
        const float* W = (b == 2) ? W2 : W1;
        unsigned short* th = (b == 2) ? w2h : w1h;
        unsigned short* tl = (b == 2) ? w2l : w1l;
        for (int i = tid; i < 16384; i += 256) {
            int k = i >> 7, n = i & 127;
            float v = W[k * 128 + n];
            unsigned short hi = f2bf(v);
            th[n * 128 + k] = hi;
            tl[n * 128 + k] = f2bf(v - bf2f(hi));
        }
        return;
    }
    if (b < 3 + NX) {                                // x -> bf16
        long long g = (long long)(b - 3) * 256 + tid;
        if (g >= n8) return;
        float4 a = x4[g * 2], c = x4[g * 2 + 1];
        union { unsigned short us[8]; uint4 v; } o;
        o.us[0] = f2bf(a.x); o.us[1] = f2bf(a.y); o.us[2] = f2bf(a.z); o.us[3] = f2bf(a.w);
        o.us[4] = f2bf(c.x); o.us[5] = f2bf(c.y); o.us[6] = f2bf(c.z); o.us[7] = f2bf(c.w);
        xb[g] = o.v;
        return;
    }
    // count role (bucketed path only): histogram of row>>10
    int cblk = b - 3 - NX;
    for (int i = tid; i < nbukp; i += 256) hist[i] = 0;
    __syncthreads();
    int e0 = cblk * per, e1 = min(E, e0 + per);
    for (int e = e0 + tid; e < e1; e += 256)
        atomicAdd(&hist[rows[e] >> 10], 1);
    __syncthreads();
    for (int i = tid; i < nbukp; i += 256) C[i * P2B + cblk] = hist[i];
}

// P2a: block b scans bucket-b's row of C (coalesced; Hillis-Steele in LDS);
// C becomes within-bucket exclusive prefix; tot[b] = bucket total.
__global__ __launch_bounds__(256) void scan1_k(int* __restrict__ C,
        int* __restrict__ tot, int nbukp, int nblk) {
    __shared__ int buf[256];
    int b = blockIdx.x, tid = threadIdx.x;
    int v = (tid < nblk) ? C[b * P2B + tid] : 0;
    buf[tid] = v;
    __syncthreads();
#pragma unroll
    for (int off = 1; off < 256; off <<= 1) {
        int t = (tid >= off) ? buf[tid - off] : 0;
        __syncthreads();
        buf[tid] += t;
        __syncthreads();
    }
    if (tid < nblk) C[b * P2B + tid] = buf[tid] - v;     // exclusive
    if (tid == 255) tot[b] = buf[255];
}

// P2b: bucket-grouped 4B records: d | col<<3 | (row&1023)<<20
// bucket bases derived inline from tot[]
__global__ __launch_bounds__(256) void scatter_k(const int* __restrict__ rows,
        const int* __restrict__ cols, const int* __restrict__ ew,
        const int* __restrict__ O, const int* __restrict__ tot,
        unsigned* __restrict__ bucketed, int E, int per, int nbukp, int K) {
    __shared__ int buf[128];
    __shared__ unsigned curs[128];
    int blk = blockIdx.x, tid = threadIdx.x;
    int v = (tid < 128 && tid < nbukp) ? tot[tid] : 0;
    if (tid < 128) buf[tid] = v;
    __syncthreads();
#pragma unroll
    for (int off = 1; off < 128; off <<= 1) {
        int t = (tid >= off && tid < 128) ? buf[tid - off] : 0;
        __syncthreads();
        if (tid < 128) buf[tid] += t;
        __syncthreads();
    }
    if (tid < nbukp)
        curs[tid] = (unsigned)(O[tid * P2B + blk] + buf[tid] - v);  // excl base
    __syncthreads();
    int e0 = blk * per, e1 = min(E, e0 + per);
    for (int e = e0 + tid; e < e1; e += 256) {
        int r = rows[e];
        int c = cols[e];
        int d = ew[e];
        if (d < 1 || d > K) d = 0;                   // hwp[0] = 0 -> weight 0
        unsigned idx = atomicAdd(&curs[r >> 10], 1u);
        bucketed[idx] = (unsigned)d | ((unsigned)c << 3) | ((unsigned)(r & 1023) << 20);
    }
}

// P3: per-bucket LDS counting sort -> compact row-sorted records + rowstart.
// One block per bucket. No global atomics; removes cur, RCAP, staging pad.
__global__ __launch_bounds__(256) void slot3s_k(const unsigned* __restrict__ bucketed,
        const int* __restrict__ tot, unsigned* __restrict__ rowsorted,
        int* __restrict__ rowstart, int nbukp, int N) {
    __shared__ int bbuf[128];
    __shared__ int cnt[1024];
    __shared__ int pre[1024];
    __shared__ int sb[256];
    int tid = threadIdx.x;
    // bucket-base scan over tot (inclusive H-S on 128)
    if (tid < 128) bbuf[tid] = (tid < nbukp) ? tot[tid] : 0;
    __syncthreads();
#pragma unroll
    for (int off = 1; off < 128; off <<= 1) {
        int t = (tid >= off && tid < 128) ? bbuf[tid - off] : 0;
        __syncthreads();
        if (tid < 128) bbuf[tid] += t;
        __syncthreads();
    }
    int bucket = blockIdx.x;
    int s1 = bbuf[bucket];
    int cntb = tot[bucket];
    int s0 = s1 - cntb;
    int rbase = bucket << 10;
    int rlim = min(1024, N - rbase);                 // <=0 for padded buckets
    if (bucket == 0 && tid == 0) rowstart[N] = bbuf[127];   // grand total = E
    // pass 1: per-row histogram
    for (int i = tid; i < 1024; i += 256) cnt[i] = 0;
    __syncthreads();
    for (int e = s0 + tid; e < s1; e += 256)
        atomicAdd(&cnt[bucketed[e] >> 20], 1);
    __syncthreads();
    // exclusive prefix over 1024 (4 per thread + 256-wide H-S)
    int b4 = tid * 4;
    int c0 = cnt[b4], c1 = cnt[b4 + 1], c2 = cnt[b4 + 2], c3 = cnt[b4 + 3];
    int ts = c0 + c1 + c2 + c3;
    sb[tid] = ts;
    __syncthreads();
#pragma unroll
    for (int off = 1; off < 256; off <<= 1) {
        int t = (tid >= off) ? sb[tid - off] : 0;
        __syncthreads();
        sb[tid] += t;
        __syncthreads();
    }
    int eb = sb[tid] - ts;                           // exclusive group base
    pre[b4] = eb;
    pre[b4 + 1] = eb + c0;
    pre[b4 + 2] = eb + c0 + c1;
    pre[b4 + 3] = eb + c0 + c1 + c2;
    __syncthreads();
    // rowstart (absolute) for this bucket's rows
    for (int lr = tid; lr < rlim; lr += 256)
        rowstart[rbase + lr] = s0 + pre[lr];
    // cursors = prefix
    for (int i = tid; i < 1024; i += 256) cnt[i] = pre[i];
    __syncthreads();
    // pass 2: place records (LDS cursor atomics only)
    for (int e = s0 + tid; e < s1; e += 256) {
        unsigned u = bucketed[e];
        int lr = (int)(u >> 20);
        int p = atomicAdd(&cnt[lr], 1);
        rowsorted[s0 + p] = u & 0xFFFFFu;
    }
}

// legacy single-pass slot (fallback: N/K out of packing range or ws too small)
__global__ __launch_bounds__(256) void slot_k(const int* __restrict__ rows,
        const int* __restrict__ cols, const int* __restrict__ ew,
        int* __restrict__ cur, unsigned* __restrict__ staging, int E, int K) {
    int e = blockIdx.x * 256 + threadIdx.x;
    if (e >= E) return;
    int r = rows[e];
    int d = ew[e];
    if (d < 1 || d > K) d = 0;
    int s = atomicAdd(&cur[r], 1);
    if (s < RCAP)
        staging[((size_t)r << 6) + s] = (unsigned)d | ((unsigned)cols[e] << 3);
}

// one wave per row, 4 edges per wave-step: each 16-lane group loads one full
// 256B row (uint4/lane). Compact payloads from rowsorted[rowstart[r]..).
__global__ __launch_bounds__(256) void gather_k(
        const unsigned short* __restrict__ xb, const unsigned* __restrict__ rowsorted,
        const int* __restrict__ rowstart, const float* __restrict__ hwp,
        unsigned short* __restrict__ h, int N) {
    __shared__ float hwl[8];
    int tid = threadIdx.x;
    if (tid < 8) hwl[tid] = hwp[tid];
    __syncthreads();
    int wid = (blockIdx.x * 256 + tid) >> 6;
    if (wid >= N) return;
    int lane = tid & 63;
    int g4 = lane >> 4, li = lane & 15;
    int st = rowstart[wid];
    int deg = rowstart[wid + 1] - st;
    const unsigned* ep = rowsorted + st;
    const unsigned short* xrow = xb + li * 8;          // 16B per lane within row
    float a0 = 0.f, a1 = 0.f, a2 = 0.f, a3 = 0.f;
    float a4 = 0.f, a5 = 0.f, a6 = 0.f, a7 = 0.f;
    if (g4 == 0) {                                     // GIN self term (eps=0)
        uint4 u = *(const uint4*)(xb + (size_t)wid * 128 + li * 8);
        a0 = bflo(u.x); a1 = bfhi(u.x); a2 = bflo(u.y); a3 = bfhi(u.y);
        a4 = bflo(u.z); a5 = bfhi(u.z); a6 = bflo(u.w); a7 = bfhi(u.w);
    }
    int j = 0;
    for (; j + 16 <= deg; j += 16) {
        unsigned p0 = ep[j + g4];
        unsigned p1 = ep[j + 4 + g4];
        unsigned p2 = ep[j + 8 + g4];
        unsigned p3 = ep[j + 12 + g4];
        uint4 u0 = *(const uint4*)(xrow + (size_t)(p0 >> 3) * 128);
        uint4 u1 = *(const uint4*)(xrow + (size_t)(p1 >> 3) * 128);
        uint4 u2 = *(const uint4*)(xrow + (size_t)(p2 >> 3) * 128);
        uint4 u3 = *(const uint4*)(xrow + (size_t)(p3 >> 3) * 128);
        float w0 = hwl[p0 & 7], w1 = hwl[p1 & 7];
        float w2 = hwl[p2 & 7], w3 = hwl[p3 & 7];
        a0 = fmaf(w0, bflo(u0.x), a0); a1 = fmaf(w0, bfhi(u0.x), a1);
        a2 = fmaf(w0, bflo(u0.y), a2); a3 = fmaf(w0, bfhi(u0.y), a3);
        a4 = fmaf(w0, bflo(u0.z), a4); a5 = fmaf(w0, bfhi(u0.z), a5);
        a6 = fmaf(w0, bflo(u0.w), a6); a7 = fmaf(w0, bfhi(u0.w), a7);
        a0 = fmaf(w1, bflo(u1.x), a0); a1 = fmaf(w1, bfhi(u1.x), a1);
        a2 = fmaf(w1, bflo(u1.y), a2); a3 = fmaf(w1, bfhi(u1.y), a3);
        a4 = fmaf(w1, bflo(u1.z), a4); a5 = fmaf(w1, bfhi(u1.z), a5);
        a6 = fmaf(w1, bflo(u1.w), a6); a7 = fmaf(w1, bfhi(u1.w), a7);
        a0 = fmaf(w2, bflo(u2.x), a0); a1 = fmaf(w2, bfhi(u2.x), a1);
        a2 = fmaf(w2, bflo(u2.y), a2); a3 = fmaf(w2, bfhi(u2.y), a3);
        a4 = fmaf(w2, bflo(u2.z), a4); a5 = fmaf(w2, bfhi(u2.z), a5);
        a6 = fmaf(w2, bflo(u2.w), a6); a7 = fmaf(w2, bfhi(u2.w), a7);
        a0 = fmaf(w3, bflo(u3.x), a0); a1 = fmaf(w3, bfhi(u3.x), a1);
        a2 = fmaf(w3, bflo(u3.y), a2); a3 = fmaf(w3, bfhi(u3.y), a3);
        a4 = fmaf(w3, bflo(u3.z), a4); a5 = fmaf(w3, bfhi(u3.z), a5);
        a6 = fmaf(w3, bflo(u3.w), a6); a7 = fmaf(w3, bfhi(u3.w), a7);
    }
    for (; j + 4 <= deg; j += 4) {
        unsigned p = ep[j + g4];
        uint4 u = *(const uint4*)(xrow + (size_t)(p >> 3) * 128);
        float w = hwl[p & 7];
        a0 = fmaf(w, bflo(u.x), a0); a1 = fmaf(w, bfhi(u.x), a1);
        a2 = fmaf(w, bflo(u.y), a2); a3 = fmaf(w, bfhi(u.y), a3);
        a4 = fmaf(w, bflo(u.z), a4); a5 = fmaf(w, bfhi(u.z), a5);
        a6 = fmaf(w, bflo(u.w), a6); a7 = fmaf(w, bfhi(u.w), a7);
    }
    if (j < deg) {                                     // tail 1..3 edges
        int jj = min(j + g4, deg - 1);
        unsigned p = ep[jj];
        float w = (j + g4 < deg) ? hwl[p & 7] : 0.f;
        uint4 u = *(const uint4*)(xrow + (size_t)(p >> 3) * 128);
        a0 = fmaf(w, bflo(u.x), a0); a1 = fmaf(w, bfhi(u.x), a1);
        a2 = fmaf(w, bflo(u.y), a2); a3 = fmaf(w, bfhi(u.y), a3);
        a4 = fmaf(w, bflo(u.z), a4); a5 = fmaf(w, bfhi(u.z), a5);
        a6 = fmaf(w, bflo(u.w), a6); a7 = fmaf(w, bfhi(u.w), a7);
    }
    a0 += __shfl_xor(a0, 16); a1 += __shfl_xor(a1, 16);
    a2 += __shfl_xor(a2, 16); a3 += __shfl_xor(a3, 16);
    a4 += __shfl_xor(a4, 16); a5 += __shfl_xor(a5, 16);
    a6 += __shfl_xor(a6, 16); a7 += __shfl_xor(a7, 16);
    a0 += __shfl_xor(a0, 32); a1 += __shfl_xor(a1, 32);
    a2 += __shfl_xor(a2, 32); a3 += __shfl_xor(a3, 32);
    a4 += __shfl_xor(a4, 32); a5 += __shfl_xor(a5, 32);
    a6 += __shfl_xor(a6, 32); a7 += __shfl_xor(a7, 32);
    if (g4 == 0) {
        uint4 o;
        o.x = (unsigned int)f2bf(a0) | ((unsigned int)f2bf(a1) << 16);
        o.y = (unsigned int)f2bf(a2) | ((unsigned int)f2bf(a3) << 16);
        o.z = (unsigned int)f2bf(a4) | ((unsigned int)f2bf(a5) << 16);
        o.w = (unsigned int)f2bf(a6) | ((unsigned int)f2bf(a7) << 16);
        *(uint4*)(h + (size_t)wid * 128 + li * 8) = o;
    }
}

// legacy staged gather (fallback path; staging + cur)
__global__ __launch_bounds__(256) void gather_stg_k(
        const unsigned short* __restrict__ xb, const unsigned* __restrict__ staging,
        const int* __restrict__ cur, const float* __restrict__ hwp,
        unsigned short* __restrict__ h, int N) {
    __shared__ float hwl[8];
    int tid = threadIdx.x;
    if (tid < 8) hwl[tid] = hwp[tid];
    __syncthreads();
    int wid = (blockIdx.x * 256 + tid) >> 6;
    if (wid >= N) return;
    int lane = tid & 63;
    int g4 = lane >> 4, li = lane & 15;
    int deg = __builtin_amdgcn_readfirstlane(cur[wid]);
    deg = min(deg, RCAP);
    const unsigned* ep = staging + ((size_t)wid << 6);
    const unsigned short* xrow = xb + li * 8;
    float a0 = 0.f, a1 = 0.f, a2 = 0.f, a3 = 0.f;
    float a4 = 0.f, a5 = 0.f, a6 = 0.f, a7 = 0.f;
    if (g4 == 0) {
        uint4 u = *(const uint4*)(xb + (size_t)wid * 128 + li * 8);
        a0 = bflo(u.x); a1 = bfhi(u.x); a2 = bflo(u.y); a3 = bfhi(u.y);
        a4 = bflo(u.z); a5 = bfhi(u.z); a6 = bflo(u.w); a7 = bfhi(u.w);
    }
    for (int j = 0; j < deg; j += 4) {
        int jj = min(j + g4, deg - 1);
        unsigned p = ep[jj];
        float w = (j + g4 < deg) ? hwl[p & 7] : 0.f;
        uint4 u = *(const uint4*)(xrow + (size_t)(p >> 3) * 128);
        a0 = fmaf(w, bflo(u.x), a0); a1 = fmaf(w, bfhi(u.x), a1);
        a2 = fmaf(w, bflo(u.y), a2); a3 = fmaf(w, bfhi(u.y), a3);
        a4 = fmaf(w, bflo(u.z), a4); a5 = fmaf(w, bfhi(u.z), a5);
        a6 = fmaf(w, bflo(u.w), a6); a7 = fmaf(w, bfhi(u.w), a7);
    }
    a0 += __shfl_xor(a0, 16); a1 += __shfl_xor(a1, 16);
    a2 += __shfl_xor(a2, 16); a3 += __shfl_xor(a3, 16);
    a4 += __shfl_xor(a4, 16); a5 += __shfl_xor(a5, 16);
    a6 += __shfl_xor(a6, 16); a7 += __shfl_xor(a7, 16);
    a0 += __shfl_xor(a0, 32); a1 += __shfl_xor(a1, 32);
    a2 += __shfl_xor(a2, 32); a3 += __shfl_xor(a3, 32);
    a4 += __shfl_xor(a4, 32); a5 += __shfl_xor(a5, 32);
    a6 += __shfl_xor(a6, 32); a7 += __shfl_xor(a7, 32);
    if (g4 == 0) {
        uint4 o;
        o.x = (unsigned int)f2bf(a0) | ((unsigned int)f2bf(a1) << 16);
        o.y = (unsigned int)f2bf(a2) | ((unsigned int)f2bf(a3) << 16);
        o.z = (unsigned int)f2bf(a4) | ((unsigned int)f2bf(a5) << 16);
        o.w = (unsigned int)f2bf(a6) | ((unsigned int)f2bf(a7) << 16);
        *(uint4*)(h + (size_t)wid * 128 + li * 8) = o;
    }
}

// --- bf16 MFMA GEMM, 2-pass B staging (hi then lo), A cached in registers.
__global__ __launch_bounds__(256, 4) void gemm_mfma_k(
        const unsigned short* __restrict__ Ain,
        const unsigned short* __restrict__ Bhg, const unsigned short* __restrict__ Blg,
        const float* __restrict__ bias, unsigned short* __restrict__ zout,
        float* __restrict__ sum_out, float* __restrict__ sq_out, int N) {
    __shared__ unsigned short Bs[128 * 136];
    int tid = threadIdx.x;
    int wave = tid >> 6, lane = tid & 63;
    int n16 = lane & 15, q = lane >> 4;
    int rowbase = blockIdx.x * 128 + wave * 32;
    for (int i = tid; i < 2048; i += 256) {            // stage B_hi
        int n = i >> 4, c = i & 15;
        *(uint4*)&Bs[n * 136 + c * 8] = *(const uint4*)(Bhg + n * 128 + c * 8);
    }
    short8 afr[4][2];                                  // all A frags, kept in regs
#pragma unroll
    for (int kk = 0; kk < 4; kk++)
#pragma unroll
        for (int mt = 0; mt < 2; mt++) {
            int ar = rowbase + mt * 16 + n16;
            ar = min(ar, N - 1);
            afr[kk][mt] = *(const short8*)(Ain + (size_t)ar * 128 + kk * 32 + q * 8);
        }
    f32x4 acc[2][8];
#pragma unroll
    for (int mt = 0; mt < 2; mt++)
#pragma unroll
        for (int t = 0; t < 8; t++) acc[mt][t] = (f32x4){0.f, 0.f, 0.f, 0.f};
    __syncthreads();
    int ldsb = n16 * 136 + q * 8;
#pragma unroll
    for (int kk = 0; kk < 4; kk++)
#pragma unroll
        for (int t = 0; t < 8; t++) {
            short8 b = *(const short8*)&Bs[t * 16 * 136 + ldsb + kk * 32];
            acc[0][t] = __builtin_amdgcn_mfma_f32_16x16x32_bf16(afr[kk][0], b, acc[0][t], 0, 0, 0);
            acc[1][t] = __builtin_amdgcn_mfma_f32_16x16x32_bf16(afr[kk][1], b, acc[1][t], 0, 0, 0);
        }
    __syncthreads();
    for (int i = tid; i < 2048; i += 256) {            // stage B_lo
        int n = i >> 4, c = i & 15;
        *(uint4*)&Bs[n * 136 + c * 8] = *(const uint4*)(Blg + n * 128 + c * 8);
    }
    __syncthreads();
#pragma unroll
    for (int kk = 0; kk < 4; kk++)
#pragma unroll
        for (int t = 0; t < 8; t++) {
            short8 b = *(const short8*)&Bs[t * 16 * 136 + ldsb + kk * 32];
            acc[0][t] = __builtin_amdgcn_mfma_f32_16x16x32_bf16(afr[kk][0], b, acc[0][t], 0, 0, 0);
            acc[1][t] = __builtin_amdgcn_mfma_f32_16x16x32_bf16(afr[kk][1], b, acc[1][t], 0, 0, 0);
        }
    // epilogue: bias, store bf16 z, per-column stats
    float csum[8], csq[8];
#pragma unroll
    for (int t = 0; t < 8; t++) { csum[t] = 0.f; csq[t] = 0.f; }
#pragma unroll
    for (int t = 0; t < 8; t++) {
        int col = n16 + 16 * t;
        float bv = bias[col];
#pragma unroll
        for (int mt = 0; mt < 2; mt++) {
#pragma unroll
            for (int r = 0; r < 4; r++) {
                int row = rowbase + mt * 16 + q * 4 + r;
                if (row < N) {
                    float v = acc[mt][t][r] + bv;
                    zout[(size_t)row * 128 + col] = f2bf(v);
                    csum[t] += v;
                    csq[t] += v * v;
                }
            }
        }
    }
#pragma unroll
    for (int t = 0; t < 8; t++) {
        csum[t] += __shfl_xor(csum[t], 16);
        csum[t] += __shfl_xor(csum[t], 32);
        csq[t] += __shfl_xor(csq[t], 16);
        csq[t] += __shfl_xor(csq[t], 32);
    }
    __syncthreads();
    float* red = (float*)Bs;
    if (q == 0) {
#pragma unroll
        for (int t = 0; t < 8; t++) {
            int col = n16 + 16 * t;
            red[wave * 128 + col] = csum[t];
            red[512 + wave * 128 + col] = csq[t];
        }
    }
    __syncthreads();
    if (tid < 128) {
        float s = 0.f, qq = 0.f;
#pragma unroll
        for (int w = 0; w < 4; w++) {
            s += red[w * 128 + tid];
            qq += red[512 + w * 128 + tid];
        }
        unsafeAtomicAdd(&sum_out[tid], s);
        unsafeAtomicAdd(&sq_out[tid], qq);
    }
}

// --- gemm2 with BN1+ReLU fused at A-load: A = f2bf(relu(s*z1+t)).
__global__ __launch_bounds__(256, 4) void gemm_mfma_bn_k(
        const unsigned short* __restrict__ Zin,
        const float* __restrict__ sum_in, const float* __restrict__ sq_in,
        const float* __restrict__ gamma, const float* __restrict__ beta,
        float invN,
        const unsigned short* __restrict__ Bhg, const unsigned short* __restrict__ Blg,
        const float* __restrict__ bias, unsigned short* __restrict__ zout,
        float* __restrict__ sum_out, float* __restrict__ sq_out, int N) {
    __shared__ unsigned short Bs[128 * 136];
    __shared__ float sc[128], sh[128];
    int tid = threadIdx.x;
    int wave = tid >> 6, lane = tid & 63;
    int n16 = lane & 15, q = lane >> 4;
    int rowbase = blockIdx.x * 128 + wave * 32;
    for (int i = tid; i < 2048; i += 256) {            // stage B_hi
        int n = i >> 4, c = i & 15;
        *(uint4*)&Bs[n * 136 + c * 8] = *(const uint4*)(Bhg + n * 128 + c * 8);
    }
    if (tid < 128) {                                   // BN1 constants
        float mean = sum_in[tid] * invN;
        float var = fmaxf(sq_in[tid] * invN - mean * mean, 0.f);
        float s = gamma[tid] * rsqrtf(var + 1e-5f);
        sc[tid] = s;
        sh[tid] = beta[tid] - mean * s;
    }
    __syncthreads();
    short8 afr[4][2];                                  // A = relu-BN(z1), bf16
#pragma unroll
    for (int kk = 0; kk < 4; kk++)
#pragma unroll
        for (int mt = 0; mt < 2; mt++) {
            int ar = rowbase + mt * 16 + n16;
            ar = min(ar, N - 1);
            short8 raw = *(const short8*)(Zin + (size_t)ar * 128 + kk * 32 + q * 8);
            short8 outv;
#pragma unroll
            for (int i = 0; i < 8; i++) {
                int col = kk * 32 + q * 8 + i;
                float f = bf2f((unsigned short)raw[i]);
                float v = fmaxf(fmaf(f, sc[col], sh[col]), 0.f);
                outv[i] = (short)f2bf(v);
            }
            afr[kk][mt] = outv;
        }
    f32x4 acc[2][8];
#pragma unroll
    for (int mt = 0; mt < 2; mt++)
#pragma unroll
        for (int t = 0; t < 8; t++) acc[mt][t] = (f32x4){0.f, 0.f, 0.f, 0.f};
    int ldsb = n16 * 136 + q * 8;
#pragma unroll
    for (int kk = 0; kk < 4; kk++)
#pragma unroll
        for (int t = 0; t < 8; t++) {
            short8 b = *(const short8*)&Bs[t * 16 * 136 + ldsb + kk * 32];
            acc[0][t] = __builtin_amdgcn_mfma_f32_16x16x32_bf16(afr[kk][0], b, acc[0][t], 0, 0, 0);
            acc[1][t] = __builtin_amdgcn_mfma_f32_16x16x32_bf16(afr[kk][1], b, acc[1][t], 0, 0, 0);
        }
    __syncthreads();
    for (int i = tid; i < 2048; i += 256) {            // stage B_lo
        int n = i >> 4, c = i & 15;
        *(uint4*)&Bs[n * 136 + c * 8] = *(const uint4*)(Blg + n * 128 + c * 8);
    }
    __syncthreads();
#pragma unroll
    for (int kk = 0; kk < 4; kk++)
#pragma unroll
        for (int t = 0; t < 8; t++) {
            short8 b = *(const short8*)&Bs[t * 16 * 136 + ldsb + kk * 32];
            acc[0][t] = __builtin_amdgcn_mfma_f32_16x16x32_bf16(afr[kk][0], b, acc[0][t], 0, 0, 0);
            acc[1][t] = __builtin_amdgcn_mfma_f32_16x16x32_bf16(afr[kk][1], b, acc[1][t], 0, 0, 0);
        }
    // epilogue: bias, store bf16 z, per-column stats
    float csum[8], csq[8];
#pragma unroll
    for (int t = 0; t < 8; t++) { csum[t] = 0.f; csq[t] = 0.f; }
#pragma unroll
    for (int t = 0; t < 8; t++) {
        int col = n16 + 16 * t;
        float bv = bias[col];
#pragma unroll
        for (int mt = 0; mt < 2; mt++) {
#pragma unroll
            for (int r = 0; r < 4; r++) {
                int row = rowbase + mt * 16 + q * 4 + r;
                if (row < N) {
                    float v = acc[mt][t][r] + bv;
                    zout[(size_t)row * 128 + col] = f2bf(v);
                    csum[t] += v;
                    csq[t] += v * v;
                }
            }
        }
    }
#pragma unroll
    for (int t = 0; t < 8; t++) {
        csum[t] += __shfl_xor(csum[t], 16);
        csum[t] += __shfl_xor(csum[t], 32);
        csq[t] += __shfl_xor(csq[t], 16);
        csq[t] += __shfl_xor(csq[t], 32);
    }
    __syncthreads();
    float* red = (float*)Bs;
    if (q == 0) {
#pragma unroll
        for (int t = 0; t < 8; t++) {
            int col = n16 + 16 * t;
            red[wave * 128 + col] = csum[t];
            red[512 + wave * 128 + col] = csq[t];
        }
    }
    __syncthreads();
    if (tid < 128) {
        float s = 0.f, qq = 0.f;
#pragma unroll
        for (int w = 0; w < 4; w++) {
            s += red[w * 128 + tid];
            qq += red[512 + w * 128 + tid];
        }
        unsafeAtomicAdd(&sum_out[tid], s);
        unsafeAtomicAdd(&sq_out[tid], qq);
    }
}

// out = relu(BN2(z2))  (bf16 in, f32 out)
__global__ __launch_bounds__(256) void bn2_k(const unsigned short* __restrict__ z2,
        const float* __restrict__ sum2, const float* __restrict__ sq2,
        const float* __restrict__ gamma, const float* __restrict__ beta,
        float* __restrict__ out, long long n8, float invN) {
    __shared__ float sc[128], sh[128];
    int tid = threadIdx.x;
    if (tid < 128) {
        float mean = sum2[tid] * invN;
        float var = fmaxf(sq2[tid] * invN - mean * mean, 0.f);
        float s = gamma[tid] * rsqrtf(var + 1e-5f);
        sc[tid] = s;
        sh[tid] = beta[tid] - mean * s;
    }
    __syncthreads();
    long long g = (long long)blockIdx.x * 256 + tid;
    if (g >= n8) return;
    uint4 u = ((const uint4*)z2)[g];
    int cb = (int)((g * 8) & 127);
    float4 s0 = *(const float4*)&sc[cb], s1 = *(const float4*)&sc[cb + 4];
    float4 t0 = *(const float4*)&sh[cb], t1 = *(const float4*)&sh[cb + 4];
    float4 o0, o1;
    o0.x = fmaxf(fmaf(bflo(u.x), s0.x, t0.x), 0.f);
    o0.y = fmaxf(fmaf(bfhi(u.x), s0.y, t0.y), 0.f);
    o0.z = fmaxf(fmaf(bflo(u.y), s0.z, t0.z), 0.f);
    o0.w = fmaxf(fmaf(bfhi(u.y), s0.w, t0.w), 0.f);
    o1.x = fmaxf(fmaf(bflo(u.z), s1.x, t1.x), 0.f);
    o1.y = fmaxf(fmaf(bfhi(u.z), s1.y, t1.y), 0.f);
    o1.z = fmaxf(fmaf(bflo(u.w), s1.z, t1.z), 0.f);
    o1.w = fmaxf(fmaf(bfhi(u.w), s1.w, t1.w), 0.f);
    ((float4*)out)[g * 2] = o0;
    ((float4*)out)[g * 2 + 1] = o1;
}

extern "C" void kernel_launch(void* const* d_in, const int* in_sizes, int n_in,
                              void* d_out, int out_size, void* d_ws, size_t ws_size,
                              hipStream_t stream) {
    const float* x   = (const float*)d_in[0];
    const int*   ei  = (const int*)d_in[1];
    const int*   ew  = (const int*)d_in[2];
    const float* hc  = (const float*)d_in[3];
    const float* W1  = (const float*)d_in[4];
    const float* b1  = (const float*)d_in[5];
    const float* g1  = (const float*)d_in[6];
    const float* be1 = (const float*)d_in[7];
    const float* W2  = (const float*)d_in[8];
    const float* b2  = (const float*)d_in[9];
    const float* g2  = (const float*)d_in[10];
    const float* be2 = (const float*)d_in[11];

    int N = in_sizes[0] / 128;
    int E = in_sizes[2];
    int K = in_sizes[3];
    size_t NF = (size_t)N * 128;
    long long n8 = (long long)(NF / 8);
    int NX = (int)((n8 + 255) / 256);

    // workspace (aliases: z1 reuses xb after gather; z2 reuses h after gemm1)
    unsigned short* h = (unsigned short*)d_ws;          // NF ush
    unsigned short* xb = h + NF;                        // NF ush
    unsigned short* z1 = xb;                            // alias (xb dead post-gather)
    unsigned short* z2 = h;                             // alias (h dead post-gemm1)
    unsigned* staging = (unsigned*)(xb + NF);           // N*RCAP u32 (fallback) /
    unsigned* rowsorted = staging;                      // rowsorted E u32 (bucketed)
    int* cur = (int*)(staging + (size_t)N * RCAP);      // N (fallback only)
    unsigned short* w1h = (unsigned short*)(cur + N);
    unsigned short* w1l = w1h + 16384;
    unsigned short* w2h = w1l + 16384;
    unsigned short* w2l = w2h + 16384;
    float* hwp = (float*)(w2l + 16384);                 // 8
    float* sums = hwp + 8;                              // 512
    float* sum1 = sums, *sq1 = sums + 128, *sum2 = sums + 256, *sq2 = sums + 384;
    int nbuk  = (N + 1023) >> 10;
    int nbukp = (nbuk + 7) & ~7;                        // %8 == 0
    int* C = (int*)(sums + 512);                        // nbukp * P2B (transposed)
    int* tot = C + (size_t)nbukp * P2B;                 // nbukp
    unsigned* bucketed = (unsigned*)(tot + nbukp);      // E records
    int* rowstart = (int*)(bucketed + E);               // N + 1
    size_t ws_need = (size_t)((char*)(rowstart + N + 1) - (char*)d_ws);
    bool use_bucketed = (nbukp <= 128) && (N <= (1 << 17)) && (K <= 7)
                        && ((size_t)E <= (size_t)N * RCAP)
                        && (ws_need <= ws_size);

    float invN = 1.0f / (float)N;
    int per = (E + P2B - 1) / P2B;

    int prep_grid = use_bucketed ? (3 + NX + P2B) : (3 + NX);
    if (!use_bucketed)
        hipMemsetAsync(cur, 0, (size_t)N * sizeof(int), stream);
    prep_k<<<prep_grid, 256, 0, stream>>>(hc, hwp, sums, W1, W2,
        w1h, w1l, w2h, w2l, (const float4*)x, (uint4*)xb, K, n8,
        ei, C, E, per, nbukp, N, NX);
    long long tot_thr = (long long)N * 64;
    int ggrid = (int)((tot_thr + 255) / 256);
    if (use_bucketed) {
        scan1_k<<<nbukp, 256, 0, stream>>>(C, tot, nbukp, P2B);
        scatter_k<<<P2B, 256, 0, stream>>>(ei, ei + E, ew, C, tot, bucketed,
                                           E, per, nbukp, K);
        slot3s_k<<<nbukp, 256, 0, stream>>>(bucketed, tot, rowsorted, rowstart,
                                            nbukp, N);
        gather_k<<<ggrid, 256, 0, stream>>>(xb, rowsorted, rowstart, hwp, h, N);
    } else {
        slot_k<<<(E + 255) / 256, 256, 0, stream>>>(ei, ei + E, ew, cur, staging, E, K);
        gather_stg_k<<<ggrid, 256, 0, stream>>>(xb, staging, cur, hwp, h, N);
    }
    int gblocks = (N + 127) / 128;
    gemm_mfma_k<<<gblocks, 256, 0, stream>>>(h, w1h, w1l, b1, z1, sum1, sq1, N);
    gemm_mfma_bn_k<<<gblocks, 256, 0, stream>>>(z1, sum1, sq1, g1, be1, invN,
        w2h, w2l, b2, z2, sum2, sq2, N);
    bn2_k<<<NX, 256, 0, stream>>>(z2, sum2, sq2, g2, be2, (float*)d_out, n8, invN);
}

// Round 11
// 402.343 us; speedup vs baseline: 1.3956x; 1.0169x over previous
//
#include <hip/hip_runtime.h>
#include <hip/hip_bf16.h>

// ---------------------------------------------------------------------------
// SPN layer (R19): prep{softmax||Wsplit||x->bf16||count} -> scan1 ->
// scatter(+inline bucket-base scan) -> slot3s (per-bucket LDS counting sort)
// -> gather (rowstart/rowsorted) -> gemm1 -> gemm2+fusedBN1 -> bn2.
// R19 change: GEMM epilogues stored zout as 64 scalar 2B stores/thread at
// stride 32B (uncoalesced). Now: acc -> per-wave 8KB LDS slice (f32, bias +
// stats as before) -> repack -> 16B uint4 stores, 16 lanes = contiguous
// 256B row. Identical numerics; store path becomes coalesced.
// gather measured ~90% of its random-256B L3 service floor -- left as is.
// ---------------------------------------------------------------------------

#define RCAP 64    // fallback path only
#define P2B 256    // blocks in count/scatter passes

typedef __attribute__((ext_vector_type(8))) short short8;
typedef __attribute__((ext_vector_type(4))) float f32x4;

__device__ inline unsigned short f2bf(float v) {           // RNE bf16 round
    unsigned int u = __float_as_uint(v);
    return (unsigned short)((u + 0x7fffu + ((u >> 16) & 1u)) >> 16);
}
__device__ inline float bf2f(unsigned int u) { return __uint_as_float(u << 16); }
__device__ inline float bflo(unsigned int u) { return __uint_as_float(u << 16); }
__device__ inline float bfhi(unsigned int u) { return __uint_as_float(u & 0xFFFF0000u); }

// --- prep: [0]=softmax+zero stats, [1..2]=W split, [3..3+NX)=x->bf16,
//     [3+NX..3+NX+P2B) = edge-count histogram (bucketed path) --------------
__global__ __launch_bounds__(256) void prep_k(
        const float* __restrict__ hc, float* __restrict__ hwp, float* __restrict__ sums,
        const float* __restrict__ W1, const float* __restrict__ W2,
        unsigned short* __restrict__ w1h, unsigned short* __restrict__ w1l,
        unsigned short* __restrict__ w2h, unsigned short* __restrict__ w2l,
        const float4* __restrict__ x4, uint4* __restrict__ xb, int K, long long n8,
        const int* __restrict__ rows, int* __restrict__ C,
        int E, int per, int nbukp, int N, int NX) {
    __shared__ int hist[128];
    int b = blockIdx.x, tid = threadIdx.x;
    if (b == 0) {                                    // softmax + zero stats
        sums[tid] = 0.f; sums[tid + 256] = 0.f;
        if (tid == 0) {
            float tmp[8];
            float m = -1e30f;
            for (int k = 0; k < K; ++k) m = fmaxf(m, hc[k]);
            float s = 0.f;
            for (int k = 0; k < K; ++k) { float e = __expf(hc[k] - m); tmp[k] = e; s += e; }
            float inv = 1.f / s;
            for (int k = 0; k < 8; ++k) hwp[k] = 0.f;
            for (int k = 0; k < K; ++k) hwp[k + 1] = tmp[k] * inv;
        }
        return;
    }
    if (b <= 2) {                                    // W split (transposed hi/lo)
        const float* W = (b == 2) ? W2 : W1;
        unsigned short* th = (b == 2) ? w2h : w1h;
        unsigned short* tl = (b == 2) ? w2l : w1l;
        for (int i = tid; i < 16384; i += 256) {
            int k = i >> 7, n = i & 127;
            float v = W[k * 128 + n];
            unsigned short hi = f2bf(v);
            th[n * 128 + k] = hi;
            tl[n * 128 + k] = f2bf(v - bf2f(hi));
        }
        return;
    }
    if (b < 3 + NX) {                                // x -> bf16
        long long g = (long long)(b - 3) * 256 + tid;
        if (g >= n8) return;
        float4 a = x4[g * 2], c = x4[g * 2 + 1];
        union { unsigned short us[8]; uint4 v; } o;
        o.us[0] = f2bf(a.x); o.us[1] = f2bf(a.y); o.us[2] = f2bf(a.z); o.us[3] = f2bf(a.w);
        o.us[4] = f2bf(c.x); o.us[5] = f2bf(c.y); o.us[6] = f2bf(c.z); o.us[7] = f2bf(c.w);
        xb[g] = o.v;
        return;
    }
    // count role (bucketed path only): histogram of row>>10
    int cblk = b - 3 - NX;
    for (int i = tid; i < nbukp; i += 256) hist[i] = 0;
    __syncthreads();
    int e0 = cblk * per, e1 = min(E, e0 + per);
    for (int e = e0 + tid; e < e1; e += 256)
        atomicAdd(&hist[rows[e] >> 10], 1);
    __syncthreads();
    for (int i = tid; i < nbukp; i += 256) C[i * P2B + cblk] = hist[i];
}

// P2a: block b scans bucket-b's row of C (coalesced; Hillis-Steele in LDS);
// C becomes within-bucket exclusive prefix; tot[b] = bucket total.
__global__ __launch_bounds__(256) void scan1_k(int* __restrict__ C,
        int* __restrict__ tot, int nbukp, int nblk) {
    __shared__ int buf[256];
    int b = blockIdx.x, tid = threadIdx.x;
    int v = (tid < nblk) ? C[b * P2B + tid] : 0;
    buf[tid] = v;
    __syncthreads();
#pragma unroll
    for (int off = 1; off < 256; off <<= 1) {
        int t = (tid >= off) ? buf[tid - off] : 0;
        __syncthreads();
        buf[tid] += t;
        __syncthreads();
    }
    if (tid < nblk) C[b * P2B + tid] = buf[tid] - v;     // exclusive
    if (tid == 255) tot[b] = buf[255];
}

// P2b: bucket-grouped 4B records: d | col<<3 | (row&1023)<<20
// bucket bases derived inline from tot[]
__global__ __launch_bounds__(256) void scatter_k(const int* __restrict__ rows,
        const int* __restrict__ cols, const int* __restrict__ ew,
        const int* __restrict__ O, const int* __restrict__ tot,
        unsigned* __restrict__ bucketed, int E, int per, int nbukp, int K) {
    __shared__ int buf[128];
    __shared__ unsigned curs[128];
    int blk = blockIdx.x, tid = threadIdx.x;
    int v = (tid < 128 && tid < nbukp) ? tot[tid] : 0;
    if (tid < 128) buf[tid] = v;
    __syncthreads();
#pragma unroll
    for (int off = 1; off < 128; off <<= 1) {
        int t = (tid >= off && tid < 128) ? buf[tid - off] : 0;
        __syncthreads();
        if (tid < 128) buf[tid] += t;
        __syncthreads();
    }
    if (tid < nbukp)
        curs[tid] = (unsigned)(O[tid * P2B + blk] + buf[tid] - v);  // excl base
    __syncthreads();
    int e0 = blk * per, e1 = min(E, e0 + per);
    for (int e = e0 + tid; e < e1; e += 256) {
        int r = rows[e];
        int c = cols[e];
        int d = ew[e];
        if (d < 1 || d > K) d = 0;                   // hwp[0] = 0 -> weight 0
        unsigned idx = atomicAdd(&curs[r >> 10], 1u);
        bucketed[idx] = (unsigned)d | ((unsigned)c << 3) | ((unsigned)(r & 1023) << 20);
    }
}

// P3: per-bucket LDS counting sort -> compact row-sorted records + rowstart.
__global__ __launch_bounds__(256) void slot3s_k(const unsigned* __restrict__ bucketed,
        const int* __restrict__ tot, unsigned* __restrict__ rowsorted,
        int* __restrict__ rowstart, int nbukp, int N) {
    __shared__ int bbuf[128];
    __shared__ int cnt[1024];
    __shared__ int pre[1024];
    __shared__ int sb[256];
    int tid = threadIdx.x;
    if (tid < 128) bbuf[tid] = (tid < nbukp) ? tot[tid] : 0;
    __syncthreads();
#pragma unroll
    for (int off = 1; off < 128; off <<= 1) {
        int t = (tid >= off && tid < 128) ? bbuf[tid - off] : 0;
        __syncthreads();
        if (tid < 128) bbuf[tid] += t;
        __syncthreads();
    }
    int bucket = blockIdx.x;
    int s1 = bbuf[bucket];
    int cntb = tot[bucket];
    int s0 = s1 - cntb;
    int rbase = bucket << 10;
    int rlim = min(1024, N - rbase);
    if (bucket == 0 && tid == 0) rowstart[N] = bbuf[127];
    for (int i = tid; i < 1024; i += 256) cnt[i] = 0;
    __syncthreads();
    for (int e = s0 + tid; e < s1; e += 256)
        atomicAdd(&cnt[bucketed[e] >> 20], 1);
    __syncthreads();
    int b4 = tid * 4;
    int c0 = cnt[b4], c1 = cnt[b4 + 1], c2 = cnt[b4 + 2], c3 = cnt[b4 + 3];
    int ts = c0 + c1 + c2 + c3;
    sb[tid] = ts;
    __syncthreads();
#pragma unroll
    for (int off = 1; off < 256; off <<= 1) {
        int t = (tid >= off) ? sb[tid - off] : 0;
        __syncthreads();
        sb[tid] += t;
        __syncthreads();
    }
    int eb = sb[tid] - ts;
    pre[b4] = eb;
    pre[b4 + 1] = eb + c0;
    pre[b4 + 2] = eb + c0 + c1;
    pre[b4 + 3] = eb + c0 + c1 + c2;
    __syncthreads();
    for (int lr = tid; lr < rlim; lr += 256)
        rowstart[rbase + lr] = s0 + pre[lr];
    for (int i = tid; i < 1024; i += 256) cnt[i] = pre[i];
    __syncthreads();
    for (int e = s0 + tid; e < s1; e += 256) {
        unsigned u = bucketed[e];
        int lr = (int)(u >> 20);
        int p = atomicAdd(&cnt[lr], 1);
        rowsorted[s0 + p] = u & 0xFFFFFu;
    }
}

// legacy single-pass slot (fallback path)
__global__ __launch_bounds__(256) void slot_k(const int* __restrict__ rows,
        const int* __restrict__ cols, const int* __restrict__ ew,
        int* __restrict__ cur, unsigned* __restrict__ staging, int E, int K) {
    int e = blockIdx.x * 256 + threadIdx.x;
    if (e >= E) return;
    int r = rows[e];
    int d = ew[e];
    if (d < 1 || d > K) d = 0;
    int s = atomicAdd(&cur[r], 1);
    if (s < RCAP)
        staging[((size_t)r << 6) + s] = (unsigned)d | ((unsigned)cols[e] << 3);
}

// one wave per row, 4 edges per wave-step: each 16-lane group loads one full
// 256B row (uint4/lane). Compact payloads from rowsorted[rowstart[r]..).
__global__ __launch_bounds__(256) void gather_k(
        const unsigned short* __restrict__ xb, const unsigned* __restrict__ rowsorted,
        const int* __restrict__ rowstart, const float* __restrict__ hwp,
        unsigned short* __restrict__ h, int N) {
    __shared__ float hwl[8];
    int tid = threadIdx.x;
    if (tid < 8) hwl[tid] = hwp[tid];
    __syncthreads();
    int wid = (blockIdx.x * 256 + tid) >> 6;
    if (wid >= N) return;
    int lane = tid & 63;
    int g4 = lane >> 4, li = lane & 15;
    int st = rowstart[wid];
    int deg = rowstart[wid + 1] - st;
    const unsigned* ep = rowsorted + st;
    const unsigned short* xrow = xb + li * 8;          // 16B per lane within row
    float a0 = 0.f, a1 = 0.f, a2 = 0.f, a3 = 0.f;
    float a4 = 0.f, a5 = 0.f, a6 = 0.f, a7 = 0.f;
    if (g4 == 0) {                                     // GIN self term (eps=0)
        uint4 u = *(const uint4*)(xb + (size_t)wid * 128 + li * 8);
        a0 = bflo(u.x); a1 = bfhi(u.x); a2 = bflo(u.y); a3 = bfhi(u.y);
        a4 = bflo(u.z); a5 = bfhi(u.z); a6 = bflo(u.w); a7 = bfhi(u.w);
    }
    int j = 0;
    for (; j + 16 <= deg; j += 16) {
        unsigned p0 = ep[j + g4];
        unsigned p1 = ep[j + 4 + g4];
        unsigned p2 = ep[j + 8 + g4];
        unsigned p3 = ep[j + 12 + g4];
        uint4 u0 = *(const uint4*)(xrow + (size_t)(p0 >> 3) * 128);
        uint4 u1 = *(const uint4*)(xrow + (size_t)(p1 >> 3) * 128);
        uint4 u2 = *(const uint4*)(xrow + (size_t)(p2 >> 3) * 128);
        uint4 u3 = *(const uint4*)(xrow + (size_t)(p3 >> 3) * 128);
        float w0 = hwl[p0 & 7], w1 = hwl[p1 & 7];
        float w2 = hwl[p2 & 7], w3 = hwl[p3 & 7];
        a0 = fmaf(w0, bflo(u0.x), a0); a1 = fmaf(w0, bfhi(u0.x), a1);
        a2 = fmaf(w0, bflo(u0.y), a2); a3 = fmaf(w0, bfhi(u0.y), a3);
        a4 = fmaf(w0, bflo(u0.z), a4); a5 = fmaf(w0, bfhi(u0.z), a5);
        a6 = fmaf(w0, bflo(u0.w), a6); a7 = fmaf(w0, bfhi(u0.w), a7);
        a0 = fmaf(w1, bflo(u1.x), a0); a1 = fmaf(w1, bfhi(u1.x), a1);
        a2 = fmaf(w1, bflo(u1.y), a2); a3 = fmaf(w1, bfhi(u1.y), a3);
        a4 = fmaf(w1, bflo(u1.z), a4); a5 = fmaf(w1, bfhi(u1.z), a5);
        a6 = fmaf(w1, bflo(u1.w), a6); a7 = fmaf(w1, bfhi(u1.w), a7);
        a0 = fmaf(w2, bflo(u2.x), a0); a1 = fmaf(w2, bfhi(u2.x), a1);
        a2 = fmaf(w2, bflo(u2.y), a2); a3 = fmaf(w2, bfhi(u2.y), a3);
        a4 = fmaf(w2, bflo(u2.z), a4); a5 = fmaf(w2, bfhi(u2.z), a5);
        a6 = fmaf(w2, bflo(u2.w), a6); a7 = fmaf(w2, bfhi(u2.w), a7);
        a0 = fmaf(w3, bflo(u3.x), a0); a1 = fmaf(w3, bfhi(u3.x), a1);
        a2 = fmaf(w3, bflo(u3.y), a2); a3 = fmaf(w3, bfhi(u3.y), a3);
        a4 = fmaf(w3, bflo(u3.z), a4); a5 = fmaf(w3, bfhi(u3.z), a5);
        a6 = fmaf(w3, bflo(u3.w), a6); a7 = fmaf(w3, bfhi(u3.w), a7);
    }
    for (; j + 4 <= deg; j += 4) {
        unsigned p = ep[j + g4];
        uint4 u = *(const uint4*)(xrow + (size_t)(p >> 3) * 128);
        float w = hwl[p & 7];
        a0 = fmaf(w, bflo(u.x), a0); a1 = fmaf(w, bfhi(u.x), a1);
        a2 = fmaf(w, bflo(u.y), a2); a3 = fmaf(w, bfhi(u.y), a3);
        a4 = fmaf(w, bflo(u.z), a4); a5 = fmaf(w, bfhi(u.z), a5);
        a6 = fmaf(w, bflo(u.w), a6); a7 = fmaf(w, bfhi(u.w), a7);
    }
    if (j < deg) {                                     // tail 1..3 edges
        int jj = min(j + g4, deg - 1);
        unsigned p = ep[jj];
        float w = (j + g4 < deg) ? hwl[p & 7] : 0.f;
        uint4 u = *(const uint4*)(xrow + (size_t)(p >> 3) * 128);
        a0 = fmaf(w, bflo(u.x), a0); a1 = fmaf(w, bfhi(u.x), a1);
        a2 = fmaf(w, bflo(u.y), a2); a3 = fmaf(w, bfhi(u.y), a3);
        a4 = fmaf(w, bflo(u.z), a4); a5 = fmaf(w, bfhi(u.z), a5);
        a6 = fmaf(w, bflo(u.w), a6); a7 = fmaf(w, bfhi(u.w), a7);
    }
    a0 += __shfl_xor(a0, 16); a1 += __shfl_xor(a1, 16);
    a2 += __shfl_xor(a2, 16); a3 += __shfl_xor(a3, 16);
    a4 += __shfl_xor(a4, 16); a5 += __shfl_xor(a5, 16);
    a6 += __shfl_xor(a6, 16); a7 += __shfl_xor(a7, 16);
    a0 += __shfl_xor(a0, 32); a1 += __shfl_xor(a1, 32);
    a2 += __shfl_xor(a2, 32); a3 += __shfl_xor(a3, 32);
    a4 += __shfl_xor(a4, 32); a5 += __shfl_xor(a5, 32);
    a6 += __shfl_xor(a6, 32); a7 += __shfl_xor(a7, 32);
    if (g4 == 0) {
        uint4 o;
        o.x = (unsigned int)f2bf(a0) | ((unsigned int)f2bf(a1) << 16);
        o.y = (unsigned int)f2bf(a2) | ((unsigned int)f2bf(a3) << 16);
        o.z = (unsigned int)f2bf(a4) | ((unsigned int)f2bf(a5) << 16);
        o.w = (unsigned int)f2bf(a6) | ((unsigned int)f2bf(a7) << 16);
        *(uint4*)(h + (size_t)wid * 128 + li * 8) = o;
    }
}

// legacy staged gather (fallback path; staging + cur)
__global__ __launch_bounds__(256) void gather_stg_k(
        const unsigned short* __restrict__ xb, const unsigned* __restrict__ staging,
        const int* __restrict__ cur, const float* __restrict__ hwp,
        unsigned short* __restrict__ h, int N) {
    __shared__ float hwl[8];
    int tid = threadIdx.x;
    if (tid < 8) hwl[tid] = hwp[tid];
    __syncthreads();
    int wid = (blockIdx.x * 256 + tid) >> 6;
    if (wid >= N) return;
    int lane = tid & 63;
    int g4 = lane >> 4, li = lane & 15;
    int deg = __builtin_amdgcn_readfirstlane(cur[wid]);
    deg = min(deg, RCAP);
    const unsigned* ep = staging + ((size_t)wid << 6);
    const unsigned short* xrow = xb + li * 8;
    float a0 = 0.f, a1 = 0.f, a2 = 0.f, a3 = 0.f;
    float a4 = 0.f, a5 = 0.f, a6 = 0.f, a7 = 0.f;
    if (g4 == 0) {
        uint4 u = *(const uint4*)(xb + (size_t)wid * 128 + li * 8);
        a0 = bflo(u.x); a1 = bfhi(u.x); a2 = bflo(u.y); a3 = bfhi(u.y);
        a4 = bflo(u.z); a5 = bfhi(u.z); a6 = bflo(u.w); a7 = bfhi(u.w);
    }
    for (int j = 0; j < deg; j += 4) {
        int jj = min(j + g4, deg - 1);
        unsigned p = ep[jj];
        float w = (j + g4 < deg) ? hwl[p & 7] : 0.f;
        uint4 u = *(const uint4*)(xrow + (size_t)(p >> 3) * 128);
        a0 = fmaf(w, bflo(u.x), a0); a1 = fmaf(w, bfhi(u.x), a1);
        a2 = fmaf(w, bflo(u.y), a2); a3 = fmaf(w, bfhi(u.y), a3);
        a4 = fmaf(w, bflo(u.z), a4); a5 = fmaf(w, bfhi(u.z), a5);
        a6 = fmaf(w, bflo(u.w), a6); a7 = fmaf(w, bfhi(u.w), a7);
    }
    a0 += __shfl_xor(a0, 16); a1 += __shfl_xor(a1, 16);
    a2 += __shfl_xor(a2, 16); a3 += __shfl_xor(a3, 16);
    a4 += __shfl_xor(a4, 16); a5 += __shfl_xor(a5, 16);
    a6 += __shfl_xor(a6, 16); a7 += __shfl_xor(a7, 16);
    a0 += __shfl_xor(a0, 32); a1 += __shfl_xor(a1, 32);
    a2 += __shfl_xor(a2, 32); a3 += __shfl_xor(a3, 32);
    a4 += __shfl_xor(a4, 32); a5 += __shfl_xor(a5, 32);
    a6 += __shfl_xor(a6, 32); a7 += __shfl_xor(a7, 32);
    if (g4 == 0) {
        uint4 o;
        o.x = (unsigned int)f2bf(a0) | ((unsigned int)f2bf(a1) << 16);
        o.y = (unsigned int)f2bf(a2) | ((unsigned int)f2bf(a3) << 16);
        o.z = (unsigned int)f2bf(a4) | ((unsigned int)f2bf(a5) << 16);
        o.w = (unsigned int)f2bf(a6) | ((unsigned int)f2bf(a7) << 16);
        *(uint4*)(h + (size_t)wid * 128 + li * 8) = o;
    }
}

// --- bf16 MFMA GEMM, 2-pass B staging (hi then lo), A cached in registers.
// Epilogue: acc -> per-wave LDS slice -> coalesced 16B bf16 stores.
__global__ __launch_bounds__(256, 4) void gemm_mfma_k(
        const unsigned short* __restrict__ Ain,
        const unsigned short* __restrict__ Bhg, const unsigned short* __restrict__ Blg,
        const float* __restrict__ bias, unsigned short* __restrict__ zout,
        float* __restrict__ sum_out, float* __restrict__ sq_out, int N) {
    __shared__ unsigned short Bs[128 * 136];
    int tid = threadIdx.x;
    int wave = tid >> 6, lane = tid & 63;
    int n16 = lane & 15, q = lane >> 4;
    int rowbase = blockIdx.x * 128 + wave * 32;
    for (int i = tid; i < 2048; i += 256) {            // stage B_hi
        int n = i >> 4, c = i & 15;
        *(uint4*)&Bs[n * 136 + c * 8] = *(const uint4*)(Bhg + n * 128 + c * 8);
    }
    short8 afr[4][2];                                  // all A frags, kept in regs
#pragma unroll
    for (int kk = 0; kk < 4; kk++)
#pragma unroll
        for (int mt = 0; mt < 2; mt++) {
            int ar = rowbase + mt * 16 + n16;
            ar = min(ar, N - 1);
            afr[kk][mt] = *(const short8*)(Ain + (size_t)ar * 128 + kk * 32 + q * 8);
        }
    f32x4 acc[2][8];
#pragma unroll
    for (int mt = 0; mt < 2; mt++)
#pragma unroll
        for (int t = 0; t < 8; t++) acc[mt][t] = (f32x4){0.f, 0.f, 0.f, 0.f};
    __syncthreads();
    int ldsb = n16 * 136 + q * 8;
#pragma unroll
    for (int kk = 0; kk < 4; kk++)
#pragma unroll
        for (int t = 0; t < 8; t++) {
            short8 b = *(const short8*)&Bs[t * 16 * 136 + ldsb + kk * 32];
            acc[0][t] = __builtin_amdgcn_mfma_f32_16x16x32_bf16(afr[kk][0], b, acc[0][t], 0, 0, 0);
            acc[1][t] = __builtin_amdgcn_mfma_f32_16x16x32_bf16(afr[kk][1], b, acc[1][t], 0, 0, 0);
        }
    __syncthreads();
    for (int i = tid; i < 2048; i += 256) {            // stage B_lo
        int n = i >> 4, c = i & 15;
        *(uint4*)&Bs[n * 136 + c * 8] = *(const uint4*)(Blg + n * 128 + c * 8);
    }
    __syncthreads();
#pragma unroll
    for (int kk = 0; kk < 4; kk++)
#pragma unroll
        for (int t = 0; t < 8; t++) {
            short8 b = *(const short8*)&Bs[t * 16 * 136 + ldsb + kk * 32];
            acc[0][t] = __builtin_amdgcn_mfma_f32_16x16x32_bf16(afr[kk][0], b, acc[0][t], 0, 0, 0);
            acc[1][t] = __builtin_amdgcn_mfma_f32_16x16x32_bf16(afr[kk][1], b, acc[1][t], 0, 0, 0);
        }
    // epilogue: bias + stats; store via per-wave LDS slice, coalesced 16B
    float csum[8], csq[8];
#pragma unroll
    for (int t = 0; t < 8; t++) { csum[t] = 0.f; csq[t] = 0.f; }
    float* wbuf = (float*)Bs + wave * 2048;            // 16 rows x 128 f32
    int c8 = (lane & 15) * 8, rr = lane >> 4;
    __syncthreads();                                   // all B-reads done
#pragma unroll
    for (int mt = 0; mt < 2; mt++) {
#pragma unroll
        for (int t = 0; t < 8; t++) {
            int col = n16 + 16 * t;
            float bv = bias[col];
#pragma unroll
            for (int r = 0; r < 4; r++) {
                int row = rowbase + mt * 16 + q * 4 + r;
                float v = acc[mt][t][r] + bv;
                wbuf[(q * 4 + r) * 128 + col] = v;
                if (row < N) { csum[t] += v; csq[t] += v * v; }
            }
        }
        __syncthreads();
#pragma unroll
        for (int jj = 0; jj < 4; jj++) {
            int lrow = rr + jj * 4;
            int row = rowbase + mt * 16 + lrow;
            const float* p = wbuf + lrow * 128 + c8;
            uint4 o;
            o.x = (unsigned int)f2bf(p[0]) | ((unsigned int)f2bf(p[1]) << 16);
            o.y = (unsigned int)f2bf(p[2]) | ((unsigned int)f2bf(p[3]) << 16);
            o.z = (unsigned int)f2bf(p[4]) | ((unsigned int)f2bf(p[5]) << 16);
            o.w = (unsigned int)f2bf(p[6]) | ((unsigned int)f2bf(p[7]) << 16);
            if (row < N)
                *(uint4*)(zout + (size_t)row * 128 + c8) = o;
        }
        __syncthreads();
    }
#pragma unroll
    for (int t = 0; t < 8; t++) {
        csum[t] += __shfl_xor(csum[t], 16);
        csum[t] += __shfl_xor(csum[t], 32);
        csq[t] += __shfl_xor(csq[t], 16);
        csq[t] += __shfl_xor(csq[t], 32);
    }
    float* red = (float*)Bs;
    if (q == 0) {
#pragma unroll
        for (int t = 0; t < 8; t++) {
            int col = n16 + 16 * t;
            red[wave * 128 + col] = csum[t];
            red[512 + wave * 128 + col] = csq[t];
        }
    }
    __syncthreads();
    if (tid < 128) {
        float s = 0.f, qq = 0.f;
#pragma unroll
        for (int w = 0; w < 4; w++) {
            s += red[w * 128 + tid];
            qq += red[512 + w * 128 + tid];
        }
        unsafeAtomicAdd(&sum_out[tid], s);
        unsafeAtomicAdd(&sq_out[tid], qq);
    }
}

// --- gemm2 with BN1+ReLU fused at A-load; same coalesced epilogue.
__global__ __launch_bounds__(256, 4) void gemm_mfma_bn_k(
        const unsigned short* __restrict__ Zin,
        const float* __restrict__ sum_in, const float* __restrict__ sq_in,
        const float* __restrict__ gamma, const float* __restrict__ beta,
        float invN,
        const unsigned short* __restrict__ Bhg, const unsigned short* __restrict__ Blg,
        const float* __restrict__ bias, unsigned short* __restrict__ zout,
        float* __restrict__ sum_out, float* __restrict__ sq_out, int N) {
    __shared__ unsigned short Bs[128 * 136];
    __shared__ float sc[128], sh[128];
    int tid = threadIdx.x;
    int wave = tid >> 6, lane = tid & 63;
    int n16 = lane & 15, q = lane >> 4;
    int rowbase = blockIdx.x * 128 + wave * 32;
    for (int i = tid; i < 2048; i += 256) {            // stage B_hi
        int n = i >> 4, c = i & 15;
        *(uint4*)&Bs[n * 136 + c * 8] = *(const uint4*)(Bhg + n * 128 + c * 8);
    }
    if (tid < 128) {                                   // BN1 constants
        float mean = sum_in[tid] * invN;
        float var = fmaxf(sq_in[tid] * invN - mean * mean, 0.f);
        float s = gamma[tid] * rsqrtf(var + 1e-5f);
        sc[tid] = s;
        sh[tid] = beta[tid] - mean * s;
    }
    __syncthreads();
    short8 afr[4][2];                                  // A = relu-BN(z1), bf16
#pragma unroll
    for (int kk = 0; kk < 4; kk++)
#pragma unroll
        for (int mt = 0; mt < 2; mt++) {
            int ar = rowbase + mt * 16 + n16;
            ar = min(ar, N - 1);
            short8 raw = *(const short8*)(Zin + (size_t)ar * 128 + kk * 32 + q * 8);
            short8 outv;
#pragma unroll
            for (int i = 0; i < 8; i++) {
                int col = kk * 32 + q * 8 + i;
                float f = bf2f((unsigned short)raw[i]);
                float v = fmaxf(fmaf(f, sc[col], sh[col]), 0.f);
                outv[i] = (short)f2bf(v);
            }
            afr[kk][mt] = outv;
        }
    f32x4 acc[2][8];
#pragma unroll
    for (int mt = 0; mt < 2; mt++)
#pragma unroll
        for (int t = 0; t < 8; t++) acc[mt][t] = (f32x4){0.f, 0.f, 0.f, 0.f};
    int ldsb = n16 * 136 + q * 8;
#pragma unroll
    for (int kk = 0; kk < 4; kk++)
#pragma unroll
        for (int t = 0; t < 8; t++) {
            short8 b = *(const short8*)&Bs[t * 16 * 136 + ldsb + kk * 32];
            acc[0][t] = __builtin_amdgcn_mfma_f32_16x16x32_bf16(afr[kk][0], b, acc[0][t], 0, 0, 0);
            acc[1][t] = __builtin_amdgcn_mfma_f32_16x16x32_bf16(afr[kk][1], b, acc[1][t], 0, 0, 0);
        }
    __syncthreads();
    for (int i = tid; i < 2048; i += 256) {            // stage B_lo
        int n = i >> 4, c = i & 15;
        *(uint4*)&Bs[n * 136 + c * 8] = *(const uint4*)(Blg + n * 128 + c * 8);
    }
    __syncthreads();
#pragma unroll
    for (int kk = 0; kk < 4; kk++)
#pragma unroll
        for (int t = 0; t < 8; t++) {
            short8 b = *(const short8*)&Bs[t * 16 * 136 + ldsb + kk * 32];
            acc[0][t] = __builtin_amdgcn_mfma_f32_16x16x32_bf16(afr[kk][0], b, acc[0][t], 0, 0, 0);
            acc[1][t] = __builtin_amdgcn_mfma_f32_16x16x32_bf16(afr[kk][1], b, acc[1][t], 0, 0, 0);
        }
    // epilogue: bias + stats; store via per-wave LDS slice, coalesced 16B
    float csum[8], csq[8];
#pragma unroll
    for (int t = 0; t < 8; t++) { csum[t] = 0.f; csq[t] = 0.f; }
    float* wbuf = (float*)Bs + wave * 2048;
    int c8 = (lane & 15) * 8, rr = lane >> 4;
    __syncthreads();
#pragma unroll
    for (int mt = 0; mt < 2; mt++) {
#pragma unroll
        for (int t = 0; t < 8; t++) {
            int col = n16 + 16 * t;
            float bv = bias[col];
#pragma unroll
            for (int r = 0; r < 4; r++) {
                int row = rowbase + mt * 16 + q * 4 + r;
                float v = acc[mt][t][r] + bv;
                wbuf[(q * 4 + r) * 128 + col] = v;
                if (row < N) { csum[t] += v; csq[t] += v * v; }
            }
        }
        __syncthreads();
#pragma unroll
        for (int jj = 0; jj < 4; jj++) {
            int lrow = rr + jj * 4;
            int row = rowbase + mt * 16 + lrow;
            const float* p = wbuf + lrow * 128 + c8;
            uint4 o;
            o.x = (unsigned int)f2bf(p[0]) | ((unsigned int)f2bf(p[1]) << 16);
            o.y = (unsigned int)f2bf(p[2]) | ((unsigned int)f2bf(p[3]) << 16);
            o.z = (unsigned int)f2bf(p[4]) | ((unsigned int)f2bf(p[5]) << 16);
            o.w = (unsigned int)f2bf(p[6]) | ((unsigned int)f2bf(p[7]) << 16);
            if (row < N)
                *(uint4*)(zout + (size_t)row * 128 + c8) = o;
        }
        __syncthreads();
    }
#pragma unroll
    for (int t = 0; t < 8; t++) {
        csum[t] += __shfl_xor(csum[t], 16);
        csum[t] += __shfl_xor(csum[t], 32);
        csq[t] += __shfl_xor(csq[t], 16);
        csq[t] += __shfl_xor(csq[t], 32);
    }
    float* red = (float*)Bs;
    if (q == 0) {
#pragma unroll
        for (int t = 0; t < 8; t++) {
            int col = n16 + 16 * t;
            red[wave * 128 + col] = csum[t];
            red[512 + wave * 128 + col] = csq[t];
        }
    }
    __syncthreads();
    if (tid < 128) {
        float s = 0.f, qq = 0.f;
#pragma unroll
        for (int w = 0; w < 4; w++) {
            s += red[w * 128 + tid];
            qq += red[512 + w * 128 + tid];
        }
        unsafeAtomicAdd(&sum_out[tid], s);
        unsafeAtomicAdd(&sq_out[tid], qq);
    }
}

// out = relu(BN2(z2))  (bf16 in, f32 out)
__global__ __launch_bounds__(256) void bn2_k(const unsigned short* __restrict__ z2,
        const float* __restrict__ sum2, const float* __restrict__ sq2,
        const float* __restrict__ gamma, const float* __restrict__ beta,
        float* __restrict__ out, long long n8, float invN) {
    __shared__ float sc[128], sh[128];
    int tid = threadIdx.x;
    if (tid < 128) {
        float mean = sum2[tid] * invN;
        float var = fmaxf(sq2[tid] * invN - mean * mean, 0.f);
        float s = gamma[tid] * rsqrtf(var + 1e-5f);
        sc[tid] = s;
        sh[tid] = beta[tid] - mean * s;
    }
    __syncthreads();
    long long g = (long long)blockIdx.x * 256 + tid;
    if (g >= n8) return;
    uint4 u = ((const uint4*)z2)[g];
    int cb = (int)((g * 8) & 127);
    float4 s0 = *(const float4*)&sc[cb], s1 = *(const float4*)&sc[cb + 4];
    float4 t0 = *(const float4*)&sh[cb], t1 = *(const float4*)&sh[cb + 4];
    float4 o0, o1;
    o0.x = fmaxf(fmaf(bflo(u.x), s0.x, t0.x), 0.f);
    o0.y = fmaxf(fmaf(bfhi(u.x), s0.y, t0.y), 0.f);
    o0.z = fmaxf(fmaf(bflo(u.y), s0.z, t0.z), 0.f);
    o0.w = fmaxf(fmaf(bfhi(u.y), s0.w, t0.w), 0.f);
    o1.x = fmaxf(fmaf(bflo(u.z), s1.x, t1.x), 0.f);
    o1.y = fmaxf(fmaf(bfhi(u.z), s1.y, t1.y), 0.f);
    o1.z = fmaxf(fmaf(bflo(u.w), s1.z, t1.z), 0.f);
    o1.w = fmaxf(fmaf(bfhi(u.w), s1.w, t1.w), 0.f);
    ((float4*)out)[g * 2] = o0;
    ((float4*)out)[g * 2 + 1] = o1;
}

extern "C" void kernel_launch(void* const* d_in, const int* in_sizes, int n_in,
                              void* d_out, int out_size, void* d_ws, size_t ws_size,
                              hipStream_t stream) {
    const float* x   = (const float*)d_in[0];
    const int*   ei  = (const int*)d_in[1];
    const int*   ew  = (const int*)d_in[2];
    const float* hc  = (const float*)d_in[3];
    const float* W1  = (const float*)d_in[4];
    const float* b1  = (const float*)d_in[5];
    const float* g1  = (const float*)d_in[6];
    const float* be1 = (const float*)d_in[7];
    const float* W2  = (const float*)d_in[8];
    const float* b2  = (const float*)d_in[9];
    const float* g2  = (const float*)d_in[10];
    const float* be2 = (const float*)d_in[11];

    int N = in_sizes[0] / 128;
    int E = in_sizes[2];
    int K = in_sizes[3];
    size_t NF = (size_t)N * 128;
    long long n8 = (long long)(NF / 8);
    int NX = (int)((n8 + 255) / 256);

    // workspace (aliases: z1 reuses xb after gather; z2 reuses h after gemm1)
    unsigned short* h = (unsigned short*)d_ws;          // NF ush
    unsigned short* xb = h + NF;                        // NF ush
    unsigned short* z1 = xb;                            // alias (xb dead post-gather)
    unsigned short* z2 = h;                             // alias (h dead post-gemm1)
    unsigned* staging = (unsigned*)(xb + NF);           // N*RCAP u32 (fallback) /
    unsigned* rowsorted = staging;                      // rowsorted E u32 (bucketed)
    int* cur = (int*)(staging + (size_t)N * RCAP);      // N (fallback only)
    unsigned short* w1h = (unsigned short*)(cur + N);
    unsigned short* w1l = w1h + 16384;
    unsigned short* w2h = w1l + 16384;
    unsigned short* w2l = w2h + 16384;
    float* hwp = (float*)(w2l + 16384);                 // 8
    float* sums = hwp + 8;                              // 512
    float* sum1 = sums, *sq1 = sums + 128, *sum2 = sums + 256, *sq2 = sums + 384;
    int nbuk  = (N + 1023) >> 10;
    int nbukp = (nbuk + 7) & ~7;                        // %8 == 0
    int* C = (int*)(sums + 512);                        // nbukp * P2B (transposed)
    int* tot = C + (size_t)nbukp * P2B;                 // nbukp
    unsigned* bucketed = (unsigned*)(tot + nbukp);      // E records
    int* rowstart = (int*)(bucketed + E);               // N + 1
    size_t ws_need = (size_t)((char*)(rowstart + N + 1) - (char*)d_ws);
    bool use_bucketed = (nbukp <= 128) && (N <= (1 << 17)) && (K <= 7)
                        && ((size_t)E <= (size_t)N * RCAP)
                        && (ws_need <= ws_size);

    float invN = 1.0f / (float)N;
    int per = (E + P2B - 1) / P2B;

    int prep_grid = use_bucketed ? (3 + NX + P2B) : (3 + NX);
    if (!use_bucketed)
        hipMemsetAsync(cur, 0, (size_t)N * sizeof(int), stream);
    prep_k<<<prep_grid, 256, 0, stream>>>(hc, hwp, sums, W1, W2,
        w1h, w1l, w2h, w2l, (const float4*)x, (uint4*)xb, K, n8,
        ei, C, E, per, nbukp, N, NX);
    long long tot_thr = (long long)N * 64;
    int ggrid = (int)((tot_thr + 255) / 256);
    if (use_bucketed) {
        scan1_k<<<nbukp, 256, 0, stream>>>(C, tot, nbukp, P2B);
        scatter_k<<<P2B, 256, 0, stream>>>(ei, ei + E, ew, C, tot, bucketed,
                                           E, per, nbukp, K);
        slot3s_k<<<nbukp, 256, 0, stream>>>(bucketed, tot, rowsorted, rowstart,
                                            nbukp, N);
        gather_k<<<ggrid, 256, 0, stream>>>(xb, rowsorted, rowstart, hwp, h, N);
    } else {
        slot_k<<<(E + 255) / 256, 256, 0, stream>>>(ei, ei + E, ew, cur, staging, E, K);
        gather_stg_k<<<ggrid, 256, 0, stream>>>(xb, staging, cur, hwp, h, N);
    }
    int gblocks = (N + 127) / 128;
    gemm_mfma_k<<<gblocks, 256, 0, stream>>>(h, w1h, w1l, b1, z1, sum1, sq1, N);
    gemm_mfma_bn_k<<<gblocks, 256, 0, stream>>>(z1, sum1, sq1, g1, be1, invN,
        w2h, w2l, b2, z2, sum2, sq2, N);
    bn2_k<<<NX, 256, 0, stream>>>(z2, sum2, sq2, g2, be2, (float*)d_out, n8, invN);
}